// Round 4
// baseline (316.764 us; speedup 1.0000x reference)
//
#include <hip/hip_runtime.h>
#include <hip/hip_bf16.h>

// Shapes (fixed): B=8, H=W=32, E=768, nh=12, hd=64, N=1024, BH=96
// ws layout (bytes):
//   xb      @ 0          : 12,582,912  (x cast to bf16)
//   wqkvT   @ 12582912   :  3,538,944  (Wqkv^T bf16)
//   wprojT  @ 16121856   :  1,179,648  (Wproj^T bf16)
//   qkvb    @ 17301504   : 37,748,736  (qkv bf16; later aliased by attn-out bf16)
//   Q       @ 55050240   : 12,582,912
//   K       @ 67633152   : 12,582,912
//   Vt      @ 80216064   : 12,582,912  (V transposed: [bh][d][n])

typedef __attribute__((ext_vector_type(8))) short short8;
typedef __attribute__((ext_vector_type(4))) float f32x4;

__global__ __launch_bounds__(256) void cast_f32_bf16(const float* __restrict__ in,
                                                     __hip_bfloat16* __restrict__ out) {
  int i = (blockIdx.x * 256 + threadIdx.x) * 4;
  float4 v = *(const float4*)&in[i];
  out[i + 0] = __float2bfloat16(v.x);
  out[i + 1] = __float2bfloat16(v.y);
  out[i + 2] = __float2bfloat16(v.z);
  out[i + 3] = __float2bfloat16(v.w);
}

// in [K][N] f32 -> out [N][K] bf16
__global__ __launch_bounds__(256) void transpose_cast(const float* __restrict__ in,
                                                      __hip_bfloat16* __restrict__ out,
                                                      int K, int N) {
  __shared__ float tile[32][33];
  int n0 = blockIdx.x * 32, k0 = blockIdx.y * 32;
  int tx = threadIdx.x & 31, ty = threadIdx.x >> 5;  // 32 x 8
#pragma unroll
  for (int i = 0; i < 4; ++i)
    tile[ty + i * 8][tx] = in[(size_t)(k0 + ty + i * 8) * N + n0 + tx];
  __syncthreads();
#pragma unroll
  for (int i = 0; i < 4; ++i)
    out[(size_t)(n0 + ty + i * 8) * K + k0 + tx] = __float2bfloat16(tile[tx][ty + i * 8]);
}

__device__ inline void gload16(const void* g, void* l) {
  __builtin_amdgcn_global_load_lds((const __attribute__((address_space(1))) void*)g,
                                   (__attribute__((address_space(3))) void*)l, 16, 0, 0);
}

// C[M,N] = A[M,K]*Bt[N,K]^T + bias ; 128x128 tile, 4 waves (2x2), BK=64,
// staging via global_load_lds width=16 into linear LDS (m97 structure).
template<bool OUT_BF16>
__global__ __launch_bounds__(256) void gemm_dma(const __hip_bfloat16* __restrict__ A,
                                                const __hip_bfloat16* __restrict__ Bt,
                                                const float* __restrict__ bias,
                                                void* __restrict__ Cout,
                                                int N, int K) {
  __shared__ __hip_bfloat16 Al[128 * 64];
  __shared__ __hip_bfloat16 Bl[128 * 64];
  int n0 = blockIdx.x * 128, m0 = blockIdx.y * 128;
  int tid = threadIdx.x, lane = tid & 63, wid = tid >> 6;
  int wm = wid >> 1, wn = wid & 1;
  int lr = lane & 15, lg = lane >> 4;
  int row_l = lane >> 3, col8 = (lane & 7) * 8;
  f32x4 acc[4][4] = {};
  for (int k0 = 0; k0 < K; k0 += 64) {
#pragma unroll
    for (int j = 0; j < 4; ++j) {
      int jj = wid * 4 + j;                 // 0..15, uniform per wave
      int arow = jj * 8 + row_l;
      gload16(&A[(size_t)(m0 + arow) * K + k0 + col8], &Al[jj * 512]);
      gload16(&Bt[(size_t)(n0 + arow) * K + k0 + col8], &Bl[jj * 512]);
    }
    __syncthreads();  // drains vmcnt (DMA writes) per compiler barrier semantics
#pragma unroll
    for (int ks = 0; ks < 2; ++ks) {
      short8 af[4], bfr[4];
#pragma unroll
      for (int m = 0; m < 4; ++m)
        af[m] = *(const short8*)&Al[(wm * 64 + m * 16 + lr) * 64 + ks * 32 + lg * 8];
#pragma unroll
      for (int n = 0; n < 4; ++n)
        bfr[n] = *(const short8*)&Bl[(wn * 64 + n * 16 + lr) * 64 + ks * 32 + lg * 8];
#pragma unroll
      for (int m = 0; m < 4; ++m)
#pragma unroll
        for (int n = 0; n < 4; ++n)
          acc[m][n] = __builtin_amdgcn_mfma_f32_16x16x32_bf16(af[m], bfr[n], acc[m][n], 0, 0, 0);
    }
    __syncthreads();
  }
#pragma unroll
  for (int n = 0; n < 4; ++n) {
    int col = n0 + wn * 64 + n * 16 + lr;
    float bv = bias[col];
#pragma unroll
    for (int m = 0; m < 4; ++m) {
      int rowb = m0 + wm * 64 + m * 16 + lg * 4;
#pragma unroll
      for (int r = 0; r < 4; ++r) {
        float v = acc[m][n][r] + bv;
        if (OUT_BF16)
          ((__hip_bfloat16*)Cout)[(size_t)(rowb + r) * N + col] = __float2bfloat16(v);
        else
          ((float*)Cout)[(size_t)(rowb + r) * N + col] = v;
      }
    }
  }
}

// Faithful scrambled qkv extraction (verified in R0).
__global__ __launch_bounds__(256) void permute_qkv(const __hip_bfloat16* __restrict__ qkv,
                                                   __hip_bfloat16* __restrict__ Q,
                                                   __hip_bfloat16* __restrict__ Kd,
                                                   __hip_bfloat16* __restrict__ Vt) {
  int bh = blockIdx.y;
  int n0 = blockIdx.x * 64;
  int tid = threadIdx.x;
  __shared__ __hip_bfloat16 vt[64][72];
#pragma unroll
  for (int i = 0; i < 16; ++i) {
    int idx = tid + i * 256;
    int nl = idx >> 6, d2 = idx & 63;
    int n2 = n0 + nl;
    int F = bh * 196608 + n2 * 192 + d2 * 3;
#pragma unroll
    for (int c2 = 0; c2 < 3; ++c2) {
      int Fc = F + c2;
      int b = Fc / 2359296;
      int G = Fc % 2359296;
      int n = G / 2304, G2 = G % 2304;
      int h = G2 / 192, G3 = G2 % 192;
      int c = G3 >> 6, dd = G3 & 63;
      __hip_bfloat16 v = qkv[(size_t)(b * 1024 + n) * 2304 + h * 192 + dd * 3 + c];
      if (c2 == 0)      Q[(size_t)bh * 65536 + n2 * 64 + d2] = v;
      else if (c2 == 1) Kd[(size_t)bh * 65536 + n2 * 64 + d2] = v;
      else              vt[d2][nl] = v;
    }
  }
  __syncthreads();
#pragma unroll
  for (int i = 0; i < 16; ++i) {
    int idx = tid + i * 256;
    int d2 = idx >> 6, nl = idx & 63;
    Vt[(size_t)bh * 65536 + d2 * 1024 + n0 + nl] = vt[d2][nl];
  }
}

__device__ inline short8 cvt8(const float* p) {
  short8 r;
#pragma unroll
  for (int j = 0; j < 8; ++j) {
    __hip_bfloat16 b = __float2bfloat16(p[j]);
    r[j] = *reinterpret_cast<const short*>(&b);
  }
  return r;
}

// truncation pack: [b_hi16 | a_hi16] in one v_perm_b32 (P>=0, no NaN)
__device__ inline unsigned packtrunc(float a, float b) {
  return __builtin_amdgcn_perm(__float_as_uint(b), __float_as_uint(a), 0x07060302u);
}

// Flash attention v4: 1 wave/block, 16 q-rows/wave, 64-kv chunks,
// K/V register double-buffer via same-register early re-issue (no ping-pong),
// defer-max + defer-sum, exp2 domain, perm-truncation P pack.
#define L2E 1.44269504088896f
__global__ __launch_bounds__(64, 4) void attn4(const __hip_bfloat16* __restrict__ Q,
                                               const __hip_bfloat16* __restrict__ Kd,
                                               const __hip_bfloat16* __restrict__ Vt,
                                               const float* __restrict__ rph,
                                               const float* __restrict__ rpw,
                                               __hip_bfloat16* __restrict__ outp) {
  int orig = blockIdx.x;                   // 6144 = 96 bh * 64 qtiles
  int xcd = orig & 7, loc = orig >> 3;     // 768 per xcd
  int bh = xcd * 12 + (loc % 12);
  int qt = loc / 12;                       // 0..63
  int lane = threadIdx.x;
  int lr = lane & 15, lg = lane >> 4;

  __shared__ float rh_lds[16 * 33];        // rh[q_local][kh]*L2E
  __shared__ __hip_bfloat16 smem[16 * 72]; // rw staging (16x68), then P tile

  const __hip_bfloat16* Qb = Q + (size_t)bh * 65536;
  const __hip_bfloat16* Kb = Kd + (size_t)bh * 65536;
  const __hip_bfloat16* Vb = Vt + (size_t)bh * 65536;

  int q0 = qt * 16;
  int hq = qt >> 1;                        // (q0+r)>>5 for r<16
  int wq_lane = (qt & 1) * 16 + lr;        // (q0+lr)&31

  short8 qf0 = *(const short8*)&Qb[(size_t)(q0 + lr) * 64 + lg * 8];
  short8 qf1 = *(const short8*)&Qb[(size_t)(q0 + lr) * 64 + 32 + lg * 8];

  // rel-pos bias via MFMA (pre-scaled by L2E for exp2 domain)
#pragma unroll
  for (int kt = 0; kt < 2; ++kt) {
    int row = hq - (kt * 16 + lr) + 31;    // in [0,62]
    const float* tp = rph + (size_t)row * 64 + lg * 8;
    short8 th0 = cvt8(tp), th1 = cvt8(tp + 32);
    f32x4 a = {};
    a = __builtin_amdgcn_mfma_f32_16x16x32_bf16(qf0, th0, a, 0, 0, 0);
    a = __builtin_amdgcn_mfma_f32_16x16x32_bf16(qf1, th1, a, 0, 0, 0);
#pragma unroll
    for (int r = 0; r < 4; ++r)
      rh_lds[(lg * 4 + r) * 33 + kt * 16 + lr] = a[r] * L2E;
  }
#pragma unroll
  for (int jt = 0; jt < 4; ++jt) {
    const float* tp = rpw + (size_t)(jt * 16 + lr) * 64 + lg * 8;
    short8 tw0 = cvt8(tp), tw1 = cvt8(tp + 32);
    f32x4 a = {};
    a = __builtin_amdgcn_mfma_f32_16x16x32_bf16(qf0, tw0, a, 0, 0, 0);
    a = __builtin_amdgcn_mfma_f32_16x16x32_bf16(qf1, tw1, a, 0, 0, 0);
#pragma unroll
    for (int r = 0; r < 4; ++r)
      smem[(lg * 4 + r) * 68 + jt * 16 + lr] = __float2bfloat16(a[r] * L2E);
  }
  // gather per-lane rw registers (lane handles q=lr; kv&31 = (i>>2)*16+lg*4+(i&3))
  float rwreg[8];
#pragma unroll
  for (int i = 0; i < 8; ++i) {
    int k = (i >> 2) * 16 + lg * 4 + (i & 3);
    rwreg[i] = __bfloat162float(smem[lr * 68 + (wq_lane - k + 31)]);
  }

  f32x4 O[4] = {};
  float m_ = -1e30f, lsum = 0.f;
  const float C = 0.125f * L2E;

  // prologue: chunk 0 K/V frags
  short8 kf[8], vf[8];
#pragma unroll
  for (int t = 0; t < 4; ++t) {
    kf[2 * t]     = *(const short8*)&Kb[(size_t)(t * 16 + lr) * 64 + lg * 8];
    kf[2 * t + 1] = *(const short8*)&Kb[(size_t)(t * 16 + lr) * 64 + 32 + lg * 8];
    vf[2 * t]     = *(const short8*)&Vb[(size_t)(t * 16 + lr) * 1024 + lg * 8];
    vf[2 * t + 1] = *(const short8*)&Vb[(size_t)(t * 16 + lr) * 1024 + 32 + lg * 8];
  }

#pragma unroll 1
  for (int kv0 = 0; kv0 < 1024; kv0 += 64) {
    int nxt = kv0 + 64;
    if (nxt > 960) nxt = 960;  // last-iter dummy refetch (in-bounds, unused)
    // ---- QK^T (swapped): st[t][r] = S[kv=kv0+t*16+lg*4+r][q=lr]
    f32x4 st[4];
#pragma unroll
    for (int t = 0; t < 4; ++t) {
      f32x4 z = {};
      z = __builtin_amdgcn_mfma_f32_16x16x32_bf16(kf[2 * t], qf0, z, 0, 0, 0);
      z = __builtin_amdgcn_mfma_f32_16x16x32_bf16(kf[2 * t + 1], qf1, z, 0, 0, 0);
      st[t] = z;
    }
    // ---- prefetch next K into the SAME registers (WAR-safe, hides under softmax+PV)
#pragma unroll
    for (int t = 0; t < 4; ++t) {
      kf[2 * t]     = *(const short8*)&Kb[(size_t)(nxt + t * 16 + lr) * 64 + lg * 8];
      kf[2 * t + 1] = *(const short8*)&Kb[(size_t)(nxt + t * 16 + lr) * 64 + 32 + lg * 8];
    }
    // ---- bias add (log2 domain) + in-lane max
    int kh = kv0 >> 5;
    float bh0 = rh_lds[lr * 33 + kh];
    float bh1 = rh_lds[lr * 33 + kh + 1];
    float mx = -1e30f;
#pragma unroll
    for (int t = 0; t < 4; ++t)
#pragma unroll
      for (int r = 0; r < 4; ++r) {
        float sv = fmaf(st[t][r], C, ((t < 2) ? bh0 : bh1) + rwreg[(t & 1) * 4 + r]);
        st[t][r] = sv;
        mx = fmaxf(mx, sv);
      }
    // ---- defer-max rescale (rare)
    if (!__all(mx <= m_ + 8.f)) {
      float mw = fmaxf(mx, __shfl_xor(mx, 16, 64));
      mw = fmaxf(mw, __shfl_xor(mw, 32, 64));
      float mnew = fmaxf(m_, mw);
      float al = exp2f(m_ - mnew);
      lsum *= al;
      m_ = mnew;
#pragma unroll
      for (int r = 0; r < 4; ++r) {
        float av = __shfl(al, lg * 4 + r, 64);
#pragma unroll
        for (int dt = 0; dt < 4; ++dt) O[dt][r] *= av;
      }
    }
    // ---- exp2 + per-lane partial sum + truncation-pack to LDS
    float sa = 0.f;
#pragma unroll
    for (int t = 0; t < 4; ++t) {
      float p0 = exp2f(st[t][0] - m_);
      float p1 = exp2f(st[t][1] - m_);
      float p2 = exp2f(st[t][2] - m_);
      float p3 = exp2f(st[t][3] - m_);
      sa += (p0 + p1) + (p2 + p3);
      uint2 w;
      w.x = packtrunc(p0, p1);
      w.y = packtrunc(p2, p3);
      *(uint2*)&smem[lr * 72 + t * 16 + lg * 4] = w;
    }
    lsum += sa;
    // ---- read P A-frags (in-wave DS ordering, no barrier)
    short8 pf0 = *(const short8*)&smem[lr * 72 + lg * 8];
    short8 pf1 = *(const short8*)&smem[lr * 72 + 32 + lg * 8];
    // ---- PV
#pragma unroll
    for (int dt = 0; dt < 4; ++dt) {
      O[dt] = __builtin_amdgcn_mfma_f32_16x16x32_bf16(pf0, vf[2 * dt], O[dt], 0, 0, 0);
      O[dt] = __builtin_amdgcn_mfma_f32_16x16x32_bf16(pf1, vf[2 * dt + 1], O[dt], 0, 0, 0);
    }
    // ---- prefetch next V into the SAME registers (hides under next QK^T+softmax)
#pragma unroll
    for (int t = 0; t < 4; ++t) {
      vf[2 * t]     = *(const short8*)&Vb[(size_t)(t * 16 + lr) * 1024 + nxt + lg * 8];
      vf[2 * t + 1] = *(const short8*)&Vb[(size_t)(t * 16 + lr) * 1024 + nxt + 32 + lg * 8];
    }
  }

  // epilogue: reduce deferred l, then faithful out permutation (verified in R0)
  float lt = lsum;
  lt += __shfl_xor(lt, 16, 64);
  lt += __shfl_xor(lt, 32, 64);
  float linv = 1.f / lt;
#pragma unroll
  for (int r = 0; r < 4; ++r) {
    float lv = __shfl(linv, lg * 4 + r, 64);
    int n = q0 + lg * 4 + r;
#pragma unroll
    for (int dt = 0; dt < 4; ++dt) {
      int d = dt * 16 + lr;
      int Sidx = bh * 65536 + n * 64 + d;
      int b = Sidx / 786432, r1 = Sidx % 786432;
      int pp = r1 / 24576, r2 = r1 % 24576;
      int qq = r2 / 768, r3 = r2 % 768;
      int j = r3 >> 6, dd = r3 & 63;
      int P = b * 786432 + j * 65536 + pp * 2048 + qq * 64 + dd;
      outp[P] = __float2bfloat16(O[dt][r] * lv);
    }
  }
}

extern "C" void kernel_launch(void* const* d_in, const int* in_sizes, int n_in,
                              void* d_out, int out_size, void* d_ws, size_t ws_size,
                              hipStream_t stream) {
  const float* x     = (const float*)d_in[0];
  const float* Wqkv  = (const float*)d_in[1];
  const float* bqkv  = (const float*)d_in[2];
  const float* Wproj = (const float*)d_in[3];
  const float* bproj = (const float*)d_in[4];
  const float* rph   = (const float*)d_in[5];
  const float* rpw   = (const float*)d_in[6];
  float* out = (float*)d_out;
  char* ws = (char*)d_ws;

  __hip_bfloat16* xb     = (__hip_bfloat16*)(ws);
  __hip_bfloat16* wqkvT  = (__hip_bfloat16*)(ws + 12582912);
  __hip_bfloat16* wprojT = (__hip_bfloat16*)(ws + 16121856);
  __hip_bfloat16* qkvb   = (__hip_bfloat16*)(ws + 17301504);  // later aliased as attn-out
  __hip_bfloat16* Qm     = (__hip_bfloat16*)(ws + 55050240);
  __hip_bfloat16* Km     = (__hip_bfloat16*)(ws + 67633152);
  __hip_bfloat16* Vtm    = (__hip_bfloat16*)(ws + 80216064);

  cast_f32_bf16<<<dim3(6144), dim3(256), 0, stream>>>(x, xb);
  transpose_cast<<<dim3(72, 24), dim3(256), 0, stream>>>(Wqkv, wqkvT, 768, 2304);
  transpose_cast<<<dim3(24, 24), dim3(256), 0, stream>>>(Wproj, wprojT, 768, 768);
  gemm_dma<true><<<dim3(18, 64), dim3(256), 0, stream>>>(xb, wqkvT, bqkv, (void*)qkvb, 2304, 768);
  permute_qkv<<<dim3(16, 96), dim3(256), 0, stream>>>(qkvb, Qm, Km, Vtm);
  attn4<<<dim3(6144), dim3(64), 0, stream>>>(Qm, Km, Vtm, rph, rpw, qkvb);
  gemm_dma<false><<<dim3(6, 64), dim3(256), 0, stream>>>(qkvb, wprojT, bproj, (void*)out, 768, 768);
}

// Round 5
// 225.927 us; speedup vs baseline: 1.4021x; 1.4021x over previous
//
#include <hip/hip_runtime.h>
#include <hip/hip_bf16.h>

// Shapes (fixed): B=8, H=W=32, E=768, nh=12, hd=64, N=1024, BH=96
// ws layout (bytes):
//   xb      @ 0          : 12,582,912  (x cast to bf16)
//   wqkvT   @ 12582912   :  3,538,944  (Wqkv^T bf16)
//   wprojT  @ 16121856   :  1,179,648  (Wproj^T bf16)
//   qkvb    @ 17301504   : 37,748,736  (qkv bf16; later aliased by attn-out bf16)
//   Q       @ 55050240   : 12,582,912
//   K       @ 67633152   : 12,582,912
//   Vt      @ 80216064   : 12,582,912  (V transposed: [bh][d][n])

typedef __attribute__((ext_vector_type(8))) short short8;
typedef __attribute__((ext_vector_type(4))) float f32x4;

__global__ __launch_bounds__(256) void cast_f32_bf16(const float* __restrict__ in,
                                                     __hip_bfloat16* __restrict__ out) {
  int i = (blockIdx.x * 256 + threadIdx.x) * 4;
  float4 v = *(const float4*)&in[i];
  out[i + 0] = __float2bfloat16(v.x);
  out[i + 1] = __float2bfloat16(v.y);
  out[i + 2] = __float2bfloat16(v.z);
  out[i + 3] = __float2bfloat16(v.w);
}

// in [K][N] f32 -> out [N][K] bf16
__global__ __launch_bounds__(256) void transpose_cast(const float* __restrict__ in,
                                                      __hip_bfloat16* __restrict__ out,
                                                      int K, int N) {
  __shared__ float tile[32][33];
  int n0 = blockIdx.x * 32, k0 = blockIdx.y * 32;
  int tx = threadIdx.x & 31, ty = threadIdx.x >> 5;  // 32 x 8
#pragma unroll
  for (int i = 0; i < 4; ++i)
    tile[ty + i * 8][tx] = in[(size_t)(k0 + ty + i * 8) * N + n0 + tx];
  __syncthreads();
#pragma unroll
  for (int i = 0; i < 4; ++i)
    out[(size_t)(n0 + ty + i * 8) * K + k0 + tx] = __float2bfloat16(tile[tx][ty + i * 8]);
}

__device__ inline void gload16(const void* g, void* l) {
  __builtin_amdgcn_global_load_lds((const __attribute__((address_space(1))) void*)g,
                                   (__attribute__((address_space(3))) void*)l, 16, 0, 0);
}

// C[M,N] = A[M,K]*Bt[N,K]^T + bias ; 128x128 tile, 4 waves (2x2), BK=64,
// staging via global_load_lds width=16 into linear LDS (m97 structure).
template<bool OUT_BF16>
__global__ __launch_bounds__(256) void gemm_dma(const __hip_bfloat16* __restrict__ A,
                                                const __hip_bfloat16* __restrict__ Bt,
                                                const float* __restrict__ bias,
                                                void* __restrict__ Cout,
                                                int N, int K) {
  __shared__ __hip_bfloat16 Al[128 * 64];
  __shared__ __hip_bfloat16 Bl[128 * 64];
  int n0 = blockIdx.x * 128, m0 = blockIdx.y * 128;
  int tid = threadIdx.x, lane = tid & 63, wid = tid >> 6;
  int wm = wid >> 1, wn = wid & 1;
  int lr = lane & 15, lg = lane >> 4;
  int row_l = lane >> 3, col8 = (lane & 7) * 8;
  f32x4 acc[4][4] = {};
  for (int k0 = 0; k0 < K; k0 += 64) {
#pragma unroll
    for (int j = 0; j < 4; ++j) {
      int jj = wid * 4 + j;                 // 0..15, uniform per wave
      int arow = jj * 8 + row_l;
      gload16(&A[(size_t)(m0 + arow) * K + k0 + col8], &Al[jj * 512]);
      gload16(&Bt[(size_t)(n0 + arow) * K + k0 + col8], &Bl[jj * 512]);
    }
    __syncthreads();  // drains vmcnt (DMA writes) per compiler barrier semantics
#pragma unroll
    for (int ks = 0; ks < 2; ++ks) {
      short8 af[4], bfr[4];
#pragma unroll
      for (int m = 0; m < 4; ++m)
        af[m] = *(const short8*)&Al[(wm * 64 + m * 16 + lr) * 64 + ks * 32 + lg * 8];
#pragma unroll
      for (int n = 0; n < 4; ++n)
        bfr[n] = *(const short8*)&Bl[(wn * 64 + n * 16 + lr) * 64 + ks * 32 + lg * 8];
#pragma unroll
      for (int m = 0; m < 4; ++m)
#pragma unroll
        for (int n = 0; n < 4; ++n)
          acc[m][n] = __builtin_amdgcn_mfma_f32_16x16x32_bf16(af[m], bfr[n], acc[m][n], 0, 0, 0);
    }
    __syncthreads();
  }
#pragma unroll
  for (int n = 0; n < 4; ++n) {
    int col = n0 + wn * 64 + n * 16 + lr;
    float bv = bias[col];
#pragma unroll
    for (int m = 0; m < 4; ++m) {
      int rowb = m0 + wm * 64 + m * 16 + lg * 4;
#pragma unroll
      for (int r = 0; r < 4; ++r) {
        float v = acc[m][n][r] + bv;
        if (OUT_BF16)
          ((__hip_bfloat16*)Cout)[(size_t)(rowb + r) * N + col] = __float2bfloat16(v);
        else
          ((float*)Cout)[(size_t)(rowb + r) * N + col] = v;
      }
    }
  }
}

// Faithful scrambled qkv extraction (verified in R0).
__global__ __launch_bounds__(256) void permute_qkv(const __hip_bfloat16* __restrict__ qkv,
                                                   __hip_bfloat16* __restrict__ Q,
                                                   __hip_bfloat16* __restrict__ Kd,
                                                   __hip_bfloat16* __restrict__ Vt) {
  int bh = blockIdx.y;
  int n0 = blockIdx.x * 64;
  int tid = threadIdx.x;
  __shared__ __hip_bfloat16 vt[64][72];
#pragma unroll
  for (int i = 0; i < 16; ++i) {
    int idx = tid + i * 256;
    int nl = idx >> 6, d2 = idx & 63;
    int n2 = n0 + nl;
    int F = bh * 196608 + n2 * 192 + d2 * 3;
#pragma unroll
    for (int c2 = 0; c2 < 3; ++c2) {
      int Fc = F + c2;
      int b = Fc / 2359296;
      int G = Fc % 2359296;
      int n = G / 2304, G2 = G % 2304;
      int h = G2 / 192, G3 = G2 % 192;
      int c = G3 >> 6, dd = G3 & 63;
      __hip_bfloat16 v = qkv[(size_t)(b * 1024 + n) * 2304 + h * 192 + dd * 3 + c];
      if (c2 == 0)      Q[(size_t)bh * 65536 + n2 * 64 + d2] = v;
      else if (c2 == 1) Kd[(size_t)bh * 65536 + n2 * 64 + d2] = v;
      else              vt[d2][nl] = v;
    }
  }
  __syncthreads();
#pragma unroll
  for (int i = 0; i < 16; ++i) {
    int idx = tid + i * 256;
    int d2 = idx >> 6, nl = idx & 63;
    Vt[(size_t)bh * 65536 + d2 * 1024 + n0 + nl] = vt[d2][nl];
  }
}

__device__ inline short8 cvt8(const float* p) {
  short8 r;
#pragma unroll
  for (int j = 0; j < 8; ++j) {
    __hip_bfloat16 b = __float2bfloat16(p[j]);
    r[j] = *reinterpret_cast<const short*>(&b);
  }
  return r;
}

__device__ inline unsigned pack2(float a, float b) {
  __hip_bfloat16 b0 = __float2bfloat16(a);
  __hip_bfloat16 b1 = __float2bfloat16(b);
  return ((unsigned)*(const unsigned short*)&b1 << 16) |
         (unsigned)*(const unsigned short*)&b0;
}

// Flash attention v5: 1 wave/block, 32 q-rows/wave, 64-kv chunks.
// K/V staged by global_load_lds DMA (zero VGPR cost), double-buffered with
// counted s_waitcnt vmcnt(16) (T3/T4, 1-wave form: no barriers at all).
// XOR-swizzled LDS (slot ^= row&7) applied on BOTH the DMA source address and
// the ds_read address (rule #21) -> <=2-way bank conflicts everywhere.
#define L2E 1.44269504088896f
__global__ __launch_bounds__(64) void attn5(const __hip_bfloat16* __restrict__ Q,
                                            const __hip_bfloat16* __restrict__ Kd,
                                            const __hip_bfloat16* __restrict__ Vt,
                                            const float* __restrict__ rph,
                                            const float* __restrict__ rpw,
                                            __hip_bfloat16* __restrict__ outp) {
  int orig = blockIdx.x;                   // 3072 = 96 bh * 32 qtiles
  int xcd = orig & 7, loc = orig >> 3;     // 384 per xcd
  int bh = xcd * 12 + (loc % 12);
  int qt = loc / 12;                       // 0..31
  int lane = threadIdx.x;
  int lr = lane & 15, lg = lane >> 4;

  __shared__ __hip_bfloat16 Kl[2][4096];   // [buf][64 rows][8 slots x 16B], swizzled
  __shared__ __hip_bfloat16 Vl[2][4096];
  __shared__ __hip_bfloat16 rh_b[32 * 36]; // rh[q_local][kh]*L2E, bf16
  __shared__ __align__(16) char paux[4608]; // rw table (prologue) then P tiles [2][16][64] swz

  const __hip_bfloat16* Qb = Q + (size_t)bh * 65536;
  const __hip_bfloat16* Kb = Kd + (size_t)bh * 65536;
  const __hip_bfloat16* Vb = Vt + (size_t)bh * 65536;

  int q0 = qt * 32;
  int hq = qt;
  int xr = lr & 7;                          // row-XOR for swizzle

  short8 qf[2][2];
#pragma unroll
  for (int qh = 0; qh < 2; ++qh) {
    qf[qh][0] = *(const short8*)&Qb[(size_t)(q0 + qh * 16 + lr) * 64 + lg * 8];
    qf[qh][1] = *(const short8*)&Qb[(size_t)(q0 + qh * 16 + lr) * 64 + 32 + lg * 8];
  }

  // ---- rel-pos bias via MFMA (pre-scaled by L2E for exp2 domain) ----
#pragma unroll
  for (int kt = 0; kt < 2; ++kt) {
    int row = hq - (kt * 16 + lr) + 31;    // 0..62
    const float* tp = rph + (size_t)row * 64 + lg * 8;
    short8 th0 = cvt8(tp), th1 = cvt8(tp + 32);
#pragma unroll
    for (int qh = 0; qh < 2; ++qh) {
      f32x4 a = {};
      a = __builtin_amdgcn_mfma_f32_16x16x32_bf16(qf[qh][0], th0, a, 0, 0, 0);
      a = __builtin_amdgcn_mfma_f32_16x16x32_bf16(qf[qh][1], th1, a, 0, 0, 0);
#pragma unroll
      for (int r = 0; r < 4; ++r)
        rh_b[(qh * 16 + lg * 4 + r) * 36 + kt * 16 + lr] = __float2bfloat16(a[r] * L2E);
    }
  }
  __hip_bfloat16* rwt = (__hip_bfloat16*)paux;  // [32][68] bf16, prologue only
#pragma unroll
  for (int jt = 0; jt < 4; ++jt) {
    const float* tp = rpw + (size_t)(jt * 16 + lr) * 64 + lg * 8;
    short8 tw0 = cvt8(tp), tw1 = cvt8(tp + 32);
#pragma unroll
    for (int qh = 0; qh < 2; ++qh) {
      f32x4 a = {};
      a = __builtin_amdgcn_mfma_f32_16x16x32_bf16(qf[qh][0], tw0, a, 0, 0, 0);
      a = __builtin_amdgcn_mfma_f32_16x16x32_bf16(qf[qh][1], tw1, a, 0, 0, 0);
#pragma unroll
      for (int r = 0; r < 4; ++r)
        rwt[(qh * 16 + lg * 4 + r) * 68 + jt * 16 + lr] = __float2bfloat16(a[r] * L2E);
    }
  }
  // gather per-lane rw registers (q_local = qh*16+lr; kv&31 = (i>>2)*16+lg*4+(i&3))
  float rwreg[2][8];
#pragma unroll
  for (int qh = 0; qh < 2; ++qh) {
    int wq = qh * 16 + lr;
#pragma unroll
    for (int i = 0; i < 8; ++i) {
      int k = (i >> 2) * 16 + lg * 4 + (i & 3);
      rwreg[qh][i] = __bfloat162float(rwt[(qh * 16 + lr) * 68 + (wq - k + 31)]);
    }
  }

  f32x4 O[2][4] = {};
  float m_[2] = {-1e30f, -1e30f};
  float lsum[2] = {0.f, 0.f};
  const float C = 0.125f * L2E;
  char* pc = paux;  // P tiles: [qh][16 rows][8 slots x 16B], swizzled

  // DMA staging lane geometry: group g = lane>>3 (row-in-8), slot = lane&7,
  // source col pre-swizzled so LDS physical slot p holds logical col (p ^ row&7).
  int g_ = lane >> 3;
  int colb = ((lane & 7) ^ g_) * 8;

  // ---- prologue: drain prologue vmem, stage chunk 0 into buf 0 ----
  asm volatile("s_waitcnt vmcnt(0)" ::: "memory");
#pragma unroll
  for (int i = 0; i < 8; ++i)
    gload16(&Kb[(size_t)(i * 8 + g_) * 64 + colb], &Kl[0][i * 512]);
#pragma unroll
  for (int i = 0; i < 8; ++i)
    gload16(&Vb[(size_t)(i * 8 + g_) * 1024 + colb], &Vl[0][i * 512]);

  int cur = 0;
#pragma unroll 1
  for (int kv0 = 0; kv0 < 1024; kv0 += 64) {
    __builtin_amdgcn_sched_barrier(0);
    // ---- stage next chunk into buf^1 (16 DMA ops; last iter re-stages 960, unused)
    int nkv = (kv0 + 64 < 1024) ? kv0 + 64 : 960;
#pragma unroll
    for (int i = 0; i < 8; ++i)
      gload16(&Kb[(size_t)(nkv + i * 8 + g_) * 64 + colb], &Kl[cur ^ 1][i * 512]);
#pragma unroll
    for (int i = 0; i < 8; ++i)
      gload16(&Vb[(size_t)(i * 8 + g_) * 1024 + nkv + colb], &Vl[cur ^ 1][i * 512]);
    // ---- wait for the 16 OLDEST vmem ops = buf[cur]'s DMA (safe vs extra vmem)
    asm volatile("s_waitcnt vmcnt(16)" ::: "memory");
    __builtin_amdgcn_sched_barrier(0);

    const char* kc = (const char*)Kl[cur];
    const char* vc = (const char*)Vl[cur];
    // ---- K frags (swizzled ds_read_b128, <=2-way) ----
    short8 kf[8];
#pragma unroll
    for (int t = 0; t < 4; ++t)
#pragma unroll
      for (int h = 0; h < 2; ++h)
        kf[2 * t + h] = *(const short8*)(kc + (t * 16 + lr) * 128 + (((h * 4 + lg) ^ xr) * 16));
    // ---- QK^T (swapped): st[qh][t][r] = S[kv0+t*16+lg*4+r][q0+qh*16+lr]
    f32x4 st[2][4];
#pragma unroll
    for (int t = 0; t < 4; ++t)
#pragma unroll
      for (int qh = 0; qh < 2; ++qh) {
        f32x4 z = {};
        z = __builtin_amdgcn_mfma_f32_16x16x32_bf16(kf[2 * t], qf[qh][0], z, 0, 0, 0);
        z = __builtin_amdgcn_mfma_f32_16x16x32_bf16(kf[2 * t + 1], qf[qh][1], z, 0, 0, 0);
        st[qh][t] = z;
      }
    // ---- bias add (log2 domain) + in-lane max ----
    int kh = kv0 >> 5;
    float mxl[2];
#pragma unroll
    for (int qh = 0; qh < 2; ++qh) {
      float bh0 = __bfloat162float(rh_b[(qh * 16 + lr) * 36 + kh]);
      float bh1 = __bfloat162float(rh_b[(qh * 16 + lr) * 36 + kh + 1]);
      float mx = -1e30f;
#pragma unroll
      for (int t = 0; t < 4; ++t)
#pragma unroll
        for (int r = 0; r < 4; ++r) {
          float sv = fmaf(st[qh][t][r], C, ((t < 2) ? bh0 : bh1) + rwreg[qh][(t & 1) * 4 + r]);
          st[qh][t][r] = sv;
          mx = fmaxf(mx, sv);
        }
      mxl[qh] = mx;
    }
    // ---- defer-max rescale (rare) ----
    int cond = (mxl[0] <= m_[0] + 8.f) && (mxl[1] <= m_[1] + 8.f);
    if (!__all(cond)) {
#pragma unroll
      for (int qh = 0; qh < 2; ++qh) {
        float mw = fmaxf(mxl[qh], __shfl_xor(mxl[qh], 16, 64));
        mw = fmaxf(mw, __shfl_xor(mw, 32, 64));
        float mnew = fmaxf(m_[qh], mw);
        float al = exp2f(m_[qh] - mnew);
        lsum[qh] *= al;
        m_[qh] = mnew;
#pragma unroll
        for (int r = 0; r < 4; ++r) {
          float av = __shfl(al, lg * 4 + r, 64);
#pragma unroll
          for (int dt = 0; dt < 4; ++dt) O[qh][dt][r] *= av;
        }
      }
    }
    // ---- exp2 + per-lane partial sum + RNE pack to swizzled P tile ----
#pragma unroll
    for (int qh = 0; qh < 2; ++qh) {
      float mq = m_[qh];
      float sa = 0.f;
#pragma unroll
      for (int t = 0; t < 4; ++t) {
        float p0 = exp2f(st[qh][t][0] - mq);
        float p1 = exp2f(st[qh][t][1] - mq);
        float p2 = exp2f(st[qh][t][2] - mq);
        float p3 = exp2f(st[qh][t][3] - mq);
        sa += (p0 + p1) + (p2 + p3);
        uint2 w;
        w.x = pack2(p0, p1);
        w.y = pack2(p2, p3);
        int slot = (2 * t + (lg >> 1)) ^ xr;
        *(uint2*)(pc + qh * 2048 + lr * 128 + slot * 16 + (lg & 1) * 8) = w;
      }
      lsum[qh] += sa;
    }
    // ---- P frags (same-wave DS order; no barrier) ----
    short8 pf[2][2];
#pragma unroll
    for (int qh = 0; qh < 2; ++qh)
#pragma unroll
      for (int h = 0; h < 2; ++h)
        pf[qh][h] = *(const short8*)(pc + qh * 2048 + lr * 128 + (((h * 4 + lg) ^ xr) * 16));
    // ---- PV ----
#pragma unroll
    for (int dt = 0; dt < 4; ++dt) {
      short8 vf0 = *(const short8*)(vc + (dt * 16 + lr) * 128 + (((0 + lg) ^ xr) * 16));
      short8 vf1 = *(const short8*)(vc + (dt * 16 + lr) * 128 + (((4 + lg) ^ xr) * 16));
#pragma unroll
      for (int qh = 0; qh < 2; ++qh) {
        O[qh][dt] = __builtin_amdgcn_mfma_f32_16x16x32_bf16(pf[qh][0], vf0, O[qh][dt], 0, 0, 0);
        O[qh][dt] = __builtin_amdgcn_mfma_f32_16x16x32_bf16(pf[qh][1], vf1, O[qh][dt], 0, 0, 0);
      }
    }
    cur ^= 1;
  }

  // epilogue: reduce deferred l, then faithful out permutation (verified in R0)
#pragma unroll
  for (int qh = 0; qh < 2; ++qh) {
    float lt = lsum[qh];
    lt += __shfl_xor(lt, 16, 64);
    lt += __shfl_xor(lt, 32, 64);
    float linv = 1.f / lt;
#pragma unroll
    for (int r = 0; r < 4; ++r) {
      float lv = __shfl(linv, lg * 4 + r, 64);
      int n = q0 + qh * 16 + lg * 4 + r;
#pragma unroll
      for (int dt = 0; dt < 4; ++dt) {
        int d = dt * 16 + lr;
        int Sidx = bh * 65536 + n * 64 + d;
        int b = Sidx / 786432, r1 = Sidx % 786432;
        int pp = r1 / 24576, r2 = r1 % 24576;
        int qq = r2 / 768, r3 = r2 % 768;
        int j = r3 >> 6, dd = r3 & 63;
        int P = b * 786432 + j * 65536 + pp * 2048 + qq * 64 + dd;
        outp[P] = __float2bfloat16(O[qh][dt][r] * lv);
      }
    }
  }
}

extern "C" void kernel_launch(void* const* d_in, const int* in_sizes, int n_in,
                              void* d_out, int out_size, void* d_ws, size_t ws_size,
                              hipStream_t stream) {
  const float* x     = (const float*)d_in[0];
  const float* Wqkv  = (const float*)d_in[1];
  const float* bqkv  = (const float*)d_in[2];
  const float* Wproj = (const float*)d_in[3];
  const float* bproj = (const float*)d_in[4];
  const float* rph   = (const float*)d_in[5];
  const float* rpw   = (const float*)d_in[6];
  float* out = (float*)d_out;
  char* ws = (char*)d_ws;

  __hip_bfloat16* xb     = (__hip_bfloat16*)(ws);
  __hip_bfloat16* wqkvT  = (__hip_bfloat16*)(ws + 12582912);
  __hip_bfloat16* wprojT = (__hip_bfloat16*)(ws + 16121856);
  __hip_bfloat16* qkvb   = (__hip_bfloat16*)(ws + 17301504);  // later aliased as attn-out
  __hip_bfloat16* Qm     = (__hip_bfloat16*)(ws + 55050240);
  __hip_bfloat16* Km     = (__hip_bfloat16*)(ws + 67633152);
  __hip_bfloat16* Vtm    = (__hip_bfloat16*)(ws + 80216064);

  cast_f32_bf16<<<dim3(6144), dim3(256), 0, stream>>>(x, xb);
  transpose_cast<<<dim3(72, 24), dim3(256), 0, stream>>>(Wqkv, wqkvT, 768, 2304);
  transpose_cast<<<dim3(24, 24), dim3(256), 0, stream>>>(Wproj, wprojT, 768, 768);
  gemm_dma<true><<<dim3(18, 64), dim3(256), 0, stream>>>(xb, wqkvT, bqkv, (void*)qkvb, 2304, 768);
  permute_qkv<<<dim3(16, 96), dim3(256), 0, stream>>>(qkvb, Qm, Km, Vtm);
  attn5<<<dim3(3072), dim3(64), 0, stream>>>(Qm, Km, Vtm, rph, rpw, qkvb);
  gemm_dma<false><<<dim3(6, 64), dim3(256), 0, stream>>>(qkvb, wprojT, bproj, (void*)out, 768, 768);
}

// Round 9
// 190.508 us; speedup vs baseline: 1.6627x; 1.1859x over previous
//
#include <hip/hip_runtime.h>
#include <hip/hip_bf16.h>

// Shapes (fixed): B=8, H=W=32, E=768, nh=12, hd=64, N=1024, BH=96
// ws layout (bytes):
//   xb      @ 0          : 12,582,912  (x cast to bf16)
//   wqkvT   @ 12582912   :  3,538,944  (Wqkv^T bf16)
//   wprojT  @ 16121856   :  1,179,648  (Wproj^T bf16)
//   qkvb    @ 17301504   : 37,748,736  (qkv bf16; later aliased by attn-out bf16)
//   Q       @ 55050240   : 12,582,912
//   K       @ 67633152   : 12,582,912
//   Vt      @ 80216064   : 12,582,912  (V transposed: [bh][d][n])

typedef __attribute__((ext_vector_type(8))) short short8;
typedef __attribute__((ext_vector_type(4))) float f32x4;

__global__ __launch_bounds__(256) void cast_f32_bf16(const float* __restrict__ in,
                                                     __hip_bfloat16* __restrict__ out) {
  int i = (blockIdx.x * 256 + threadIdx.x) * 4;
  float4 v = *(const float4*)&in[i];
  out[i + 0] = __float2bfloat16(v.x);
  out[i + 1] = __float2bfloat16(v.y);
  out[i + 2] = __float2bfloat16(v.z);
  out[i + 3] = __float2bfloat16(v.w);
}

// in [K][N] f32 -> out [N][K] bf16
__global__ __launch_bounds__(256) void transpose_cast(const float* __restrict__ in,
                                                      __hip_bfloat16* __restrict__ out,
                                                      int K, int N) {
  __shared__ float tile[32][33];
  int n0 = blockIdx.x * 32, k0 = blockIdx.y * 32;
  int tx = threadIdx.x & 31, ty = threadIdx.x >> 5;  // 32 x 8
#pragma unroll
  for (int i = 0; i < 4; ++i)
    tile[ty + i * 8][tx] = in[(size_t)(k0 + ty + i * 8) * N + n0 + tx];
  __syncthreads();
#pragma unroll
  for (int i = 0; i < 4; ++i)
    out[(size_t)(n0 + ty + i * 8) * K + k0 + tx] = __float2bfloat16(tile[tx][ty + i * 8]);
}

__device__ inline void gload16(const void* g, void* l) {
  __builtin_amdgcn_global_load_lds((const __attribute__((address_space(1))) void*)g,
                                   (__attribute__((address_space(3))) void*)l, 16, 0, 0);
}

// C[M,N] = A[M,K]*Bt[N,K]^T + bias ; 128x128 tile, 4 waves (2x2), BK=64,
// staging via global_load_lds width=16 into linear LDS (m97 structure).
template<bool OUT_BF16>
__global__ __launch_bounds__(256) void gemm_dma(const __hip_bfloat16* __restrict__ A,
                                                const __hip_bfloat16* __restrict__ Bt,
                                                const float* __restrict__ bias,
                                                void* __restrict__ Cout,
                                                int N, int K) {
  __shared__ __hip_bfloat16 Al[128 * 64];
  __shared__ __hip_bfloat16 Bl[128 * 64];
  int n0 = blockIdx.x * 128, m0 = blockIdx.y * 128;
  int tid = threadIdx.x, lane = tid & 63, wid = tid >> 6;
  int wm = wid >> 1, wn = wid & 1;
  int lr = lane & 15, lg = lane >> 4;
  int row_l = lane >> 3, col8 = (lane & 7) * 8;
  f32x4 acc[4][4] = {};
  for (int k0 = 0; k0 < K; k0 += 64) {
#pragma unroll
    for (int j = 0; j < 4; ++j) {
      int jj = wid * 4 + j;                 // 0..15, uniform per wave
      int arow = jj * 8 + row_l;
      gload16(&A[(size_t)(m0 + arow) * K + k0 + col8], &Al[jj * 512]);
      gload16(&Bt[(size_t)(n0 + arow) * K + k0 + col8], &Bl[jj * 512]);
    }
    __syncthreads();  // drains vmcnt (DMA writes) per compiler barrier semantics
#pragma unroll
    for (int ks = 0; ks < 2; ++ks) {
      short8 af[4], bfr[4];
#pragma unroll
      for (int m = 0; m < 4; ++m)
        af[m] = *(const short8*)&Al[(wm * 64 + m * 16 + lr) * 64 + ks * 32 + lg * 8];
#pragma unroll
      for (int n = 0; n < 4; ++n)
        bfr[n] = *(const short8*)&Bl[(wn * 64 + n * 16 + lr) * 64 + ks * 32 + lg * 8];
#pragma unroll
      for (int m = 0; m < 4; ++m)
#pragma unroll
        for (int n = 0; n < 4; ++n)
          acc[m][n] = __builtin_amdgcn_mfma_f32_16x16x32_bf16(af[m], bfr[n], acc[m][n], 0, 0, 0);
    }
    __syncthreads();
  }
#pragma unroll
  for (int n = 0; n < 4; ++n) {
    int col = n0 + wn * 64 + n * 16 + lr;
    float bv = bias[col];
#pragma unroll
    for (int m = 0; m < 4; ++m) {
      int rowb = m0 + wm * 64 + m * 16 + lg * 4;
#pragma unroll
      for (int r = 0; r < 4; ++r) {
        float v = acc[m][n][r] + bv;
        if (OUT_BF16)
          ((__hip_bfloat16*)Cout)[(size_t)(rowb + r) * N + col] = __float2bfloat16(v);
        else
          ((float*)Cout)[(size_t)(rowb + r) * N + col] = v;
      }
    }
  }
}

// permute_qkv v2 (fixed): per dest (bh,n2) the CONTIGUOUS source window
// qkv_flat[(bh*1024+n2)*192 .. +192) with fixed intra-window permutation
// src_off(u) = (u&63)*3 + (u>>6), u = d2*3 + c2.
// R7 bug: Vt writeback covered only 8 of each 16 n-columns (2048 of 4096
// shorts) -> half of V^T was poison. Fix: write BOTH short8 halves.
__global__ __launch_bounds__(256) void permute_v2(const __hip_bfloat16* __restrict__ qkv,
                                                  __hip_bfloat16* __restrict__ Q,
                                                  __hip_bfloat16* __restrict__ Kd,
                                                  __hip_bfloat16* __restrict__ Vt) {
  int bh = blockIdx.y, n0 = blockIdx.x * 64;
  int tid = threadIdx.x;
  __shared__ short raw[64 * 200];     // window wi stride 200 (pad)
  __shared__ short vt[64][72];
  const short* src = (const short*)qkv + (size_t)(bh * 1024 + n0) * 192;
  // coalesced load of 12288 contiguous shorts (1536 x 16B; 24 chunks/window)
#pragma unroll
  for (int i = 0; i < 6; ++i) {
    int c16 = tid + i * 256;          // 0..1535
    int wi = c16 / 24, off = (c16 % 24) * 8;
    *(short8*)&raw[wi * 200 + off] = *(const short8*)&src[(size_t)c16 * 8];
  }
  __syncthreads();
  int wi = tid >> 2, g4 = tid & 3;
  const short* rw_ = &raw[wi * 200];
  short8 qv[2], kv_[2];
#pragma unroll
  for (int half = 0; half < 2; ++half)
#pragma unroll
    for (int j = 0; j < 8; ++j) {
      int d2 = g4 * 16 + half * 8 + j;
      int u = 3 * d2;
      qv[half][j]  = rw_[((u) & 63) * 3 + ((u) >> 6)];
      kv_[half][j] = rw_[((u + 1) & 63) * 3 + ((u + 1) >> 6)];
      vt[d2][wi]   = rw_[((u + 2) & 63) * 3 + ((u + 2) >> 6)];
    }
  size_t base = (size_t)bh * 65536 + (size_t)(n0 + wi) * 64 + g4 * 16;
  *(short8*)&Q[base] = qv[0];
  *(short8*)&Q[base + 8] = qv[1];
  *(short8*)&Kd[base] = kv_[0];
  *(short8*)&Kd[base + 8] = kv_[1];
  __syncthreads();
  int d2r = tid >> 2;
  size_t vbase = (size_t)bh * 65536 + (size_t)d2r * 1024 + n0 + g4 * 16;
  *(short8*)&Vt[vbase]     = *(const short8*)&vt[d2r][g4 * 16];
  *(short8*)&Vt[vbase + 8] = *(const short8*)&vt[d2r][g4 * 16 + 8];
}

__device__ inline short8 cvt8(const float* p) {
  short8 r;
#pragma unroll
  for (int j = 0; j < 8; ++j) {
    __hip_bfloat16 b = __float2bfloat16(p[j]);
    r[j] = *reinterpret_cast<const short*>(&b);
  }
  return r;
}

__device__ inline unsigned pack2(float a, float b) {
  __hip_bfloat16 b0 = __float2bfloat16(a);
  __hip_bfloat16 b1 = __float2bfloat16(b);
  return ((unsigned)*(const unsigned short*)&b1 << 16) |
         (unsigned)*(const unsigned short*)&b0;
}

// Flash attention v7: 4 waves/block, 16 q-rows/wave (block = 64 q-rows),
// shared K/V LDS staging via global_load_lds DMA, double-buffered with the
// SAFE 2-phase recipe: {issue next-chunk DMA -> compute current -> __syncthreads}.
// __syncthreads at END of chunk: next-chunk DMA overlaps the whole compute.
// XOR-swizzled LDS both-sides; defer-max + defer-sum; exp2 domain.
#define L2E 1.44269504088896f
__global__ __launch_bounds__(256) void attn7(const __hip_bfloat16* __restrict__ Q,
                                             const __hip_bfloat16* __restrict__ Kd,
                                             const __hip_bfloat16* __restrict__ Vt,
                                             const float* __restrict__ rph,
                                             const float* __restrict__ rpw,
                                             __hip_bfloat16* __restrict__ outp) {
  int orig = blockIdx.x;                   // 1536 = 8 xcd * 192
  int xcd = orig & 7, loc = orig >> 3;     // 192 per xcd
  int bh = xcd * 12 + (loc % 12);
  int qt = loc / 12;                       // 0..15 (64-row q tile)
  int tid = threadIdx.x;
  int lane = tid & 63, w = tid >> 6;
  int lr = lane & 15, lg = lane >> 4;
  int xr = lr & 7;

  __shared__ __hip_bfloat16 Kl[2][4096];   // [buf][64 rows][8 slots x 16B] swizzled
  __shared__ __hip_bfloat16 Vl[2][4096];
  __shared__ __hip_bfloat16 rh_b[4][16 * 36];
  __shared__ __align__(16) char scratch[4][2304]; // per-wave: rw[16][68] staging, then P tile

  const __hip_bfloat16* Qb = Q + (size_t)bh * 65536;
  const __hip_bfloat16* Kb = Kd + (size_t)bh * 65536;
  const __hip_bfloat16* Vb = Vt + (size_t)bh * 65536;

  int q0 = qt * 64 + w * 16;               // this wave's 16 q-rows
  int hq = q0 >> 5;
  int wq_lane = (q0 & 31) + lr;

  short8 qf0 = *(const short8*)&Qb[(size_t)(q0 + lr) * 64 + lg * 8];
  short8 qf1 = *(const short8*)&Qb[(size_t)(q0 + lr) * 64 + 32 + lg * 8];

  // ---- rel-pos bias via MFMA (pre-scaled by L2E), per-wave private LDS ----
  __hip_bfloat16* rhw = rh_b[w];
#pragma unroll
  for (int kt = 0; kt < 2; ++kt) {
    int row = hq - (kt * 16 + lr) + 31;    // 0..62
    const float* tp = rph + (size_t)row * 64 + lg * 8;
    short8 th0 = cvt8(tp), th1 = cvt8(tp + 32);
    f32x4 a = {};
    a = __builtin_amdgcn_mfma_f32_16x16x32_bf16(qf0, th0, a, 0, 0, 0);
    a = __builtin_amdgcn_mfma_f32_16x16x32_bf16(qf1, th1, a, 0, 0, 0);
#pragma unroll
    for (int r = 0; r < 4; ++r)
      rhw[(lg * 4 + r) * 36 + kt * 16 + lr] = __float2bfloat16(a[r] * L2E);
  }
  __hip_bfloat16* rwt = (__hip_bfloat16*)scratch[w];   // [16][68], prologue only
#pragma unroll
  for (int jt = 0; jt < 4; ++jt) {
    const float* tp = rpw + (size_t)(jt * 16 + lr) * 64 + lg * 8;
    short8 tw0 = cvt8(tp), tw1 = cvt8(tp + 32);
    f32x4 a = {};
    a = __builtin_amdgcn_mfma_f32_16x16x32_bf16(qf0, tw0, a, 0, 0, 0);
    a = __builtin_amdgcn_mfma_f32_16x16x32_bf16(qf1, tw1, a, 0, 0, 0);
#pragma unroll
    for (int r = 0; r < 4; ++r)
      rwt[(lg * 4 + r) * 68 + jt * 16 + lr] = __float2bfloat16(a[r] * L2E);
  }
  float rwreg[8];
#pragma unroll
  for (int i = 0; i < 8; ++i) {
    int k = (i >> 2) * 16 + lg * 4 + (i & 3);
    rwreg[i] = __bfloat162float(rwt[lr * 68 + (wq_lane - k + 31)]);
  }

  f32x4 O[4] = {};
  float m_ = -1e30f, lsum = 0.f;
  const float C = 0.125f * L2E;
  char* pc = scratch[w];                   // P tile: [16 rows][8 slots x 16B] swizzled

  // DMA staging geometry: wave w stages K rows [16w,16w+16) and V rows same
  // (ops op = 2w, 2w+1; each op = 8 rows x 64 cols, lane l -> row op*8+(l>>3)).
  int g_ = lane >> 3;                      // row-in-8
  int colb = ((lane & 7) ^ g_) * 8;        // pre-swizzled source col

  // ---- prologue: stage chunk 0 into buf 0, then full-drain barrier ----
#pragma unroll
  for (int i = 0; i < 2; ++i) {
    int op = 2 * w + i;                    // 0..7
    gload16(&Kb[(size_t)(op * 8 + g_) * 64 + colb], &Kl[0][op * 512]);
    gload16(&Vb[(size_t)(op * 8 + g_) * 1024 + colb], &Vl[0][op * 512]);
  }
  __syncthreads();                         // buf0 fully staged & visible

  int cur = 0;
#pragma unroll 1
  for (int kv0 = 0; kv0 < 1024; kv0 += 64) {
    // ---- issue next-chunk DMA into buf^1 (overlaps compute below) ----
    int nkv = (kv0 + 64 < 1024) ? kv0 + 64 : 960;  // last iter: dummy restage
#pragma unroll
    for (int i = 0; i < 2; ++i) {
      int op = 2 * w + i;
      gload16(&Kb[(size_t)(nkv + op * 8 + g_) * 64 + colb], &Kl[cur ^ 1][op * 512]);
      gload16(&Vb[(size_t)(op * 8 + g_) * 1024 + nkv + colb], &Vl[cur ^ 1][op * 512]);
    }

    const char* kc = (const char*)Kl[cur];
    const char* vc = (const char*)Vl[cur];
    // ---- K frags (swizzled ds_read_b128) ----
    short8 kf[8];
#pragma unroll
    for (int t = 0; t < 4; ++t)
#pragma unroll
      for (int h = 0; h < 2; ++h)
        kf[2 * t + h] = *(const short8*)(kc + (t * 16 + lr) * 128 + (((h * 4 + lg) ^ xr) * 16));
    // ---- QK^T (swapped): st[t][r] = S[kv=kv0+t*16+lg*4+r][q=q0+lr] ----
    f32x4 st[4];
#pragma unroll
    for (int t = 0; t < 4; ++t) {
      f32x4 z = {};
      z = __builtin_amdgcn_mfma_f32_16x16x32_bf16(kf[2 * t], qf0, z, 0, 0, 0);
      z = __builtin_amdgcn_mfma_f32_16x16x32_bf16(kf[2 * t + 1], qf1, z, 0, 0, 0);
      st[t] = z;
    }
    // ---- bias add (log2 domain) + in-lane max ----
    int kh = kv0 >> 5;
    float bh0 = __bfloat162float(rhw[lr * 36 + kh]);
    float bh1 = __bfloat162float(rhw[lr * 36 + kh + 1]);
    float mx = -1e30f;
#pragma unroll
    for (int t = 0; t < 4; ++t)
#pragma unroll
      for (int r = 0; r < 4; ++r) {
        float sv = fmaf(st[t][r], C, ((t < 2) ? bh0 : bh1) + rwreg[(t & 1) * 4 + r]);
        st[t][r] = sv;
        mx = fmaxf(mx, sv);
      }
    // ---- defer-max rescale (rare) ----
    if (!__all(mx <= m_ + 8.f)) {
      float mw = fmaxf(mx, __shfl_xor(mx, 16, 64));
      mw = fmaxf(mw, __shfl_xor(mw, 32, 64));
      float mnew = fmaxf(m_, mw);
      float al = exp2f(m_ - mnew);
      lsum *= al;
      m_ = mnew;
#pragma unroll
      for (int r = 0; r < 4; ++r) {
        float av = __shfl(al, lg * 4 + r, 64);
#pragma unroll
        for (int dt = 0; dt < 4; ++dt) O[dt][r] *= av;
      }
    }
    // ---- exp2 + per-lane partial sum + pack to swizzled P tile ----
    float sa = 0.f;
#pragma unroll
    for (int t = 0; t < 4; ++t) {
      float p0 = exp2f(st[t][0] - m_);
      float p1 = exp2f(st[t][1] - m_);
      float p2 = exp2f(st[t][2] - m_);
      float p3 = exp2f(st[t][3] - m_);
      sa += (p0 + p1) + (p2 + p3);
      uint2 wv;
      wv.x = pack2(p0, p1);
      wv.y = pack2(p2, p3);
      int slot = (2 * t + (lg >> 1)) ^ xr;
      *(uint2*)(pc + lr * 128 + slot * 16 + (lg & 1) * 8) = wv;
    }
    lsum += sa;
    // ---- P frags (same-wave DS ordering; no barrier needed) ----
    short8 pf0 = *(const short8*)(pc + lr * 128 + (((0 + lg) ^ xr) * 16));
    short8 pf1 = *(const short8*)(pc + lr * 128 + (((4 + lg) ^ xr) * 16));
    // ---- PV ----
#pragma unroll
    for (int dt = 0; dt < 4; ++dt) {
      short8 vf0 = *(const short8*)(vc + (dt * 16 + lr) * 128 + (((0 + lg) ^ xr) * 16));
      short8 vf1 = *(const short8*)(vc + (dt * 16 + lr) * 128 + (((4 + lg) ^ xr) * 16));
      O[dt] = __builtin_amdgcn_mfma_f32_16x16x32_bf16(pf0, vf0, O[dt], 0, 0, 0);
      O[dt] = __builtin_amdgcn_mfma_f32_16x16x32_bf16(pf1, vf1, O[dt], 0, 0, 0);
    }
    // ---- end-of-chunk: drain next-chunk DMA + execution barrier (safe 2-phase)
    __syncthreads();
    cur ^= 1;
  }

  // epilogue: reduce deferred l, then faithful out permutation (verified in R0)
  float lt = lsum;
  lt += __shfl_xor(lt, 16, 64);
  lt += __shfl_xor(lt, 32, 64);
  float linv = 1.f / lt;
#pragma unroll
  for (int r = 0; r < 4; ++r) {
    float lv = __shfl(linv, lg * 4 + r, 64);
    int n = q0 + lg * 4 + r;
#pragma unroll
    for (int dt = 0; dt < 4; ++dt) {
      int d = dt * 16 + lr;
      int Sidx = bh * 65536 + n * 64 + d;
      int b = Sidx / 786432, r1 = Sidx % 786432;
      int pp = r1 / 24576, r2 = r1 % 24576;
      int qq = r2 / 768, r3 = r2 % 768;
      int j = r3 >> 6, dd = r3 & 63;
      int P = b * 786432 + j * 65536 + pp * 2048 + qq * 64 + dd;
      outp[P] = __float2bfloat16(O[dt][r] * lv);
    }
  }
}

extern "C" void kernel_launch(void* const* d_in, const int* in_sizes, int n_in,
                              void* d_out, int out_size, void* d_ws, size_t ws_size,
                              hipStream_t stream) {
  const float* x     = (const float*)d_in[0];
  const float* Wqkv  = (const float*)d_in[1];
  const float* bqkv  = (const float*)d_in[2];
  const float* Wproj = (const float*)d_in[3];
  const float* bproj = (const float*)d_in[4];
  const float* rph   = (const float*)d_in[5];
  const float* rpw   = (const float*)d_in[6];
  float* out = (float*)d_out;
  char* ws = (char*)d_ws;

  __hip_bfloat16* xb     = (__hip_bfloat16*)(ws);
  __hip_bfloat16* wqkvT  = (__hip_bfloat16*)(ws + 12582912);
  __hip_bfloat16* wprojT = (__hip_bfloat16*)(ws + 16121856);
  __hip_bfloat16* qkvb   = (__hip_bfloat16*)(ws + 17301504);  // later aliased as attn-out
  __hip_bfloat16* Qm     = (__hip_bfloat16*)(ws + 55050240);
  __hip_bfloat16* Km     = (__hip_bfloat16*)(ws + 67633152);
  __hip_bfloat16* Vtm    = (__hip_bfloat16*)(ws + 80216064);

  cast_f32_bf16<<<dim3(6144), dim3(256), 0, stream>>>(x, xb);
  transpose_cast<<<dim3(72, 24), dim3(256), 0, stream>>>(Wqkv, wqkvT, 768, 2304);
  transpose_cast<<<dim3(24, 24), dim3(256), 0, stream>>>(Wproj, wprojT, 768, 768);
  gemm_dma<true><<<dim3(18, 64), dim3(256), 0, stream>>>(xb, wqkvT, bqkv, (void*)qkvb, 2304, 768);
  permute_v2<<<dim3(16, 96), dim3(256), 0, stream>>>(qkvb, Qm, Km, Vtm);
  attn7<<<dim3(1536), dim3(256), 0, stream>>>(Qm, Km, Vtm, rph, rpw, qkvb);
  gemm_dma<false><<<dim3(6, 64), dim3(256), 0, stream>>>(qkvb, wprojT, bproj, (void*)out, 768, 768);
}

// Round 10
// 184.418 us; speedup vs baseline: 1.7176x; 1.0330x over previous
//
#include <hip/hip_runtime.h>
#include <hip/hip_bf16.h>

// Shapes (fixed): B=8, H=W=32, E=768, nh=12, hd=64, N=1024, BH=96
// ws layout (bytes):
//   xb      @ 0          : 12,582,912  (x cast to bf16)
//   wqkvT   @ 12582912   :  3,538,944  (Wqkv^T bf16)
//   wprojT  @ 16121856   :  1,179,648  (Wproj^T bf16)
//   qkvb    @ 17301504   : 37,748,736  (qkv bf16; later aliased by attn-out bf16)
//   Q       @ 55050240   : 12,582,912
//   K       @ 67633152   : 12,582,912
//   Vt      @ 80216064   : 12,582,912  (V transposed: [bh][d][n])

typedef __attribute__((ext_vector_type(8))) short short8;
typedef __attribute__((ext_vector_type(4))) float f32x4;

__global__ __launch_bounds__(256) void cast_f32_bf16(const float* __restrict__ in,
                                                     __hip_bfloat16* __restrict__ out) {
  int i = (blockIdx.x * 256 + threadIdx.x) * 4;
  float4 v = *(const float4*)&in[i];
  out[i + 0] = __float2bfloat16(v.x);
  out[i + 1] = __float2bfloat16(v.y);
  out[i + 2] = __float2bfloat16(v.z);
  out[i + 3] = __float2bfloat16(v.w);
}

// in [K][N] f32 -> out [N][K] bf16
__global__ __launch_bounds__(256) void transpose_cast(const float* __restrict__ in,
                                                      __hip_bfloat16* __restrict__ out,
                                                      int K, int N) {
  __shared__ float tile[32][33];
  int n0 = blockIdx.x * 32, k0 = blockIdx.y * 32;
  int tx = threadIdx.x & 31, ty = threadIdx.x >> 5;  // 32 x 8
#pragma unroll
  for (int i = 0; i < 4; ++i)
    tile[ty + i * 8][tx] = in[(size_t)(k0 + ty + i * 8) * N + n0 + tx];
  __syncthreads();
#pragma unroll
  for (int i = 0; i < 4; ++i)
    out[(size_t)(n0 + ty + i * 8) * K + k0 + tx] = __float2bfloat16(tile[tx][ty + i * 8]);
}

__device__ inline void gload16(const void* g, void* l) {
  __builtin_amdgcn_global_load_lds((const __attribute__((address_space(1))) void*)g,
                                   (__attribute__((address_space(3))) void*)l, 16, 0, 0);
}

// C[M,N] = A[M,K]*Bt[N,K]^T + bias ; BMx128 tile (BM=128 or 64), 4 waves (2x2),
// BK=64, staging via global_load_lds width=16 into linear LDS (m97 structure).
template<int BM, bool OUT_BF16>
__global__ __launch_bounds__(256) void gemm_dma(const __hip_bfloat16* __restrict__ A,
                                                const __hip_bfloat16* __restrict__ Bt,
                                                const float* __restrict__ bias,
                                                void* __restrict__ Cout,
                                                int N, int K) {
  constexpr int FM = BM / 32;               // m-frags per wave (4 or 2)
  __shared__ __hip_bfloat16 Al[BM * 64];
  __shared__ __hip_bfloat16 Bl[128 * 64];
  int n0 = blockIdx.x * 128, m0 = blockIdx.y * BM;
  int tid = threadIdx.x, lane = tid & 63, wid = tid >> 6;
  int wm = wid >> 1, wn = wid & 1;
  int lr = lane & 15, lg = lane >> 4;
  int row_l = lane >> 3, col8 = (lane & 7) * 8;
  f32x4 acc[FM][4] = {};
  for (int k0 = 0; k0 < K; k0 += 64) {
#pragma unroll
    for (int j = 0; j < BM / 32; ++j) {     // A: BM*8/64 chunks over 4 waves
      int jj = wid * (BM / 32) + j;
      int arow = jj * 8 + row_l;
      gload16(&A[(size_t)(m0 + arow) * K + k0 + col8], &Al[jj * 512]);
    }
#pragma unroll
    for (int j = 0; j < 4; ++j) {           // B: 16 chunks over 4 waves
      int jj = wid * 4 + j;
      int brow = jj * 8 + row_l;
      gload16(&Bt[(size_t)(n0 + brow) * K + k0 + col8], &Bl[jj * 512]);
    }
    __syncthreads();  // drains vmcnt (DMA writes) per compiler barrier semantics
#pragma unroll
    for (int ks = 0; ks < 2; ++ks) {
      short8 af[FM], bfr[4];
#pragma unroll
      for (int m = 0; m < FM; ++m)
        af[m] = *(const short8*)&Al[(wm * (BM / 2) + m * 16 + lr) * 64 + ks * 32 + lg * 8];
#pragma unroll
      for (int n = 0; n < 4; ++n)
        bfr[n] = *(const short8*)&Bl[(wn * 64 + n * 16 + lr) * 64 + ks * 32 + lg * 8];
#pragma unroll
      for (int m = 0; m < FM; ++m)
#pragma unroll
        for (int n = 0; n < 4; ++n)
          acc[m][n] = __builtin_amdgcn_mfma_f32_16x16x32_bf16(af[m], bfr[n], acc[m][n], 0, 0, 0);
    }
    __syncthreads();
  }
#pragma unroll
  for (int n = 0; n < 4; ++n) {
    int col = n0 + wn * 64 + n * 16 + lr;
    float bv = bias[col];
#pragma unroll
    for (int m = 0; m < FM; ++m) {
      int rowb = m0 + wm * (BM / 2) + m * 16 + lg * 4;
#pragma unroll
      for (int r = 0; r < 4; ++r) {
        float v = acc[m][n][r] + bv;
        if (OUT_BF16)
          ((__hip_bfloat16*)Cout)[(size_t)(rowb + r) * N + col] = __float2bfloat16(v);
        else
          ((float*)Cout)[(size_t)(rowb + r) * N + col] = v;
      }
    }
  }
}

// permute_qkv v2 (verified R8): per dest (bh,n2) the CONTIGUOUS source window
// qkv_flat[(bh*1024+n2)*192 .. +192) with fixed intra-window permutation
// src_off(u) = (u&63)*3 + (u>>6), u = d2*3 + c2.
__global__ __launch_bounds__(256) void permute_v2(const __hip_bfloat16* __restrict__ qkv,
                                                  __hip_bfloat16* __restrict__ Q,
                                                  __hip_bfloat16* __restrict__ Kd,
                                                  __hip_bfloat16* __restrict__ Vt) {
  int bh = blockIdx.y, n0 = blockIdx.x * 64;
  int tid = threadIdx.x;
  __shared__ short raw[64 * 200];     // window wi stride 200 (pad)
  __shared__ short vt[64][72];
  const short* src = (const short*)qkv + (size_t)(bh * 1024 + n0) * 192;
#pragma unroll
  for (int i = 0; i < 6; ++i) {
    int c16 = tid + i * 256;          // 0..1535
    int wi = c16 / 24, off = (c16 % 24) * 8;
    *(short8*)&raw[wi * 200 + off] = *(const short8*)&src[(size_t)c16 * 8];
  }
  __syncthreads();
  int wi = tid >> 2, g4 = tid & 3;
  const short* rw_ = &raw[wi * 200];
  short8 qv[2], kv_[2];
#pragma unroll
  for (int half = 0; half < 2; ++half)
#pragma unroll
    for (int j = 0; j < 8; ++j) {
      int d2 = g4 * 16 + half * 8 + j;
      int u = 3 * d2;
      qv[half][j]  = rw_[((u) & 63) * 3 + ((u) >> 6)];
      kv_[half][j] = rw_[((u + 1) & 63) * 3 + ((u + 1) >> 6)];
      vt[d2][wi]   = rw_[((u + 2) & 63) * 3 + ((u + 2) >> 6)];
    }
  size_t base = (size_t)bh * 65536 + (size_t)(n0 + wi) * 64 + g4 * 16;
  *(short8*)&Q[base] = qv[0];
  *(short8*)&Q[base + 8] = qv[1];
  *(short8*)&Kd[base] = kv_[0];
  *(short8*)&Kd[base + 8] = kv_[1];
  __syncthreads();
  int d2r = tid >> 2;
  size_t vbase = (size_t)bh * 65536 + (size_t)d2r * 1024 + n0 + g4 * 16;
  *(short8*)&Vt[vbase]     = *(const short8*)&vt[d2r][g4 * 16];
  *(short8*)&Vt[vbase + 8] = *(const short8*)&vt[d2r][g4 * 16 + 8];
}

__device__ inline short8 cvt8(const float* p) {
  short8 r;
#pragma unroll
  for (int j = 0; j < 8; ++j) {
    __hip_bfloat16 b = __float2bfloat16(p[j]);
    r[j] = *reinterpret_cast<const short*>(&b);
  }
  return r;
}

// truncation pack: [b_hi16 | a_hi16] in one v_perm_b32 (valid: P>=0, no NaN).
// <=2^-8 one-sided relative error on P only; l is accumulated in f32 pre-pack.
__device__ inline unsigned packtrunc(float a, float b) {
  return __builtin_amdgcn_perm(__float_as_uint(b), __float_as_uint(a), 0x07060302u);
}

// Flash attention v8 (= v7 + truncation P pack): 4 waves/block, 16 q-rows/wave,
// shared K/V LDS staging via global_load_lds DMA, safe 2-phase double buffer
// {issue next DMA -> compute current -> __syncthreads}. XOR-swizzled LDS;
// defer-max + defer-sum; exp2 domain.
#define L2E 1.44269504088896f
__global__ __launch_bounds__(256) void attn8(const __hip_bfloat16* __restrict__ Q,
                                             const __hip_bfloat16* __restrict__ Kd,
                                             const __hip_bfloat16* __restrict__ Vt,
                                             const float* __restrict__ rph,
                                             const float* __restrict__ rpw,
                                             __hip_bfloat16* __restrict__ outp) {
  int orig = blockIdx.x;                   // 1536 = 8 xcd * 192
  int xcd = orig & 7, loc = orig >> 3;     // 192 per xcd
  int bh = xcd * 12 + (loc % 12);
  int qt = loc / 12;                       // 0..15 (64-row q tile)
  int tid = threadIdx.x;
  int lane = tid & 63, w = tid >> 6;
  int lr = lane & 15, lg = lane >> 4;
  int xr = lr & 7;

  __shared__ __hip_bfloat16 Kl[2][4096];   // [buf][64 rows][8 slots x 16B] swizzled
  __shared__ __hip_bfloat16 Vl[2][4096];
  __shared__ __hip_bfloat16 rh_b[4][16 * 36];
  __shared__ __align__(16) char scratch[4][2304]; // per-wave: rw staging, then P tile

  const __hip_bfloat16* Qb = Q + (size_t)bh * 65536;
  const __hip_bfloat16* Kb = Kd + (size_t)bh * 65536;
  const __hip_bfloat16* Vb = Vt + (size_t)bh * 65536;

  int q0 = qt * 64 + w * 16;               // this wave's 16 q-rows
  int hq = q0 >> 5;
  int wq_lane = (q0 & 31) + lr;

  short8 qf0 = *(const short8*)&Qb[(size_t)(q0 + lr) * 64 + lg * 8];
  short8 qf1 = *(const short8*)&Qb[(size_t)(q0 + lr) * 64 + 32 + lg * 8];

  // ---- rel-pos bias via MFMA (pre-scaled by L2E), per-wave private LDS ----
  __hip_bfloat16* rhw = rh_b[w];
#pragma unroll
  for (int kt = 0; kt < 2; ++kt) {
    int row = hq - (kt * 16 + lr) + 31;    // 0..62
    const float* tp = rph + (size_t)row * 64 + lg * 8;
    short8 th0 = cvt8(tp), th1 = cvt8(tp + 32);
    f32x4 a = {};
    a = __builtin_amdgcn_mfma_f32_16x16x32_bf16(qf0, th0, a, 0, 0, 0);
    a = __builtin_amdgcn_mfma_f32_16x16x32_bf16(qf1, th1, a, 0, 0, 0);
#pragma unroll
    for (int r = 0; r < 4; ++r)
      rhw[(lg * 4 + r) * 36 + kt * 16 + lr] = __float2bfloat16(a[r] * L2E);
  }
  __hip_bfloat16* rwt = (__hip_bfloat16*)scratch[w];   // [16][68], prologue only
#pragma unroll
  for (int jt = 0; jt < 4; ++jt) {
    const float* tp = rpw + (size_t)(jt * 16 + lr) * 64 + lg * 8;
    short8 tw0 = cvt8(tp), tw1 = cvt8(tp + 32);
    f32x4 a = {};
    a = __builtin_amdgcn_mfma_f32_16x16x32_bf16(qf0, tw0, a, 0, 0, 0);
    a = __builtin_amdgcn_mfma_f32_16x16x32_bf16(qf1, tw1, a, 0, 0, 0);
#pragma unroll
    for (int r = 0; r < 4; ++r)
      rwt[(lg * 4 + r) * 68 + jt * 16 + lr] = __float2bfloat16(a[r] * L2E);
  }
  float rwreg[8];
#pragma unroll
  for (int i = 0; i < 8; ++i) {
    int k = (i >> 2) * 16 + lg * 4 + (i & 3);
    rwreg[i] = __bfloat162float(rwt[lr * 68 + (wq_lane - k + 31)]);
  }

  f32x4 O[4] = {};
  float m_ = -1e30f, lsum = 0.f;
  const float C = 0.125f * L2E;
  char* pc = scratch[w];                   // P tile: [16 rows][8 slots x 16B] swizzled

  // DMA staging geometry: wave w stages K rows [16w,16w+16) and V rows same.
  int g_ = lane >> 3;                      // row-in-8
  int colb = ((lane & 7) ^ g_) * 8;        // pre-swizzled source col

  // ---- prologue: stage chunk 0 into buf 0, then full-drain barrier ----
#pragma unroll
  for (int i = 0; i < 2; ++i) {
    int op = 2 * w + i;                    // 0..7
    gload16(&Kb[(size_t)(op * 8 + g_) * 64 + colb], &Kl[0][op * 512]);
    gload16(&Vb[(size_t)(op * 8 + g_) * 1024 + colb], &Vl[0][op * 512]);
  }
  __syncthreads();                         // buf0 fully staged & visible

  int cur = 0;
#pragma unroll 1
  for (int kv0 = 0; kv0 < 1024; kv0 += 64) {
    // ---- issue next-chunk DMA into buf^1 (overlaps compute below) ----
    int nkv = (kv0 + 64 < 1024) ? kv0 + 64 : 960;  // last iter: dummy restage
#pragma unroll
    for (int i = 0; i < 2; ++i) {
      int op = 2 * w + i;
      gload16(&Kb[(size_t)(nkv + op * 8 + g_) * 64 + colb], &Kl[cur ^ 1][op * 512]);
      gload16(&Vb[(size_t)(op * 8 + g_) * 1024 + nkv + colb], &Vl[cur ^ 1][op * 512]);
    }

    const char* kc = (const char*)Kl[cur];
    const char* vc = (const char*)Vl[cur];
    // ---- K frags (swizzled ds_read_b128) ----
    short8 kf[8];
#pragma unroll
    for (int t = 0; t < 4; ++t)
#pragma unroll
      for (int h = 0; h < 2; ++h)
        kf[2 * t + h] = *(const short8*)(kc + (t * 16 + lr) * 128 + (((h * 4 + lg) ^ xr) * 16));
    // ---- QK^T (swapped): st[t][r] = S[kv=kv0+t*16+lg*4+r][q=q0+lr] ----
    f32x4 st[4];
#pragma unroll
    for (int t = 0; t < 4; ++t) {
      f32x4 z = {};
      z = __builtin_amdgcn_mfma_f32_16x16x32_bf16(kf[2 * t], qf0, z, 0, 0, 0);
      z = __builtin_amdgcn_mfma_f32_16x16x32_bf16(kf[2 * t + 1], qf1, z, 0, 0, 0);
      st[t] = z;
    }
    // ---- bias add (log2 domain) + in-lane max ----
    int kh = kv0 >> 5;
    float bh0 = __bfloat162float(rhw[lr * 36 + kh]);
    float bh1 = __bfloat162float(rhw[lr * 36 + kh + 1]);
    float mx = -1e30f;
#pragma unroll
    for (int t = 0; t < 4; ++t)
#pragma unroll
      for (int r = 0; r < 4; ++r) {
        float sv = fmaf(st[t][r], C, ((t < 2) ? bh0 : bh1) + rwreg[(t & 1) * 4 + r]);
        st[t][r] = sv;
        mx = fmaxf(mx, sv);
      }
    // ---- defer-max rescale (rare) ----
    if (!__all(mx <= m_ + 8.f)) {
      float mw = fmaxf(mx, __shfl_xor(mx, 16, 64));
      mw = fmaxf(mw, __shfl_xor(mw, 32, 64));
      float mnew = fmaxf(m_, mw);
      float al = exp2f(m_ - mnew);
      lsum *= al;
      m_ = mnew;
#pragma unroll
      for (int r = 0; r < 4; ++r) {
        float av = __shfl(al, lg * 4 + r, 64);
#pragma unroll
        for (int dt = 0; dt < 4; ++dt) O[dt][r] *= av;
      }
    }
    // ---- exp2 + per-lane partial sum + truncation-pack to swizzled P tile ----
    float sa = 0.f;
#pragma unroll
    for (int t = 0; t < 4; ++t) {
      float p0 = exp2f(st[t][0] - m_);
      float p1 = exp2f(st[t][1] - m_);
      float p2 = exp2f(st[t][2] - m_);
      float p3 = exp2f(st[t][3] - m_);
      sa += (p0 + p1) + (p2 + p3);
      uint2 wv;
      wv.x = packtrunc(p0, p1);
      wv.y = packtrunc(p2, p3);
      int slot = (2 * t + (lg >> 1)) ^ xr;
      *(uint2*)(pc + lr * 128 + slot * 16 + (lg & 1) * 8) = wv;
    }
    lsum += sa;
    // ---- P frags (same-wave DS ordering; no barrier needed) ----
    short8 pf0 = *(const short8*)(pc + lr * 128 + (((0 + lg) ^ xr) * 16));
    short8 pf1 = *(const short8*)(pc + lr * 128 + (((4 + lg) ^ xr) * 16));
    // ---- PV ----
#pragma unroll
    for (int dt = 0; dt < 4; ++dt) {
      short8 vf0 = *(const short8*)(vc + (dt * 16 + lr) * 128 + (((0 + lg) ^ xr) * 16));
      short8 vf1 = *(const short8*)(vc + (dt * 16 + lr) * 128 + (((4 + lg) ^ xr) * 16));
      O[dt] = __builtin_amdgcn_mfma_f32_16x16x32_bf16(pf0, vf0, O[dt], 0, 0, 0);
      O[dt] = __builtin_amdgcn_mfma_f32_16x16x32_bf16(pf1, vf1, O[dt], 0, 0, 0);
    }
    // ---- end-of-chunk: drain next-chunk DMA + execution barrier (safe 2-phase)
    __syncthreads();
    cur ^= 1;
  }

  // epilogue: reduce deferred l, then faithful out permutation (verified in R0)
  float lt = lsum;
  lt += __shfl_xor(lt, 16, 64);
  lt += __shfl_xor(lt, 32, 64);
  float linv = 1.f / lt;
#pragma unroll
  for (int r = 0; r < 4; ++r) {
    float lv = __shfl(linv, lg * 4 + r, 64);
    int n = q0 + lg * 4 + r;
#pragma unroll
    for (int dt = 0; dt < 4; ++dt) {
      int d = dt * 16 + lr;
      int Sidx = bh * 65536 + n * 64 + d;
      int b = Sidx / 786432, r1 = Sidx % 786432;
      int pp = r1 / 24576, r2 = r1 % 24576;
      int qq = r2 / 768, r3 = r2 % 768;
      int j = r3 >> 6, dd = r3 & 63;
      int P = b * 786432 + j * 65536 + pp * 2048 + qq * 64 + dd;
      outp[P] = __float2bfloat16(O[dt][r] * lv);
    }
  }
}

extern "C" void kernel_launch(void* const* d_in, const int* in_sizes, int n_in,
                              void* d_out, int out_size, void* d_ws, size_t ws_size,
                              hipStream_t stream) {
  const float* x     = (const float*)d_in[0];
  const float* Wqkv  = (const float*)d_in[1];
  const float* bqkv  = (const float*)d_in[2];
  const float* Wproj = (const float*)d_in[3];
  const float* bproj = (const float*)d_in[4];
  const float* rph   = (const float*)d_in[5];
  const float* rpw   = (const float*)d_in[6];
  float* out = (float*)d_out;
  char* ws = (char*)d_ws;

  __hip_bfloat16* xb     = (__hip_bfloat16*)(ws);
  __hip_bfloat16* wqkvT  = (__hip_bfloat16*)(ws + 12582912);
  __hip_bfloat16* wprojT = (__hip_bfloat16*)(ws + 16121856);
  __hip_bfloat16* qkvb   = (__hip_bfloat16*)(ws + 17301504);  // later aliased as attn-out
  __hip_bfloat16* Qm     = (__hip_bfloat16*)(ws + 55050240);
  __hip_bfloat16* Km     = (__hip_bfloat16*)(ws + 67633152);
  __hip_bfloat16* Vtm    = (__hip_bfloat16*)(ws + 80216064);

  cast_f32_bf16<<<dim3(6144), dim3(256), 0, stream>>>(x, xb);
  transpose_cast<<<dim3(72, 24), dim3(256), 0, stream>>>(Wqkv, wqkvT, 768, 2304);
  transpose_cast<<<dim3(24, 24), dim3(256), 0, stream>>>(Wproj, wprojT, 768, 768);
  gemm_dma<128, true><<<dim3(18, 64), dim3(256), 0, stream>>>(xb, wqkvT, bqkv, (void*)qkvb, 2304, 768);
  permute_v2<<<dim3(16, 96), dim3(256), 0, stream>>>(qkvb, Qm, Km, Vtm);
  attn8<<<dim3(1536), dim3(256), 0, stream>>>(Qm, Km, Vtm, rph, rpw, qkvb);
  gemm_dma<64, false><<<dim3(6, 128), dim3(256), 0, stream>>>(qkvb, wprojT, bproj, (void*)out, 768, 768);
}

// Round 11
// 183.298 us; speedup vs baseline: 1.7281x; 1.0061x over previous
//
#include <hip/hip_runtime.h>
#include <hip/hip_bf16.h>

// Shapes (fixed): B=8, H=W=32, E=768, nh=12, hd=64, N=1024, BH=96
// ws layout (bytes):
//   xb      @ 0          : 12,582,912  (x cast to bf16)
//   wqkvT   @ 12582912   :  3,538,944  (Wqkv^T bf16)
//   wprojT  @ 16121856   :  1,179,648  (Wproj^T bf16)
//   qkvb    @ 17301504   : 37,748,736  (qkv bf16; later aliased by attn-out bf16)
//   Q       @ 55050240   : 12,582,912
//   K       @ 67633152   : 12,582,912
//   Vt      @ 80216064   : 12,582,912  (V transposed: [bh][d][n])

typedef __attribute__((ext_vector_type(8))) short short8;
typedef __attribute__((ext_vector_type(4))) float f32x4;

__global__ __launch_bounds__(256) void cast_f32_bf16(const float* __restrict__ in,
                                                     __hip_bfloat16* __restrict__ out) {
  int i = (blockIdx.x * 256 + threadIdx.x) * 4;
  float4 v = *(const float4*)&in[i];
  out[i + 0] = __float2bfloat16(v.x);
  out[i + 1] = __float2bfloat16(v.y);
  out[i + 2] = __float2bfloat16(v.z);
  out[i + 3] = __float2bfloat16(v.w);
}

// in [K][N] f32 -> out [N][K] bf16
__global__ __launch_bounds__(256) void transpose_cast(const float* __restrict__ in,
                                                      __hip_bfloat16* __restrict__ out,
                                                      int K, int N) {
  __shared__ float tile[32][33];
  int n0 = blockIdx.x * 32, k0 = blockIdx.y * 32;
  int tx = threadIdx.x & 31, ty = threadIdx.x >> 5;  // 32 x 8
#pragma unroll
  for (int i = 0; i < 4; ++i)
    tile[ty + i * 8][tx] = in[(size_t)(k0 + ty + i * 8) * N + n0 + tx];
  __syncthreads();
#pragma unroll
  for (int i = 0; i < 4; ++i)
    out[(size_t)(n0 + ty + i * 8) * K + k0 + tx] = __float2bfloat16(tile[tx][ty + i * 8]);
}

__device__ inline void gload16(const void* g, void* l) {
  __builtin_amdgcn_global_load_lds((const __attribute__((address_space(1))) void*)g,
                                   (__attribute__((address_space(3))) void*)l, 16, 0, 0);
}

// C[M,N] = A[M,K]*Bt[N,K]^T + bias ; BMx128 tile (BM=128 or 64), 4 waves (2x2),
// BK=64, staging via global_load_lds width=16 into linear LDS (m97 structure).
template<int BM, bool OUT_BF16>
__global__ __launch_bounds__(256) void gemm_dma(const __hip_bfloat16* __restrict__ A,
                                                const __hip_bfloat16* __restrict__ Bt,
                                                const float* __restrict__ bias,
                                                void* __restrict__ Cout,
                                                int N, int K) {
  constexpr int FM = BM / 32;               // m-frags per wave (4 or 2)
  __shared__ __hip_bfloat16 Al[BM * 64];
  __shared__ __hip_bfloat16 Bl[128 * 64];
  int n0 = blockIdx.x * 128, m0 = blockIdx.y * BM;
  int tid = threadIdx.x, lane = tid & 63, wid = tid >> 6;
  int wm = wid >> 1, wn = wid & 1;
  int lr = lane & 15, lg = lane >> 4;
  int row_l = lane >> 3, col8 = (lane & 7) * 8;
  f32x4 acc[FM][4] = {};
  for (int k0 = 0; k0 < K; k0 += 64) {
#pragma unroll
    for (int j = 0; j < BM / 32; ++j) {     // A: BM*8/64 chunks over 4 waves
      int jj = wid * (BM / 32) + j;
      int arow = jj * 8 + row_l;
      gload16(&A[(size_t)(m0 + arow) * K + k0 + col8], &Al[jj * 512]);
    }
#pragma unroll
    for (int j = 0; j < 4; ++j) {           // B: 16 chunks over 4 waves
      int jj = wid * 4 + j;
      int brow = jj * 8 + row_l;
      gload16(&Bt[(size_t)(n0 + brow) * K + k0 + col8], &Bl[jj * 512]);
    }
    __syncthreads();  // drains vmcnt (DMA writes) per compiler barrier semantics
#pragma unroll
    for (int ks = 0; ks < 2; ++ks) {
      short8 af[FM], bfr[4];
#pragma unroll
      for (int m = 0; m < FM; ++m)
        af[m] = *(const short8*)&Al[(wm * (BM / 2) + m * 16 + lr) * 64 + ks * 32 + lg * 8];
#pragma unroll
      for (int n = 0; n < 4; ++n)
        bfr[n] = *(const short8*)&Bl[(wn * 64 + n * 16 + lr) * 64 + ks * 32 + lg * 8];
#pragma unroll
      for (int m = 0; m < FM; ++m)
#pragma unroll
        for (int n = 0; n < 4; ++n)
          acc[m][n] = __builtin_amdgcn_mfma_f32_16x16x32_bf16(af[m], bfr[n], acc[m][n], 0, 0, 0);
    }
    __syncthreads();
  }
#pragma unroll
  for (int n = 0; n < 4; ++n) {
    int col = n0 + wn * 64 + n * 16 + lr;
    float bv = bias[col];
#pragma unroll
    for (int m = 0; m < FM; ++m) {
      int rowb = m0 + wm * (BM / 2) + m * 16 + lg * 4;
#pragma unroll
      for (int r = 0; r < 4; ++r) {
        float v = acc[m][n][r] + bv;
        if (OUT_BF16)
          ((__hip_bfloat16*)Cout)[(size_t)(rowb + r) * N + col] = __float2bfloat16(v);
        else
          ((float*)Cout)[(size_t)(rowb + r) * N + col] = v;
      }
    }
  }
}

// permute_qkv v2 (verified R8): per dest (bh,n2) the CONTIGUOUS source window
// qkv_flat[(bh*1024+n2)*192 .. +192) with fixed intra-window permutation
// src_off(u) = (u&63)*3 + (u>>6), u = d2*3 + c2.
__global__ __launch_bounds__(256) void permute_v2(const __hip_bfloat16* __restrict__ qkv,
                                                  __hip_bfloat16* __restrict__ Q,
                                                  __hip_bfloat16* __restrict__ Kd,
                                                  __hip_bfloat16* __restrict__ Vt) {
  int bh = blockIdx.y, n0 = blockIdx.x * 64;
  int tid = threadIdx.x;
  __shared__ short raw[64 * 200];     // window wi stride 200 (pad)
  __shared__ short vt[64][72];
  const short* src = (const short*)qkv + (size_t)(bh * 1024 + n0) * 192;
#pragma unroll
  for (int i = 0; i < 6; ++i) {
    int c16 = tid + i * 256;          // 0..1535
    int wi = c16 / 24, off = (c16 % 24) * 8;
    *(short8*)&raw[wi * 200 + off] = *(const short8*)&src[(size_t)c16 * 8];
  }
  __syncthreads();
  int wi = tid >> 2, g4 = tid & 3;
  const short* rw_ = &raw[wi * 200];
  short8 qv[2], kv_[2];
#pragma unroll
  for (int half = 0; half < 2; ++half)
#pragma unroll
    for (int j = 0; j < 8; ++j) {
      int d2 = g4 * 16 + half * 8 + j;
      int u = 3 * d2;
      qv[half][j]  = rw_[((u) & 63) * 3 + ((u) >> 6)];
      kv_[half][j] = rw_[((u + 1) & 63) * 3 + ((u + 1) >> 6)];
      vt[d2][wi]   = rw_[((u + 2) & 63) * 3 + ((u + 2) >> 6)];
    }
  size_t base = (size_t)bh * 65536 + (size_t)(n0 + wi) * 64 + g4 * 16;
  *(short8*)&Q[base] = qv[0];
  *(short8*)&Q[base + 8] = qv[1];
  *(short8*)&Kd[base] = kv_[0];
  *(short8*)&Kd[base + 8] = kv_[1];
  __syncthreads();
  int d2r = tid >> 2;
  size_t vbase = (size_t)bh * 65536 + (size_t)d2r * 1024 + n0 + g4 * 16;
  *(short8*)&Vt[vbase]     = *(const short8*)&vt[d2r][g4 * 16];
  *(short8*)&Vt[vbase + 8] = *(const short8*)&vt[d2r][g4 * 16 + 8];
}

__device__ inline short8 cvt8(const float* p) {
  short8 r;
#pragma unroll
  for (int j = 0; j < 8; ++j) {
    __hip_bfloat16 b = __float2bfloat16(p[j]);
    r[j] = *reinterpret_cast<const short*>(&b);
  }
  return r;
}

// truncation pack: [b_hi16 | a_hi16] in one v_perm_b32 (valid: P>=0, no NaN).
__device__ inline unsigned packtrunc(float a, float b) {
  return __builtin_amdgcn_perm(__float_as_uint(b), __float_as_uint(a), 0x07060302u);
}

// Flash attention v9: 4 waves/block, 32 q-rows/wave (block = 128 q-rows),
// grid 768 = exactly 3 blocks/CU resident, one round, no tail.
// Shared K/V LDS DMA staging, safe 2-phase double buffer; per-chunk fixed
// overhead (kf/vf reads, DMA issue, loop) amortized over 2x q-rows.
// XOR-swizzled LDS; defer-max + defer-sum; exp2 domain; truncation P pack.
#define L2E 1.44269504088896f
__global__ __launch_bounds__(256) void attn9(const __hip_bfloat16* __restrict__ Q,
                                             const __hip_bfloat16* __restrict__ Kd,
                                             const __hip_bfloat16* __restrict__ Vt,
                                             const float* __restrict__ rph,
                                             const float* __restrict__ rpw,
                                             __hip_bfloat16* __restrict__ outp) {
  int orig = blockIdx.x;                   // 768 = 8 xcd * 96
  int xcd = orig & 7, loc = orig >> 3;     // 96 per xcd
  int bh = xcd * 12 + (loc % 12);
  int qt = loc / 12;                       // 0..7 (128-row q tile)
  int tid = threadIdx.x;
  int lane = tid & 63, w = tid >> 6;
  int lr = lane & 15, lg = lane >> 4;
  int xr = lr & 7;

  __shared__ __hip_bfloat16 Kl[2][4096];   // [buf][64 rows][8 slots x 16B] swizzled
  __shared__ __hip_bfloat16 Vl[2][4096];
  __shared__ __hip_bfloat16 rh_b[4][32 * 36];     // per-wave rh[32][36] bf16
  __shared__ __align__(16) char scratch[4][2304]; // per-wave P tile

  const __hip_bfloat16* Qb = Q + (size_t)bh * 65536;
  const __hip_bfloat16* Kb = Kd + (size_t)bh * 65536;
  const __hip_bfloat16* Vb = Vt + (size_t)bh * 65536;

  int q0 = qt * 128 + w * 32;              // this wave's 32 q-rows (mult of 32)
  int hq = q0 >> 5;                        // constant per wave

  short8 qf[2][2];
#pragma unroll
  for (int qh = 0; qh < 2; ++qh) {
    qf[qh][0] = *(const short8*)&Qb[(size_t)(q0 + qh * 16 + lr) * 64 + lg * 8];
    qf[qh][1] = *(const short8*)&Qb[(size_t)(q0 + qh * 16 + lr) * 64 + 32 + lg * 8];
  }

  // ---- rel-pos bias via MFMA (pre-scaled by L2E), per-wave private LDS ----
  __hip_bfloat16* rhw = rh_b[w];
#pragma unroll
  for (int kt = 0; kt < 2; ++kt) {
    int row = hq - (kt * 16 + lr) + 31;    // 0..62
    const float* tp = rph + (size_t)row * 64 + lg * 8;
    short8 th0 = cvt8(tp), th1 = cvt8(tp + 32);
#pragma unroll
    for (int qh = 0; qh < 2; ++qh) {
      f32x4 a = {};
      a = __builtin_amdgcn_mfma_f32_16x16x32_bf16(qf[qh][0], th0, a, 0, 0, 0);
      a = __builtin_amdgcn_mfma_f32_16x16x32_bf16(qf[qh][1], th1, a, 0, 0, 0);
#pragma unroll
      for (int r = 0; r < 4; ++r)
        rhw[(qh * 16 + lg * 4 + r) * 36 + kt * 16 + lr] = __float2bfloat16(a[r] * L2E);
    }
  }
  // rw staging in the (still dead) K/V buffers: waves 0-1 -> Kl, 2-3 -> Vl
  __hip_bfloat16* rwt = (w < 2) ? ((__hip_bfloat16*)Kl + w * 2176)
                                : ((__hip_bfloat16*)Vl + (w - 2) * 2176);
#pragma unroll
  for (int jt = 0; jt < 4; ++jt) {
    const float* tp = rpw + (size_t)(jt * 16 + lr) * 64 + lg * 8;
    short8 tw0 = cvt8(tp), tw1 = cvt8(tp + 32);
#pragma unroll
    for (int qh = 0; qh < 2; ++qh) {
      f32x4 a = {};
      a = __builtin_amdgcn_mfma_f32_16x16x32_bf16(qf[qh][0], tw0, a, 0, 0, 0);
      a = __builtin_amdgcn_mfma_f32_16x16x32_bf16(qf[qh][1], tw1, a, 0, 0, 0);
#pragma unroll
      for (int r = 0; r < 4; ++r)
        rwt[(qh * 16 + lg * 4 + r) * 68 + jt * 16 + lr] = __float2bfloat16(a[r] * L2E);
    }
  }
  float rwreg[2][8];
#pragma unroll
  for (int qh = 0; qh < 2; ++qh) {
    int wq = qh * 16 + lr;                 // (q0 + qh*16 + lr) & 31
#pragma unroll
    for (int i = 0; i < 8; ++i) {
      int k = (i >> 2) * 16 + lg * 4 + (i & 3);
      rwreg[qh][i] = __bfloat162float(rwt[(qh * 16 + lr) * 68 + (wq - k + 31)]);
    }
  }
  __syncthreads();                         // all rw reads done before DMA overwrites Kl/Vl

  f32x4 O[2][4] = {};
  float m_[2] = {-1e30f, -1e30f};
  float lsum[2] = {0.f, 0.f};
  const float C = 0.125f * L2E;
  char* pc = scratch[w];                   // P tile: [16 rows][8 slots x 16B] swizzled

  // DMA staging geometry: wave w stages K rows [16w,16w+16) and V rows same.
  int g_ = lane >> 3;                      // row-in-8
  int colb = ((lane & 7) ^ g_) * 8;        // pre-swizzled source col

  // ---- prologue: stage chunk 0 into buf 0, then full-drain barrier ----
#pragma unroll
  for (int i = 0; i < 2; ++i) {
    int op = 2 * w + i;                    // 0..7
    gload16(&Kb[(size_t)(op * 8 + g_) * 64 + colb], &Kl[0][op * 512]);
    gload16(&Vb[(size_t)(op * 8 + g_) * 1024 + colb], &Vl[0][op * 512]);
  }
  __syncthreads();                         // buf0 fully staged & visible

  int cur = 0;
#pragma unroll 1
  for (int kv0 = 0; kv0 < 1024; kv0 += 64) {
    // ---- issue next-chunk DMA into buf^1 (overlaps compute below) ----
    int nkv = (kv0 + 64 < 1024) ? kv0 + 64 : 960;  // last iter: dummy restage
#pragma unroll
    for (int i = 0; i < 2; ++i) {
      int op = 2 * w + i;
      gload16(&Kb[(size_t)(nkv + op * 8 + g_) * 64 + colb], &Kl[cur ^ 1][op * 512]);
      gload16(&Vb[(size_t)(op * 8 + g_) * 1024 + nkv + colb], &Vl[cur ^ 1][op * 512]);
    }

    const char* kc = (const char*)Kl[cur];
    const char* vc = (const char*)Vl[cur];
    // ---- K frags (swizzled ds_read_b128), shared by both q-halves ----
    short8 kf[8];
#pragma unroll
    for (int t = 0; t < 4; ++t)
#pragma unroll
      for (int h = 0; h < 2; ++h)
        kf[2 * t + h] = *(const short8*)(kc + (t * 16 + lr) * 128 + (((h * 4 + lg) ^ xr) * 16));
    // ---- QK^T (swapped): st[qh][t][r] = S[kv0+t*16+lg*4+r][q0+qh*16+lr] ----
    f32x4 st[2][4];
#pragma unroll
    for (int t = 0; t < 4; ++t)
#pragma unroll
      for (int qh = 0; qh < 2; ++qh) {
        f32x4 z = {};
        z = __builtin_amdgcn_mfma_f32_16x16x32_bf16(kf[2 * t], qf[qh][0], z, 0, 0, 0);
        z = __builtin_amdgcn_mfma_f32_16x16x32_bf16(kf[2 * t + 1], qf[qh][1], z, 0, 0, 0);
        st[qh][t] = z;
      }
    // ---- bias add (log2 domain) + in-lane max ----
    int kh = kv0 >> 5;
    float mxl[2];
#pragma unroll
    for (int qh = 0; qh < 2; ++qh) {
      float bh0 = __bfloat162float(rhw[(qh * 16 + lr) * 36 + kh]);
      float bh1 = __bfloat162float(rhw[(qh * 16 + lr) * 36 + kh + 1]);
      float mx = -1e30f;
#pragma unroll
      for (int t = 0; t < 4; ++t)
#pragma unroll
        for (int r = 0; r < 4; ++r) {
          float sv = fmaf(st[qh][t][r], C, ((t < 2) ? bh0 : bh1) + rwreg[qh][(t & 1) * 4 + r]);
          st[qh][t][r] = sv;
          mx = fmaxf(mx, sv);
        }
      mxl[qh] = mx;
    }
    // ---- defer-max rescale (rare) ----
    int cond = (mxl[0] <= m_[0] + 8.f) && (mxl[1] <= m_[1] + 8.f);
    if (!__all(cond)) {
#pragma unroll
      for (int qh = 0; qh < 2; ++qh) {
        float mw = fmaxf(mxl[qh], __shfl_xor(mxl[qh], 16, 64));
        mw = fmaxf(mw, __shfl_xor(mw, 32, 64));
        float mnew = fmaxf(m_[qh], mw);
        float al = exp2f(m_[qh] - mnew);
        lsum[qh] *= al;
        m_[qh] = mnew;
#pragma unroll
        for (int r = 0; r < 4; ++r) {
          float av = __shfl(al, lg * 4 + r, 64);
#pragma unroll
          for (int dt = 0; dt < 4; ++dt) O[qh][dt][r] *= av;
        }
      }
    }
    // ---- exp2 + per-lane partial sum + truncation-pack; P tile reused per qh
    short8 pf[2][2];
#pragma unroll
    for (int qh = 0; qh < 2; ++qh) {
      float mq = m_[qh];
      float sa = 0.f;
#pragma unroll
      for (int t = 0; t < 4; ++t) {
        float p0 = exp2f(st[qh][t][0] - mq);
        float p1 = exp2f(st[qh][t][1] - mq);
        float p2 = exp2f(st[qh][t][2] - mq);
        float p3 = exp2f(st[qh][t][3] - mq);
        sa += (p0 + p1) + (p2 + p3);
        uint2 wv;
        wv.x = packtrunc(p0, p1);
        wv.y = packtrunc(p2, p3);
        int slot = (2 * t + (lg >> 1)) ^ xr;
        *(uint2*)(pc + lr * 128 + slot * 16 + (lg & 1) * 8) = wv;
      }
      lsum[qh] += sa;
      // read this half's P A-frags before overwriting the tile (same-wave DS order)
      pf[qh][0] = *(const short8*)(pc + lr * 128 + (((0 + lg) ^ xr) * 16));
      pf[qh][1] = *(const short8*)(pc + lr * 128 + (((4 + lg) ^ xr) * 16));
    }
    // ---- PV: vf reads shared by both q-halves ----
#pragma unroll
    for (int dt = 0; dt < 4; ++dt) {
      short8 vf0 = *(const short8*)(vc + (dt * 16 + lr) * 128 + (((0 + lg) ^ xr) * 16));
      short8 vf1 = *(const short8*)(vc + (dt * 16 + lr) * 128 + (((4 + lg) ^ xr) * 16));
#pragma unroll
      for (int qh = 0; qh < 2; ++qh) {
        O[qh][dt] = __builtin_amdgcn_mfma_f32_16x16x32_bf16(pf[qh][0], vf0, O[qh][dt], 0, 0, 0);
        O[qh][dt] = __builtin_amdgcn_mfma_f32_16x16x32_bf16(pf[qh][1], vf1, O[qh][dt], 0, 0, 0);
      }
    }
    // ---- end-of-chunk: drain next-chunk DMA + execution barrier (safe 2-phase)
    __syncthreads();
    cur ^= 1;
  }

  // epilogue: reduce deferred l, then faithful out permutation (verified in R0)
#pragma unroll
  for (int qh = 0; qh < 2; ++qh) {
    float lt = lsum[qh];
    lt += __shfl_xor(lt, 16, 64);
    lt += __shfl_xor(lt, 32, 64);
    float linv = 1.f / lt;
#pragma unroll
    for (int r = 0; r < 4; ++r) {
      float lv = __shfl(linv, lg * 4 + r, 64);
      int n = q0 + qh * 16 + lg * 4 + r;
#pragma unroll
      for (int dt = 0; dt < 4; ++dt) {
        int d = dt * 16 + lr;
        int Sidx = bh * 65536 + n * 64 + d;
        int b = Sidx / 786432, r1 = Sidx % 786432;
        int pp = r1 / 24576, r2 = r1 % 24576;
        int qq = r2 / 768, r3 = r2 % 768;
        int j = r3 >> 6, dd = r3 & 63;
        int P = b * 786432 + j * 65536 + pp * 2048 + qq * 64 + dd;
        outp[P] = __float2bfloat16(O[qh][dt][r] * lv);
      }
    }
  }
}

extern "C" void kernel_launch(void* const* d_in, const int* in_sizes, int n_in,
                              void* d_out, int out_size, void* d_ws, size_t ws_size,
                              hipStream_t stream) {
  const float* x     = (const float*)d_in[0];
  const float* Wqkv  = (const float*)d_in[1];
  const float* bqkv  = (const float*)d_in[2];
  const float* Wproj = (const float*)d_in[3];
  const float* bproj = (const float*)d_in[4];
  const float* rph   = (const float*)d_in[5];
  const float* rpw   = (const float*)d_in[6];
  float* out = (float*)d_out;
  char* ws = (char*)d_ws;

  __hip_bfloat16* xb     = (__hip_bfloat16*)(ws);
  __hip_bfloat16* wqkvT  = (__hip_bfloat16*)(ws + 12582912);
  __hip_bfloat16* wprojT = (__hip_bfloat16*)(ws + 16121856);
  __hip_bfloat16* qkvb   = (__hip_bfloat16*)(ws + 17301504);  // later aliased as attn-out
  __hip_bfloat16* Qm     = (__hip_bfloat16*)(ws + 55050240);
  __hip_bfloat16* Km     = (__hip_bfloat16*)(ws + 67633152);
  __hip_bfloat16* Vtm    = (__hip_bfloat16*)(ws + 80216064);

  cast_f32_bf16<<<dim3(6144), dim3(256), 0, stream>>>(x, xb);
  transpose_cast<<<dim3(72, 24), dim3(256), 0, stream>>>(Wqkv, wqkvT, 768, 2304);
  transpose_cast<<<dim3(24, 24), dim3(256), 0, stream>>>(Wproj, wprojT, 768, 768);
  gemm_dma<128, true><<<dim3(18, 64), dim3(256), 0, stream>>>(xb, wqkvT, bqkv, (void*)qkvb, 2304, 768);
  permute_v2<<<dim3(16, 96), dim3(256), 0, stream>>>(qkvb, Qm, Km, Vtm);
  attn9<<<dim3(768), dim3(256), 0, stream>>>(Qm, Km, Vtm, rph, rpw, qkvb);
  gemm_dma<64, false><<<dim3(6, 128), dim3(256), 0, stream>>>(qkvb, wprojT, bproj, (void*)out, 768, 768);
}

// Round 12
// 182.077 us; speedup vs baseline: 1.7397x; 1.0067x over previous
//
#include <hip/hip_runtime.h>
#include <hip/hip_bf16.h>

// Shapes (fixed): B=8, H=W=32, E=768, nh=12, hd=64, N=1024, BH=96
// ws layout (bytes):
//   xb      @ 0          : 12,582,912  (x cast to bf16)
//   wqkvT   @ 12582912   :  3,538,944  (Wqkv^T bf16)
//   wprojT  @ 16121856   :  1,179,648  (Wproj^T bf16)
//   qkvb    @ 17301504   : 37,748,736  (qkv bf16; later aliased by attn-out bf16)
//   Q       @ 55050240   : 12,582,912
//   K       @ 67633152   : 12,582,912
//   Vt      @ 80216064   : 12,582,912  (V transposed: [bh][d][n])

typedef __attribute__((ext_vector_type(8))) short short8;
typedef __attribute__((ext_vector_type(4))) float f32x4;

__global__ __launch_bounds__(256) void cast_f32_bf16(const float* __restrict__ in,
                                                     __hip_bfloat16* __restrict__ out) {
  int i = (blockIdx.x * 256 + threadIdx.x) * 4;
  float4 v = *(const float4*)&in[i];
  out[i + 0] = __float2bfloat16(v.x);
  out[i + 1] = __float2bfloat16(v.y);
  out[i + 2] = __float2bfloat16(v.z);
  out[i + 3] = __float2bfloat16(v.w);
}

// in [K][N] f32 -> out [N][K] bf16
__global__ __launch_bounds__(256) void transpose_cast(const float* __restrict__ in,
                                                      __hip_bfloat16* __restrict__ out,
                                                      int K, int N) {
  __shared__ float tile[32][33];
  int n0 = blockIdx.x * 32, k0 = blockIdx.y * 32;
  int tx = threadIdx.x & 31, ty = threadIdx.x >> 5;  // 32 x 8
#pragma unroll
  for (int i = 0; i < 4; ++i)
    tile[ty + i * 8][tx] = in[(size_t)(k0 + ty + i * 8) * N + n0 + tx];
  __syncthreads();
#pragma unroll
  for (int i = 0; i < 4; ++i)
    out[(size_t)(n0 + ty + i * 8) * K + k0 + tx] = __float2bfloat16(tile[tx][ty + i * 8]);
}

__device__ inline void gload16(const void* g, void* l) {
  __builtin_amdgcn_global_load_lds((const __attribute__((address_space(1))) void*)g,
                                   (__attribute__((address_space(3))) void*)l, 16, 0, 0);
}

// C[M,N] = A[M,K]*Bt[N,K]^T + bias ; BMx128 tile (BM=128 or 64), 4 waves (2x2),
// BK=64, staging via global_load_lds width=16 into linear LDS (m97 structure).
template<int BM, bool OUT_BF16>
__global__ __launch_bounds__(256) void gemm_dma(const __hip_bfloat16* __restrict__ A,
                                                const __hip_bfloat16* __restrict__ Bt,
                                                const float* __restrict__ bias,
                                                void* __restrict__ Cout,
                                                int N, int K) {
  constexpr int FM = BM / 32;               // m-frags per wave (4 or 2)
  __shared__ __hip_bfloat16 Al[BM * 64];
  __shared__ __hip_bfloat16 Bl[128 * 64];
  int n0 = blockIdx.x * 128, m0 = blockIdx.y * BM;
  int tid = threadIdx.x, lane = tid & 63, wid = tid >> 6;
  int wm = wid >> 1, wn = wid & 1;
  int lr = lane & 15, lg = lane >> 4;
  int row_l = lane >> 3, col8 = (lane & 7) * 8;
  f32x4 acc[FM][4] = {};
  for (int k0 = 0; k0 < K; k0 += 64) {
#pragma unroll
    for (int j = 0; j < BM / 32; ++j) {     // A: BM*8/64 chunks over 4 waves
      int jj = wid * (BM / 32) + j;
      int arow = jj * 8 + row_l;
      gload16(&A[(size_t)(m0 + arow) * K + k0 + col8], &Al[jj * 512]);
    }
#pragma unroll
    for (int j = 0; j < 4; ++j) {           // B: 16 chunks over 4 waves
      int jj = wid * 4 + j;
      int brow = jj * 8 + row_l;
      gload16(&Bt[(size_t)(n0 + brow) * K + k0 + col8], &Bl[jj * 512]);
    }
    __syncthreads();  // drains vmcnt (DMA writes) per compiler barrier semantics
#pragma unroll
    for (int ks = 0; ks < 2; ++ks) {
      short8 af[FM], bfr[4];
#pragma unroll
      for (int m = 0; m < FM; ++m)
        af[m] = *(const short8*)&Al[(wm * (BM / 2) + m * 16 + lr) * 64 + ks * 32 + lg * 8];
#pragma unroll
      for (int n = 0; n < 4; ++n)
        bfr[n] = *(const short8*)&Bl[(wn * 64 + n * 16 + lr) * 64 + ks * 32 + lg * 8];
#pragma unroll
      for (int m = 0; m < FM; ++m)
#pragma unroll
        for (int n = 0; n < 4; ++n)
          acc[m][n] = __builtin_amdgcn_mfma_f32_16x16x32_bf16(af[m], bfr[n], acc[m][n], 0, 0, 0);
    }
    __syncthreads();
  }
#pragma unroll
  for (int n = 0; n < 4; ++n) {
    int col = n0 + wn * 64 + n * 16 + lr;
    float bv = bias[col];
#pragma unroll
    for (int m = 0; m < FM; ++m) {
      int rowb = m0 + wm * (BM / 2) + m * 16 + lg * 4;
#pragma unroll
      for (int r = 0; r < 4; ++r) {
        float v = acc[m][n][r] + bv;
        if (OUT_BF16)
          ((__hip_bfloat16*)Cout)[(size_t)(rowb + r) * N + col] = __float2bfloat16(v);
        else
          ((float*)Cout)[(size_t)(rowb + r) * N + col] = v;
      }
    }
  }
}

// permute_qkv v2 (verified R8): per dest (bh,n2) the CONTIGUOUS source window
// qkv_flat[(bh*1024+n2)*192 .. +192) with fixed intra-window permutation
// src_off(u) = (u&63)*3 + (u>>6), u = d2*3 + c2.
__global__ __launch_bounds__(256) void permute_v2(const __hip_bfloat16* __restrict__ qkv,
                                                  __hip_bfloat16* __restrict__ Q,
                                                  __hip_bfloat16* __restrict__ Kd,
                                                  __hip_bfloat16* __restrict__ Vt) {
  int bh = blockIdx.y, n0 = blockIdx.x * 64;
  int tid = threadIdx.x;
  __shared__ short raw[64 * 200];     // window wi stride 200 (pad)
  __shared__ short vt[64][72];
  const short* src = (const short*)qkv + (size_t)(bh * 1024 + n0) * 192;
#pragma unroll
  for (int i = 0; i < 6; ++i) {
    int c16 = tid + i * 256;          // 0..1535
    int wi = c16 / 24, off = (c16 % 24) * 8;
    *(short8*)&raw[wi * 200 + off] = *(const short8*)&src[(size_t)c16 * 8];
  }
  __syncthreads();
  int wi = tid >> 2, g4 = tid & 3;
  const short* rw_ = &raw[wi * 200];
  short8 qv[2], kv_[2];
#pragma unroll
  for (int half = 0; half < 2; ++half)
#pragma unroll
    for (int j = 0; j < 8; ++j) {
      int d2 = g4 * 16 + half * 8 + j;
      int u = 3 * d2;
      qv[half][j]  = rw_[((u) & 63) * 3 + ((u) >> 6)];
      kv_[half][j] = rw_[((u + 1) & 63) * 3 + ((u + 1) >> 6)];
      vt[d2][wi]   = rw_[((u + 2) & 63) * 3 + ((u + 2) >> 6)];
    }
  size_t base = (size_t)bh * 65536 + (size_t)(n0 + wi) * 64 + g4 * 16;
  *(short8*)&Q[base] = qv[0];
  *(short8*)&Q[base + 8] = qv[1];
  *(short8*)&Kd[base] = kv_[0];
  *(short8*)&Kd[base + 8] = kv_[1];
  __syncthreads();
  int d2r = tid >> 2;
  size_t vbase = (size_t)bh * 65536 + (size_t)d2r * 1024 + n0 + g4 * 16;
  *(short8*)&Vt[vbase]     = *(const short8*)&vt[d2r][g4 * 16];
  *(short8*)&Vt[vbase + 8] = *(const short8*)&vt[d2r][g4 * 16 + 8];
}

__device__ inline short8 cvt8(const float* p) {
  short8 r;
#pragma unroll
  for (int j = 0; j < 8; ++j) {
    __hip_bfloat16 b = __float2bfloat16(p[j]);
    r[j] = *reinterpret_cast<const short*>(&b);
  }
  return r;
}

// truncation pack: [b_hi16 | a_hi16] in one v_perm_b32 (valid: P>=0, no NaN).
__device__ inline unsigned packtrunc(float a, float b) {
  return __builtin_amdgcn_perm(__float_as_uint(b), __float_as_uint(a), 0x07060302u);
}

// Flash attention v10: attn9 geometry (4 waves/block, 32 q-rows/wave, grid 768)
// + counted-vmcnt double buffer (T3/T4): loads stay in flight ACROSS barriers.
// Per chunk: {barrier A -> issue 4 DMA into buf^1 -> vmcnt(4) -> barrier B ->
// compute buf[cur]}. vmcnt(4) retires the OLDER chunk's DMA only; no vmcnt(0)
// drain anywhere in the loop. XOR-swizzled LDS; defer-max/sum; exp2 domain.
#define L2E 1.44269504088896f
__global__ __launch_bounds__(256) void attn10(const __hip_bfloat16* __restrict__ Q,
                                              const __hip_bfloat16* __restrict__ Kd,
                                              const __hip_bfloat16* __restrict__ Vt,
                                              const float* __restrict__ rph,
                                              const float* __restrict__ rpw,
                                              __hip_bfloat16* __restrict__ outp) {
  int orig = blockIdx.x;                   // 768 = 8 xcd * 96
  int xcd = orig & 7, loc = orig >> 3;     // 96 per xcd
  int bh = xcd * 12 + (loc % 12);
  int qt = loc / 12;                       // 0..7 (128-row q tile)
  int tid = threadIdx.x;
  int lane = tid & 63, w = tid >> 6;
  int lr = lane & 15, lg = lane >> 4;
  int xr = lr & 7;

  __shared__ __hip_bfloat16 Kl[2][4096];   // [buf][64 rows][8 slots x 16B] swizzled
  __shared__ __hip_bfloat16 Vl[2][4096];
  __shared__ __hip_bfloat16 rh_b[4][32 * 36];     // per-wave rh[32][36] bf16
  __shared__ __align__(16) char scratch[4][2304]; // per-wave P tile

  const __hip_bfloat16* Qb = Q + (size_t)bh * 65536;
  const __hip_bfloat16* Kb = Kd + (size_t)bh * 65536;
  const __hip_bfloat16* Vb = Vt + (size_t)bh * 65536;

  int q0 = qt * 128 + w * 32;              // this wave's 32 q-rows (mult of 32)
  int hq = q0 >> 5;                        // constant per wave

  short8 qf[2][2];
#pragma unroll
  for (int qh = 0; qh < 2; ++qh) {
    qf[qh][0] = *(const short8*)&Qb[(size_t)(q0 + qh * 16 + lr) * 64 + lg * 8];
    qf[qh][1] = *(const short8*)&Qb[(size_t)(q0 + qh * 16 + lr) * 64 + 32 + lg * 8];
  }

  // ---- rel-pos bias via MFMA (pre-scaled by L2E), per-wave private LDS ----
  __hip_bfloat16* rhw = rh_b[w];
#pragma unroll
  for (int kt = 0; kt < 2; ++kt) {
    int row = hq - (kt * 16 + lr) + 31;    // 0..62
    const float* tp = rph + (size_t)row * 64 + lg * 8;
    short8 th0 = cvt8(tp), th1 = cvt8(tp + 32);
#pragma unroll
    for (int qh = 0; qh < 2; ++qh) {
      f32x4 a = {};
      a = __builtin_amdgcn_mfma_f32_16x16x32_bf16(qf[qh][0], th0, a, 0, 0, 0);
      a = __builtin_amdgcn_mfma_f32_16x16x32_bf16(qf[qh][1], th1, a, 0, 0, 0);
#pragma unroll
      for (int r = 0; r < 4; ++r)
        rhw[(qh * 16 + lg * 4 + r) * 36 + kt * 16 + lr] = __float2bfloat16(a[r] * L2E);
    }
  }
  // rw staging in the (still dead) K/V buffers: waves 0-1 -> Kl, 2-3 -> Vl
  __hip_bfloat16* rwt = (w < 2) ? ((__hip_bfloat16*)Kl + w * 2176)
                                : ((__hip_bfloat16*)Vl + (w - 2) * 2176);
#pragma unroll
  for (int jt = 0; jt < 4; ++jt) {
    const float* tp = rpw + (size_t)(jt * 16 + lr) * 64 + lg * 8;
    short8 tw0 = cvt8(tp), tw1 = cvt8(tp + 32);
#pragma unroll
    for (int qh = 0; qh < 2; ++qh) {
      f32x4 a = {};
      a = __builtin_amdgcn_mfma_f32_16x16x32_bf16(qf[qh][0], tw0, a, 0, 0, 0);
      a = __builtin_amdgcn_mfma_f32_16x16x32_bf16(qf[qh][1], tw1, a, 0, 0, 0);
#pragma unroll
      for (int r = 0; r < 4; ++r)
        rwt[(qh * 16 + lg * 4 + r) * 68 + jt * 16 + lr] = __float2bfloat16(a[r] * L2E);
    }
  }
  float rwreg[2][8];
#pragma unroll
  for (int qh = 0; qh < 2; ++qh) {
    int wq = qh * 16 + lr;                 // (q0 + qh*16 + lr) & 31
#pragma unroll
    for (int i = 0; i < 8; ++i) {
      int k = (i >> 2) * 16 + lg * 4 + (i & 3);
      rwreg[qh][i] = __bfloat162float(rwt[(qh * 16 + lr) * 68 + (wq - k + 31)]);
    }
  }
  __syncthreads();   // all rw reads done before DMA overwrites Kl/Vl; drains all vmem

  f32x4 O[2][4] = {};
  float m_[2] = {-1e30f, -1e30f};
  float lsum[2] = {0.f, 0.f};
  const float C = 0.125f * L2E;
  char* pc = scratch[w];                   // P tile: [16 rows][8 slots x 16B] swizzled

  // DMA staging geometry: wave w stages K rows [16w,16w+16) and V rows same.
  int g_ = lane >> 3;                      // row-in-8
  int colb = ((lane & 7) ^ g_) * 8;        // pre-swizzled source col

  // ---- prologue: stage chunk 0 into buf 0 (4 ops/wave, left in flight) ----
#pragma unroll
  for (int i = 0; i < 2; ++i) {
    int op = 2 * w + i;                    // 0..7
    gload16(&Kb[(size_t)(op * 8 + g_) * 64 + colb], &Kl[0][op * 512]);
    gload16(&Vb[(size_t)(op * 8 + g_) * 1024 + colb], &Vl[0][op * 512]);
  }

  int cur = 0;
#pragma unroll 1
  for (int kv0 = 0; kv0 < 1024; kv0 += 64) {
    __builtin_amdgcn_s_barrier();          // A: all waves done reading buf[cur^1]
    // ---- issue next-chunk DMA into buf[cur^1] (4 ops; in flight across chunk)
    int nkv = (kv0 + 64 < 1024) ? kv0 + 64 : 960;  // last iter: dummy restage
#pragma unroll
    for (int i = 0; i < 2; ++i) {
      int op = 2 * w + i;
      gload16(&Kb[(size_t)(nkv + op * 8 + g_) * 64 + colb], &Kl[cur ^ 1][op * 512]);
      gload16(&Vb[(size_t)(op * 8 + g_) * 1024 + nkv + colb], &Vl[cur ^ 1][op * 512]);
    }
    // ---- wait: retire this wave's OLDER-chunk DMA (keep 4 newest in flight)
    asm volatile("s_waitcnt vmcnt(4)" ::: "memory");
    __builtin_amdgcn_sched_barrier(0);
    __builtin_amdgcn_s_barrier();          // B: ALL waves' chunk-cur DMA retired
    __builtin_amdgcn_sched_barrier(0);

    const char* kc = (const char*)Kl[cur];
    const char* vc = (const char*)Vl[cur];
    // ---- K frags (swizzled ds_read_b128), shared by both q-halves ----
    short8 kf[8];
#pragma unroll
    for (int t = 0; t < 4; ++t)
#pragma unroll
      for (int h = 0; h < 2; ++h)
        kf[2 * t + h] = *(const short8*)(kc + (t * 16 + lr) * 128 + (((h * 4 + lg) ^ xr) * 16));
    // ---- QK^T (swapped): st[qh][t][r] = S[kv0+t*16+lg*4+r][q0+qh*16+lr] ----
    f32x4 st[2][4];
#pragma unroll
    for (int t = 0; t < 4; ++t)
#pragma unroll
      for (int qh = 0; qh < 2; ++qh) {
        f32x4 z = {};
        z = __builtin_amdgcn_mfma_f32_16x16x32_bf16(kf[2 * t], qf[qh][0], z, 0, 0, 0);
        z = __builtin_amdgcn_mfma_f32_16x16x32_bf16(kf[2 * t + 1], qf[qh][1], z, 0, 0, 0);
        st[qh][t] = z;
      }
    // ---- bias add (log2 domain) + in-lane max ----
    int kh = kv0 >> 5;
    float mxl[2];
#pragma unroll
    for (int qh = 0; qh < 2; ++qh) {
      float bh0 = __bfloat162float(rhw[(qh * 16 + lr) * 36 + kh]);
      float bh1 = __bfloat162float(rhw[(qh * 16 + lr) * 36 + kh + 1]);
      float mx = -1e30f;
#pragma unroll
      for (int t = 0; t < 4; ++t)
#pragma unroll
        for (int r = 0; r < 4; ++r) {
          float sv = fmaf(st[qh][t][r], C, ((t < 2) ? bh0 : bh1) + rwreg[qh][(t & 1) * 4 + r]);
          st[qh][t][r] = sv;
          mx = fmaxf(mx, sv);
        }
      mxl[qh] = mx;
    }
    // ---- defer-max rescale (rare) ----
    int cond = (mxl[0] <= m_[0] + 8.f) && (mxl[1] <= m_[1] + 8.f);
    if (!__all(cond)) {
#pragma unroll
      for (int qh = 0; qh < 2; ++qh) {
        float mw = fmaxf(mxl[qh], __shfl_xor(mxl[qh], 16, 64));
        mw = fmaxf(mw, __shfl_xor(mw, 32, 64));
        float mnew = fmaxf(m_[qh], mw);
        float al = exp2f(m_[qh] - mnew);
        lsum[qh] *= al;
        m_[qh] = mnew;
#pragma unroll
        for (int r = 0; r < 4; ++r) {
          float av = __shfl(al, lg * 4 + r, 64);
#pragma unroll
          for (int dt = 0; dt < 4; ++dt) O[qh][dt][r] *= av;
        }
      }
    }
    // ---- exp2 + per-lane partial sum + truncation-pack; P tile reused per qh
    short8 pf[2][2];
#pragma unroll
    for (int qh = 0; qh < 2; ++qh) {
      float mq = m_[qh];
      float sa = 0.f;
#pragma unroll
      for (int t = 0; t < 4; ++t) {
        float p0 = exp2f(st[qh][t][0] - mq);
        float p1 = exp2f(st[qh][t][1] - mq);
        float p2 = exp2f(st[qh][t][2] - mq);
        float p3 = exp2f(st[qh][t][3] - mq);
        sa += (p0 + p1) + (p2 + p3);
        uint2 wv;
        wv.x = packtrunc(p0, p1);
        wv.y = packtrunc(p2, p3);
        int slot = (2 * t + (lg >> 1)) ^ xr;
        *(uint2*)(pc + lr * 128 + slot * 16 + (lg & 1) * 8) = wv;
      }
      lsum[qh] += sa;
      // read this half's P A-frags before overwriting the tile (same-wave DS order)
      pf[qh][0] = *(const short8*)(pc + lr * 128 + (((0 + lg) ^ xr) * 16));
      pf[qh][1] = *(const short8*)(pc + lr * 128 + (((4 + lg) ^ xr) * 16));
    }
    // ---- PV: vf reads shared by both q-halves ----
#pragma unroll
    for (int dt = 0; dt < 4; ++dt) {
      short8 vf0 = *(const short8*)(vc + (dt * 16 + lr) * 128 + (((0 + lg) ^ xr) * 16));
      short8 vf1 = *(const short8*)(vc + (dt * 16 + lr) * 128 + (((4 + lg) ^ xr) * 16));
#pragma unroll
      for (int qh = 0; qh < 2; ++qh) {
        O[qh][dt] = __builtin_amdgcn_mfma_f32_16x16x32_bf16(pf[qh][0], vf0, O[qh][dt], 0, 0, 0);
        O[qh][dt] = __builtin_amdgcn_mfma_f32_16x16x32_bf16(pf[qh][1], vf1, O[qh][dt], 0, 0, 0);
      }
    }
    cur ^= 1;
  }

  // epilogue: reduce deferred l, then faithful out permutation (verified in R0)
#pragma unroll
  for (int qh = 0; qh < 2; ++qh) {
    float lt = lsum[qh];
    lt += __shfl_xor(lt, 16, 64);
    lt += __shfl_xor(lt, 32, 64);
    float linv = 1.f / lt;
#pragma unroll
    for (int r = 0; r < 4; ++r) {
      float lv = __shfl(linv, lg * 4 + r, 64);
      int n = q0 + qh * 16 + lg * 4 + r;
#pragma unroll
      for (int dt = 0; dt < 4; ++dt) {
        int d = dt * 16 + lr;
        int Sidx = bh * 65536 + n * 64 + d;
        int b = Sidx / 786432, r1 = Sidx % 786432;
        int pp = r1 / 24576, r2 = r1 % 24576;
        int qq = r2 / 768, r3 = r2 % 768;
        int j = r3 >> 6, dd = r3 & 63;
        int P = b * 786432 + j * 65536 + pp * 2048 + qq * 64 + dd;
        outp[P] = __float2bfloat16(O[qh][dt][r] * lv);
      }
    }
  }
}

extern "C" void kernel_launch(void* const* d_in, const int* in_sizes, int n_in,
                              void* d_out, int out_size, void* d_ws, size_t ws_size,
                              hipStream_t stream) {
  const float* x     = (const float*)d_in[0];
  const float* Wqkv  = (const float*)d_in[1];
  const float* bqkv  = (const float*)d_in[2];
  const float* Wproj = (const float*)d_in[3];
  const float* bproj = (const float*)d_in[4];
  const float* rph   = (const float*)d_in[5];
  const float* rpw   = (const float*)d_in[6];
  float* out = (float*)d_out;
  char* ws = (char*)d_ws;

  __hip_bfloat16* xb     = (__hip_bfloat16*)(ws);
  __hip_bfloat16* wqkvT  = (__hip_bfloat16*)(ws + 12582912);
  __hip_bfloat16* wprojT = (__hip_bfloat16*)(ws + 16121856);
  __hip_bfloat16* qkvb   = (__hip_bfloat16*)(ws + 17301504);  // later aliased as attn-out
  __hip_bfloat16* Qm     = (__hip_bfloat16*)(ws + 55050240);
  __hip_bfloat16* Km     = (__hip_bfloat16*)(ws + 67633152);
  __hip_bfloat16* Vtm    = (__hip_bfloat16*)(ws + 80216064);

  cast_f32_bf16<<<dim3(6144), dim3(256), 0, stream>>>(x, xb);
  transpose_cast<<<dim3(72, 24), dim3(256), 0, stream>>>(Wqkv, wqkvT, 768, 2304);
  transpose_cast<<<dim3(24, 24), dim3(256), 0, stream>>>(Wproj, wprojT, 768, 768);
  gemm_dma<128, true><<<dim3(18, 64), dim3(256), 0, stream>>>(xb, wqkvT, bqkv, (void*)qkvb, 2304, 768);
  permute_v2<<<dim3(16, 96), dim3(256), 0, stream>>>(qkvb, Qm, Km, Vtm);
  attn10<<<dim3(768), dim3(256), 0, stream>>>(Qm, Km, Vtm, rph, rpw, qkvb);
  gemm_dma<64, false><<<dim3(6, 128), dim3(256), 0, stream>>>(qkvb, wprojT, bproj, (void*)out, 768, 768);
}

// Round 14
// 180.067 us; speedup vs baseline: 1.7592x; 1.0112x over previous
//
#include <hip/hip_runtime.h>
#include <hip/hip_bf16.h>

// Shapes (fixed): B=8, H=W=32, E=768, nh=12, hd=64, N=1024, BH=96
// ws layout (bytes):
//   xb      @ 0          : 12,582,912  (x cast to bf16)
//   wqkvT   @ 12582912   :  3,538,944  (Wqkv^T bf16)
//   wprojT  @ 16121856   :  1,179,648  (Wproj^T bf16)
//   qkvb    @ 17301504   : 37,748,736  (qkv bf16; later aliased by attn-out bf16)
//   Q       @ 55050240   : 12,582,912
//   K       @ 67633152   : 12,582,912
//   Vt      @ 80216064   : 12,582,912  (V transposed: [bh][d][n])

typedef __attribute__((ext_vector_type(8))) short short8;
typedef __attribute__((ext_vector_type(4))) float f32x4;

__global__ __launch_bounds__(256) void cast_f32_bf16(const float* __restrict__ in,
                                                     __hip_bfloat16* __restrict__ out) {
  int i = (blockIdx.x * 256 + threadIdx.x) * 4;
  float4 v = *(const float4*)&in[i];
  out[i + 0] = __float2bfloat16(v.x);
  out[i + 1] = __float2bfloat16(v.y);
  out[i + 2] = __float2bfloat16(v.z);
  out[i + 3] = __float2bfloat16(v.w);
}

// in [K][N] f32 -> out [N][K] bf16
__global__ __launch_bounds__(256) void transpose_cast(const float* __restrict__ in,
                                                      __hip_bfloat16* __restrict__ out,
                                                      int K, int N) {
  __shared__ float tile[32][33];
  int n0 = blockIdx.x * 32, k0 = blockIdx.y * 32;
  int tx = threadIdx.x & 31, ty = threadIdx.x >> 5;  // 32 x 8
#pragma unroll
  for (int i = 0; i < 4; ++i)
    tile[ty + i * 8][tx] = in[(size_t)(k0 + ty + i * 8) * N + n0 + tx];
  __syncthreads();
#pragma unroll
  for (int i = 0; i < 4; ++i)
    out[(size_t)(n0 + ty + i * 8) * K + k0 + tx] = __float2bfloat16(tile[tx][ty + i * 8]);
}

__device__ inline void gload16(const void* g, void* l) {
  __builtin_amdgcn_global_load_lds((const __attribute__((address_space(1))) void*)g,
                                   (__attribute__((address_space(3))) void*)l, 16, 0, 0);
}

// C[M,N] = A[M,K]*Bt[N,K]^T + bias ; BMx128 tile (BM=128 or 64), 4 waves (2x2),
// BK=64, staging via global_load_lds width=16 into linear LDS (m97 structure).
template<int BM, bool OUT_BF16>
__global__ __launch_bounds__(256) void gemm_dma(const __hip_bfloat16* __restrict__ A,
                                                const __hip_bfloat16* __restrict__ Bt,
                                                const float* __restrict__ bias,
                                                void* __restrict__ Cout,
                                                int N, int K) {
  constexpr int FM = BM / 32;               // m-frags per wave (4 or 2)
  __shared__ __hip_bfloat16 Al[BM * 64];
  __shared__ __hip_bfloat16 Bl[128 * 64];
  int n0 = blockIdx.x * 128, m0 = blockIdx.y * BM;
  int tid = threadIdx.x, lane = tid & 63, wid = tid >> 6;
  int wm = wid >> 1, wn = wid & 1;
  int lr = lane & 15, lg = lane >> 4;
  int row_l = lane >> 3, col8 = (lane & 7) * 8;
  f32x4 acc[FM][4] = {};
  for (int k0 = 0; k0 < K; k0 += 64) {
#pragma unroll
    for (int j = 0; j < BM / 32; ++j) {     // A: BM*8/64 chunks over 4 waves
      int jj = wid * (BM / 32) + j;
      int arow = jj * 8 + row_l;
      gload16(&A[(size_t)(m0 + arow) * K + k0 + col8], &Al[jj * 512]);
    }
#pragma unroll
    for (int j = 0; j < 4; ++j) {           // B: 16 chunks over 4 waves
      int jj = wid * 4 + j;
      int brow = jj * 8 + row_l;
      gload16(&Bt[(size_t)(n0 + brow) * K + k0 + col8], &Bl[jj * 512]);
    }
    __syncthreads();  // drains vmcnt (DMA writes) per compiler barrier semantics
#pragma unroll
    for (int ks = 0; ks < 2; ++ks) {
      short8 af[FM], bfr[4];
#pragma unroll
      for (int m = 0; m < FM; ++m)
        af[m] = *(const short8*)&Al[(wm * (BM / 2) + m * 16 + lr) * 64 + ks * 32 + lg * 8];
#pragma unroll
      for (int n = 0; n < 4; ++n)
        bfr[n] = *(const short8*)&Bl[(wn * 64 + n * 16 + lr) * 64 + ks * 32 + lg * 8];
#pragma unroll
      for (int m = 0; m < FM; ++m)
#pragma unroll
        for (int n = 0; n < 4; ++n)
          acc[m][n] = __builtin_amdgcn_mfma_f32_16x16x32_bf16(af[m], bfr[n], acc[m][n], 0, 0, 0);
    }
    __syncthreads();
  }
#pragma unroll
  for (int n = 0; n < 4; ++n) {
    int col = n0 + wn * 64 + n * 16 + lr;
    float bv = bias[col];
#pragma unroll
    for (int m = 0; m < FM; ++m) {
      int rowb = m0 + wm * (BM / 2) + m * 16 + lg * 4;
#pragma unroll
      for (int r = 0; r < 4; ++r) {
        float v = acc[m][n][r] + bv;
        if (OUT_BF16)
          ((__hip_bfloat16*)Cout)[(size_t)(rowb + r) * N + col] = __float2bfloat16(v);
        else
          ((float*)Cout)[(size_t)(rowb + r) * N + col] = v;
      }
    }
  }
}

// permute_qkv v2 (verified R8): per dest (bh,n2) the CONTIGUOUS source window
// qkv_flat[(bh*1024+n2)*192 .. +192) with fixed intra-window permutation
// src_off(u) = (u&63)*3 + (u>>6), u = d2*3 + c2.
__global__ __launch_bounds__(256) void permute_v2(const __hip_bfloat16* __restrict__ qkv,
                                                  __hip_bfloat16* __restrict__ Q,
                                                  __hip_bfloat16* __restrict__ Kd,
                                                  __hip_bfloat16* __restrict__ Vt) {
  int bh = blockIdx.y, n0 = blockIdx.x * 64;
  int tid = threadIdx.x;
  __shared__ short raw[64 * 200];     // window wi stride 200 (pad)
  __shared__ short vt[64][72];
  const short* src = (const short*)qkv + (size_t)(bh * 1024 + n0) * 192;
#pragma unroll
  for (int i = 0; i < 6; ++i) {
    int c16 = tid + i * 256;          // 0..1535
    int wi = c16 / 24, off = (c16 % 24) * 8;
    *(short8*)&raw[wi * 200 + off] = *(const short8*)&src[(size_t)c16 * 8];
  }
  __syncthreads();
  int wi = tid >> 2, g4 = tid & 3;
  const short* rw_ = &raw[wi * 200];
  short8 qv[2], kv_[2];
#pragma unroll
  for (int half = 0; half < 2; ++half)
#pragma unroll
    for (int j = 0; j < 8; ++j) {
      int d2 = g4 * 16 + half * 8 + j;
      int u = 3 * d2;
      qv[half][j]  = rw_[((u) & 63) * 3 + ((u) >> 6)];
      kv_[half][j] = rw_[((u + 1) & 63) * 3 + ((u + 1) >> 6)];
      vt[d2][wi]   = rw_[((u + 2) & 63) * 3 + ((u + 2) >> 6)];
    }
  size_t base = (size_t)bh * 65536 + (size_t)(n0 + wi) * 64 + g4 * 16;
  *(short8*)&Q[base] = qv[0];
  *(short8*)&Q[base + 8] = qv[1];
  *(short8*)&Kd[base] = kv_[0];
  *(short8*)&Kd[base + 8] = kv_[1];
  __syncthreads();
  int d2r = tid >> 2;
  size_t vbase = (size_t)bh * 65536 + (size_t)d2r * 1024 + n0 + g4 * 16;
  *(short8*)&Vt[vbase]     = *(const short8*)&vt[d2r][g4 * 16];
  *(short8*)&Vt[vbase + 8] = *(const short8*)&vt[d2r][g4 * 16 + 8];
}

__device__ inline short8 cvt8(const float* p) {
  short8 r;
#pragma unroll
  for (int j = 0; j < 8; ++j) {
    __hip_bfloat16 b = __float2bfloat16(p[j]);
    r[j] = *reinterpret_cast<const short*>(&b);
  }
  return r;
}

// truncation pack: [b_hi16 | a_hi16] in one v_perm_b32 (valid: P>=0, no NaN).
__device__ inline unsigned packtrunc(float a, float b) {
  return __builtin_amdgcn_perm(__float_as_uint(b), __float_as_uint(a), 0x07060302u);
}

// Flash attention v11b (= v11 with the op-addressing unit-slip fixed:
// each DMA op covers 1024 BYTES, so destinations are op*1024, not op*512).
// LDS 40960 B = 4 blocks/CU (16 waves/CU). K dbuf 16KB, V single 8KB,
// rh packed [32][32] bf16 8KB, P scratch 8KB. Counted-vmcnt protocol (R11):
// {barrier A -> issue V_cur + K_next -> vmcnt(4) [K_cur ready] -> barrier B ->
// QK^T/softmax -> vmcnt(2) [V_cur ready; K_next in flight] -> barrier C -> PV}.
#define L2E 1.44269504088896f
__global__ __launch_bounds__(256, 4) void attn11(const __hip_bfloat16* __restrict__ Q,
                                                 const __hip_bfloat16* __restrict__ Kd,
                                                 const __hip_bfloat16* __restrict__ Vt,
                                                 const float* __restrict__ rph,
                                                 const float* __restrict__ rpw,
                                                 __hip_bfloat16* __restrict__ outp) {
  int orig = blockIdx.x;                   // 768 = 8 xcd * 96
  int xcd = orig & 7, loc = orig >> 3;     // 96 per xcd
  int bh = xcd * 12 + (loc % 12);
  int qt = loc / 12;                       // 0..7 (128-row q tile)
  int tid = threadIdx.x;
  int lane = tid & 63, w = tid >> 6;
  int lr = lane & 15, lg = lane >> 4;
  int xr = lr & 7;

  // Carved LDS, 40960 B total (exactly 4 blocks/CU):
  //   [    0,16384): K dbuf  [buf][64 rows][128B], swizzled (op -> byte op*1024)
  //   [16384,24576): V single [64 rows][128B], swizzled
  //   [24576,32768): rh, 4 waves x [32 q][32 kh] bf16 (pairs read as u32)
  //   [32768,40960): P scratch, 4 waves x 2048B
  //   prologue rw staging: wave w at [w*4352, +4352) inside K∪V region
  __shared__ __align__(16) char lds[40960];

  const __hip_bfloat16* Qb = Q + (size_t)bh * 65536;
  const __hip_bfloat16* Kb = Kd + (size_t)bh * 65536;
  const __hip_bfloat16* Vb = Vt + (size_t)bh * 65536;

  int q0 = qt * 128 + w * 32;              // this wave's 32 q-rows (mult of 32)
  int hq = q0 >> 5;                        // constant per wave

  short8 qf[2][2];
#pragma unroll
  for (int qh = 0; qh < 2; ++qh) {
    qf[qh][0] = *(const short8*)&Qb[(size_t)(q0 + qh * 16 + lr) * 64 + lg * 8];
    qf[qh][1] = *(const short8*)&Qb[(size_t)(q0 + qh * 16 + lr) * 64 + 32 + lg * 8];
  }

  // ---- rel-pos bias via MFMA (pre-scaled by L2E) ----
  __hip_bfloat16* rhw = (__hip_bfloat16*)(lds + 24576 + w * 2048);  // [32 q][32 kh]
#pragma unroll
  for (int kt = 0; kt < 2; ++kt) {
    int row = hq - (kt * 16 + lr) + 31;    // 0..62
    const float* tp = rph + (size_t)row * 64 + lg * 8;
    short8 th0 = cvt8(tp), th1 = cvt8(tp + 32);
#pragma unroll
    for (int qh = 0; qh < 2; ++qh) {
      f32x4 a = {};
      a = __builtin_amdgcn_mfma_f32_16x16x32_bf16(qf[qh][0], th0, a, 0, 0, 0);
      a = __builtin_amdgcn_mfma_f32_16x16x32_bf16(qf[qh][1], th1, a, 0, 0, 0);
#pragma unroll
      for (int r = 0; r < 4; ++r)
        rhw[(qh * 16 + lg * 4 + r) * 32 + kt * 16 + lr] = __float2bfloat16(a[r] * L2E);
    }
  }
  // rw staging in the (still dead) K/V region: wave w at byte w*4352, [32][68] bf16
  __hip_bfloat16* rwt = (__hip_bfloat16*)(lds + w * 4352);
#pragma unroll
  for (int jt = 0; jt < 4; ++jt) {
    const float* tp = rpw + (size_t)(jt * 16 + lr) * 64 + lg * 8;
    short8 tw0 = cvt8(tp), tw1 = cvt8(tp + 32);
#pragma unroll
    for (int qh = 0; qh < 2; ++qh) {
      f32x4 a = {};
      a = __builtin_amdgcn_mfma_f32_16x16x32_bf16(qf[qh][0], tw0, a, 0, 0, 0);
      a = __builtin_amdgcn_mfma_f32_16x16x32_bf16(qf[qh][1], tw1, a, 0, 0, 0);
#pragma unroll
      for (int r = 0; r < 4; ++r)
        rwt[(qh * 16 + lg * 4 + r) * 68 + jt * 16 + lr] = __float2bfloat16(a[r] * L2E);
    }
  }
  float rwreg[2][8];
#pragma unroll
  for (int qh = 0; qh < 2; ++qh) {
    int wq = qh * 16 + lr;                 // (q0 + qh*16 + lr) & 31
#pragma unroll
    for (int i = 0; i < 8; ++i) {
      int k = (i >> 2) * 16 + lg * 4 + (i & 3);
      rwreg[qh][i] = __bfloat162float(rwt[(qh * 16 + lr) * 68 + (wq - k + 31)]);
    }
  }
  __syncthreads();   // all rw reads done before DMA overwrites K/V region; drains vmem

  f32x4 O[2][4] = {};
  float m_[2] = {-1e30f, -1e30f};
  float lsum[2] = {0.f, 0.f};
  const float C = 0.125f * L2E;
  char* pc = lds + 32768 + w * 2048;       // P tile: [16 rows][8 slots x 16B] swizzled
  char* vcb = lds + 16384;                 // V single buffer

  // DMA staging geometry: wave w stages K rows [16w,16w+16) and V rows same.
  int g_ = lane >> 3;                      // row-in-8
  int colb = ((lane & 7) ^ g_) * 8;        // pre-swizzled source col

  // ---- prologue: stage chunk-0 K into buf 0 (2 ops/wave, left in flight) ----
#pragma unroll
  for (int i = 0; i < 2; ++i) {
    int op = 2 * w + i;                    // 0..7; each op = 1024 B
    gload16(&Kb[(size_t)(op * 8 + g_) * 64 + colb], lds + op * 1024);
  }

  int cur = 0;
#pragma unroll 1
  for (int kv0 = 0; kv0 < 1024; kv0 += 64) {
    __builtin_amdgcn_sched_barrier(0);
    __builtin_amdgcn_s_barrier();          // A: PV(prev) done; Kl[cur^1] reads done
    // ---- issue V_cur into the single V buffer (2 ops/wave) ----
#pragma unroll
    for (int i = 0; i < 2; ++i) {
      int op = 2 * w + i;
      gload16(&Vb[(size_t)(op * 8 + g_) * 1024 + kv0 + colb], vcb + op * 1024);
    }
    // ---- issue K_next into Kl[cur^1] (2 ops/wave; stays in flight all chunk)
    int nkv = (kv0 + 64 < 1024) ? kv0 + 64 : 960;  // last iter: dummy restage
#pragma unroll
    for (int i = 0; i < 2; ++i) {
      int op = 2 * w + i;
      gload16(&Kb[(size_t)(nkv + op * 8 + g_) * 64 + colb], lds + (cur ^ 1) * 8192 + op * 1024);
    }
    // ---- retire this wave's K_cur (keep V_cur + K_next = 4 newest in flight)
    asm volatile("s_waitcnt vmcnt(4)" ::: "memory");
    __builtin_amdgcn_sched_barrier(0);
    __builtin_amdgcn_s_barrier();          // B: ALL waves' K_cur retired
    __builtin_amdgcn_sched_barrier(0);

    const char* kc = lds + cur * 8192;
    // ---- K frags (swizzled ds_read_b128), shared by both q-halves ----
    short8 kf[8];
#pragma unroll
    for (int t = 0; t < 4; ++t)
#pragma unroll
      for (int h = 0; h < 2; ++h)
        kf[2 * t + h] = *(const short8*)(kc + (t * 16 + lr) * 128 + (((h * 4 + lg) ^ xr) * 16));
    // ---- QK^T (swapped): st[qh][t][r] = S[kv0+t*16+lg*4+r][q0+qh*16+lr] ----
    f32x4 st[2][4];
#pragma unroll
    for (int t = 0; t < 4; ++t)
#pragma unroll
      for (int qh = 0; qh < 2; ++qh) {
        f32x4 z = {};
        z = __builtin_amdgcn_mfma_f32_16x16x32_bf16(kf[2 * t], qf[qh][0], z, 0, 0, 0);
        z = __builtin_amdgcn_mfma_f32_16x16x32_bf16(kf[2 * t + 1], qf[qh][1], z, 0, 0, 0);
        st[qh][t] = z;
      }
    // ---- bias add (log2 domain) + in-lane max; rh pair read as one u32 ----
    float mxl[2];
#pragma unroll
    for (int qh = 0; qh < 2; ++qh) {
      unsigned bu = *(const unsigned*)(lds + 24576 + w * 2048 + (qh * 16 + lr) * 64 + (kv0 >> 4));
      float bh0 = __uint_as_float(bu << 16);
      float bh1 = __uint_as_float(bu & 0xffff0000u);
      float mx = -1e30f;
#pragma unroll
      for (int t = 0; t < 4; ++t)
#pragma unroll
        for (int r = 0; r < 4; ++r) {
          float sv = fmaf(st[qh][t][r], C, ((t < 2) ? bh0 : bh1) + rwreg[qh][(t & 1) * 4 + r]);
          st[qh][t][r] = sv;
          mx = fmaxf(mx, sv);
        }
      mxl[qh] = mx;
    }
    // ---- defer-max rescale (rare) ----
    int cond = (mxl[0] <= m_[0] + 8.f) && (mxl[1] <= m_[1] + 8.f);
    if (!__all(cond)) {
#pragma unroll
      for (int qh = 0; qh < 2; ++qh) {
        float mw = fmaxf(mxl[qh], __shfl_xor(mxl[qh], 16, 64));
        mw = fmaxf(mw, __shfl_xor(mw, 32, 64));
        float mnew = fmaxf(m_[qh], mw);
        float al = exp2f(m_[qh] - mnew);
        lsum[qh] *= al;
        m_[qh] = mnew;
#pragma unroll
        for (int r = 0; r < 4; ++r) {
          float av = __shfl(al, lg * 4 + r, 64);
#pragma unroll
          for (int dt = 0; dt < 4; ++dt) O[qh][dt][r] *= av;
        }
      }
    }
    // ---- exp2 + per-lane partial sum + truncation-pack; P tile reused per qh
    short8 pf[2][2];
#pragma unroll
    for (int qh = 0; qh < 2; ++qh) {
      float mq = m_[qh];
      float sa = 0.f;
#pragma unroll
      for (int t = 0; t < 4; ++t) {
        float p0 = exp2f(st[qh][t][0] - mq);
        float p1 = exp2f(st[qh][t][1] - mq);
        float p2 = exp2f(st[qh][t][2] - mq);
        float p3 = exp2f(st[qh][t][3] - mq);
        sa += (p0 + p1) + (p2 + p3);
        uint2 wv;
        wv.x = packtrunc(p0, p1);
        wv.y = packtrunc(p2, p3);
        int slot = (2 * t + (lg >> 1)) ^ xr;
        *(uint2*)(pc + lr * 128 + slot * 16 + (lg & 1) * 8) = wv;
      }
      lsum[qh] += sa;
      // read this half's P A-frags before overwriting the tile (same-wave DS order)
      pf[qh][0] = *(const short8*)(pc + lr * 128 + (((0 + lg) ^ xr) * 16));
      pf[qh][1] = *(const short8*)(pc + lr * 128 + (((4 + lg) ^ xr) * 16));
    }
    // ---- retire V_cur (K_next stays in flight), then all-waves barrier ----
    asm volatile("s_waitcnt vmcnt(2)" ::: "memory");
    __builtin_amdgcn_sched_barrier(0);
    __builtin_amdgcn_s_barrier();          // C: ALL waves' V_cur retired
    __builtin_amdgcn_sched_barrier(0);
    // ---- PV: vf reads shared by both q-halves ----
#pragma unroll
    for (int dt = 0; dt < 4; ++dt) {
      short8 vf0 = *(const short8*)(vcb + (dt * 16 + lr) * 128 + (((0 + lg) ^ xr) * 16));
      short8 vf1 = *(const short8*)(vcb + (dt * 16 + lr) * 128 + (((4 + lg) ^ xr) * 16));
#pragma unroll
      for (int qh = 0; qh < 2; ++qh) {
        O[qh][dt] = __builtin_amdgcn_mfma_f32_16x16x32_bf16(pf[qh][0], vf0, O[qh][dt], 0, 0, 0);
        O[qh][dt] = __builtin_amdgcn_mfma_f32_16x16x32_bf16(pf[qh][1], vf1, O[qh][dt], 0, 0, 0);
      }
    }
    cur ^= 1;
  }

  // epilogue: reduce deferred l, then faithful out permutation (verified in R0)
#pragma unroll
  for (int qh = 0; qh < 2; ++qh) {
    float lt = lsum[qh];
    lt += __shfl_xor(lt, 16, 64);
    lt += __shfl_xor(lt, 32, 64);
    float linv = 1.f / lt;
#pragma unroll
    for (int r = 0; r < 4; ++r) {
      float lv = __shfl(linv, lg * 4 + r, 64);
      int n = q0 + qh * 16 + lg * 4 + r;
#pragma unroll
      for (int dt = 0; dt < 4; ++dt) {
        int d = dt * 16 + lr;
        int Sidx = bh * 65536 + n * 64 + d;
        int b = Sidx / 786432, r1 = Sidx % 786432;
        int pp = r1 / 24576, r2 = r1 % 24576;
        int qq = r2 / 768, r3 = r2 % 768;
        int j = r3 >> 6, dd = r3 & 63;
        int P = b * 786432 + j * 65536 + pp * 2048 + qq * 64 + dd;
        outp[P] = __float2bfloat16(O[qh][dt][r] * lv);
      }
    }
  }
}

extern "C" void kernel_launch(void* const* d_in, const int* in_sizes, int n_in,
                              void* d_out, int out_size, void* d_ws, size_t ws_size,
                              hipStream_t stream) {
  const float* x     = (const float*)d_in[0];
  const float* Wqkv  = (const float*)d_in[1];
  const float* bqkv  = (const float*)d_in[2];
  const float* Wproj = (const float*)d_in[3];
  const float* bproj = (const float*)d_in[4];
  const float* rph   = (const float*)d_in[5];
  const float* rpw   = (const float*)d_in[6];
  float* out = (float*)d_out;
  char* ws = (char*)d_ws;

  __hip_bfloat16* xb     = (__hip_bfloat16*)(ws);
  __hip_bfloat16* wqkvT  = (__hip_bfloat16*)(ws + 12582912);
  __hip_bfloat16* wprojT = (__hip_bfloat16*)(ws + 16121856);
  __hip_bfloat16* qkvb   = (__hip_bfloat16*)(ws + 17301504);  // later aliased as attn-out
  __hip_bfloat16* Qm     = (__hip_bfloat16*)(ws + 55050240);
  __hip_bfloat16* Km     = (__hip_bfloat16*)(ws + 67633152);
  __hip_bfloat16* Vtm    = (__hip_bfloat16*)(ws + 80216064);

  cast_f32_bf16<<<dim3(6144), dim3(256), 0, stream>>>(x, xb);
  transpose_cast<<<dim3(72, 24), dim3(256), 0, stream>>>(Wqkv, wqkvT, 768, 2304);
  transpose_cast<<<dim3(24, 24), dim3(256), 0, stream>>>(Wproj, wprojT, 768, 768);
  gemm_dma<128, true><<<dim3(18, 64), dim3(256), 0, stream>>>(xb, wqkvT, bqkv, (void*)qkvb, 2304, 768);
  permute_v2<<<dim3(16, 96), dim3(256), 0, stream>>>(qkvb, Qm, Km, Vtm);
  attn11<<<dim3(768), dim3(256), 0, stream>>>(Qm, Km, Vtm, rph, rpw, qkvb);
  gemm_dma<64, false><<<dim3(6, 128), dim3(256), 0, stream>>>(qkvb, wprojT, bproj, (void*)out, 768, 768);
}

// Round 15
// 176.149 us; speedup vs baseline: 1.7983x; 1.0222x over previous
//
#include <hip/hip_runtime.h>
#include <hip/hip_bf16.h>

// Shapes (fixed): B=8, H=W=32, E=768, nh=12, hd=64, N=1024, BH=96
// ws layout (bytes):
//   xb      @ 0          : 12,582,912  (x cast to bf16)
//   wqkvT   @ 12582912   :  3,538,944  (Wqkv^T bf16)
//   wprojT  @ 16121856   :  1,179,648  (Wproj^T bf16)
//   qkvb    @ 17301504   : 37,748,736  (qkv bf16; later aliased by attn-out bf16)
//   Q       @ 55050240   : 12,582,912
//   K       @ 67633152   : 12,582,912
//   Vt      @ 80216064   : 12,582,912  (V transposed: [bh][d][n])

typedef __attribute__((ext_vector_type(8))) short short8;
typedef __attribute__((ext_vector_type(4))) float f32x4;

__global__ __launch_bounds__(256) void cast_f32_bf16(const float* __restrict__ in,
                                                     __hip_bfloat16* __restrict__ out) {
  int i = (blockIdx.x * 256 + threadIdx.x) * 4;
  float4 v = *(const float4*)&in[i];
  out[i + 0] = __float2bfloat16(v.x);
  out[i + 1] = __float2bfloat16(v.y);
  out[i + 2] = __float2bfloat16(v.z);
  out[i + 3] = __float2bfloat16(v.w);
}

// in [K][N] f32 -> out [N][K] bf16
__global__ __launch_bounds__(256) void transpose_cast(const float* __restrict__ in,
                                                      __hip_bfloat16* __restrict__ out,
                                                      int K, int N) {
  __shared__ float tile[32][33];
  int n0 = blockIdx.x * 32, k0 = blockIdx.y * 32;
  int tx = threadIdx.x & 31, ty = threadIdx.x >> 5;  // 32 x 8
#pragma unroll
  for (int i = 0; i < 4; ++i)
    tile[ty + i * 8][tx] = in[(size_t)(k0 + ty + i * 8) * N + n0 + tx];
  __syncthreads();
#pragma unroll
  for (int i = 0; i < 4; ++i)
    out[(size_t)(n0 + ty + i * 8) * K + k0 + tx] = __float2bfloat16(tile[tx][ty + i * 8]);
}

__device__ inline void gload16(const void* g, void* l) {
  __builtin_amdgcn_global_load_lds((const __attribute__((address_space(1))) void*)g,
                                   (__attribute__((address_space(3))) void*)l, 16, 0, 0);
}

// C[M,N] = A[M,K]*Bt[N,K]^T + bias ; BMx128 tile (BM=128 or 64), 4 waves (2x2),
// BK=64, staging via global_load_lds width=16 into linear LDS (m97 structure).
template<int BM, bool OUT_BF16>
__global__ __launch_bounds__(256) void gemm_dma(const __hip_bfloat16* __restrict__ A,
                                                const __hip_bfloat16* __restrict__ Bt,
                                                const float* __restrict__ bias,
                                                void* __restrict__ Cout,
                                                int N, int K) {
  constexpr int FM = BM / 32;               // m-frags per wave (4 or 2)
  __shared__ __hip_bfloat16 Al[BM * 64];
  __shared__ __hip_bfloat16 Bl[128 * 64];
  int n0 = blockIdx.x * 128, m0 = blockIdx.y * BM;
  int tid = threadIdx.x, lane = tid & 63, wid = tid >> 6;
  int wm = wid >> 1, wn = wid & 1;
  int lr = lane & 15, lg = lane >> 4;
  int row_l = lane >> 3, col8 = (lane & 7) * 8;
  f32x4 acc[FM][4] = {};
  for (int k0 = 0; k0 < K; k0 += 64) {
#pragma unroll
    for (int j = 0; j < BM / 32; ++j) {     // A: BM*8/64 chunks over 4 waves
      int jj = wid * (BM / 32) + j;
      int arow = jj * 8 + row_l;
      gload16(&A[(size_t)(m0 + arow) * K + k0 + col8], &Al[jj * 512]);
    }
#pragma unroll
    for (int j = 0; j < 4; ++j) {           // B: 16 chunks over 4 waves
      int jj = wid * 4 + j;
      int brow = jj * 8 + row_l;
      gload16(&Bt[(size_t)(n0 + brow) * K + k0 + col8], &Bl[jj * 512]);
    }
    __syncthreads();  // drains vmcnt (DMA writes) per compiler barrier semantics
#pragma unroll
    for (int ks = 0; ks < 2; ++ks) {
      short8 af[FM], bfr[4];
#pragma unroll
      for (int m = 0; m < FM; ++m)
        af[m] = *(const short8*)&Al[(wm * (BM / 2) + m * 16 + lr) * 64 + ks * 32 + lg * 8];
#pragma unroll
      for (int n = 0; n < 4; ++n)
        bfr[n] = *(const short8*)&Bl[(wn * 64 + n * 16 + lr) * 64 + ks * 32 + lg * 8];
#pragma unroll
      for (int m = 0; m < FM; ++m)
#pragma unroll
        for (int n = 0; n < 4; ++n)
          acc[m][n] = __builtin_amdgcn_mfma_f32_16x16x32_bf16(af[m], bfr[n], acc[m][n], 0, 0, 0);
    }
    __syncthreads();
  }
#pragma unroll
  for (int n = 0; n < 4; ++n) {
    int col = n0 + wn * 64 + n * 16 + lr;
    float bv = bias[col];
#pragma unroll
    for (int m = 0; m < FM; ++m) {
      int rowb = m0 + wm * (BM / 2) + m * 16 + lg * 4;
#pragma unroll
      for (int r = 0; r < 4; ++r) {
        float v = acc[m][n][r] + bv;
        if (OUT_BF16)
          ((__hip_bfloat16*)Cout)[(size_t)(rowb + r) * N + col] = __float2bfloat16(v);
        else
          ((float*)Cout)[(size_t)(rowb + r) * N + col] = v;
      }
    }
  }
}

// permute_qkv v2 (verified R8): per dest (bh,n2) the CONTIGUOUS source window
// qkv_flat[(bh*1024+n2)*192 .. +192) with fixed intra-window permutation
// src_off(u) = (u&63)*3 + (u>>6), u = d2*3 + c2.
__global__ __launch_bounds__(256) void permute_v2(const __hip_bfloat16* __restrict__ qkv,
                                                  __hip_bfloat16* __restrict__ Q,
                                                  __hip_bfloat16* __restrict__ Kd,
                                                  __hip_bfloat16* __restrict__ Vt) {
  int bh = blockIdx.y, n0 = blockIdx.x * 64;
  int tid = threadIdx.x;
  __shared__ short raw[64 * 200];     // window wi stride 200 (pad)
  __shared__ short vt[64][72];
  const short* src = (const short*)qkv + (size_t)(bh * 1024 + n0) * 192;
#pragma unroll
  for (int i = 0; i < 6; ++i) {
    int c16 = tid + i * 256;          // 0..1535
    int wi = c16 / 24, off = (c16 % 24) * 8;
    *(short8*)&raw[wi * 200 + off] = *(const short8*)&src[(size_t)c16 * 8];
  }
  __syncthreads();
  int wi = tid >> 2, g4 = tid & 3;
  const short* rw_ = &raw[wi * 200];
  short8 qv[2], kv_[2];
#pragma unroll
  for (int half = 0; half < 2; ++half)
#pragma unroll
    for (int j = 0; j < 8; ++j) {
      int d2 = g4 * 16 + half * 8 + j;
      int u = 3 * d2;
      qv[half][j]  = rw_[((u) & 63) * 3 + ((u) >> 6)];
      kv_[half][j] = rw_[((u + 1) & 63) * 3 + ((u + 1) >> 6)];
      vt[d2][wi]   = rw_[((u + 2) & 63) * 3 + ((u + 2) >> 6)];
    }
  size_t base = (size_t)bh * 65536 + (size_t)(n0 + wi) * 64 + g4 * 16;
  *(short8*)&Q[base] = qv[0];
  *(short8*)&Q[base + 8] = qv[1];
  *(short8*)&Kd[base] = kv_[0];
  *(short8*)&Kd[base + 8] = kv_[1];
  __syncthreads();
  int d2r = tid >> 2;
  size_t vbase = (size_t)bh * 65536 + (size_t)d2r * 1024 + n0 + g4 * 16;
  *(short8*)&Vt[vbase]     = *(const short8*)&vt[d2r][g4 * 16];
  *(short8*)&Vt[vbase + 8] = *(const short8*)&vt[d2r][g4 * 16 + 8];
}

__device__ inline short8 cvt8(const float* p) {
  short8 r;
#pragma unroll
  for (int j = 0; j < 8; ++j) {
    __hip_bfloat16 b = __float2bfloat16(p[j]);
    r[j] = *reinterpret_cast<const short*>(&b);
  }
  return r;
}

// truncation pack: [b_hi16 | a_hi16] in one v_perm_b32 (valid: P>=0, no NaN).
__device__ inline unsigned packtrunc(float a, float b) {
  return __builtin_amdgcn_perm(__float_as_uint(b), __float_as_uint(a), 0x07060302u);
}

// Flash attention v12 (= v11b with the two R13 regressions fixed):
//  - plain __launch_bounds__(256): the (256,4) cap forced VGPR 64 + scratch
//    spills (WRITE_SIZE 12.3->30MB). VGPR ~100 <= 128 still allows 4 waves/SIMD.
//  - rh pair-slot XOR swizzle (slot s stored at s^(q&15)): the linear packed
//    layout made the per-chunk u32 rh read an 8-way bank conflict.
// LDS 40960 B = 4 blocks/CU. Counted-vmcnt protocol (validated R11):
// {barrier A -> issue V_cur + K_next -> vmcnt(4) [K_cur ready] -> barrier B ->
// QK^T/softmax -> vmcnt(2) [V_cur ready; K_next in flight] -> barrier C -> PV}.
#define L2E 1.44269504088896f
__global__ __launch_bounds__(256) void attn12(const __hip_bfloat16* __restrict__ Q,
                                              const __hip_bfloat16* __restrict__ Kd,
                                              const __hip_bfloat16* __restrict__ Vt,
                                              const float* __restrict__ rph,
                                              const float* __restrict__ rpw,
                                              __hip_bfloat16* __restrict__ outp) {
  int orig = blockIdx.x;                   // 768 = 8 xcd * 96
  int xcd = orig & 7, loc = orig >> 3;     // 96 per xcd
  int bh = xcd * 12 + (loc % 12);
  int qt = loc / 12;                       // 0..7 (128-row q tile)
  int tid = threadIdx.x;
  int lane = tid & 63, w = tid >> 6;
  int lr = lane & 15, lg = lane >> 4;
  int xr = lr & 7;

  // Carved LDS, 40960 B total (exactly 4 blocks/CU):
  //   [    0,16384): K dbuf  [buf][64 rows][128B], swizzled (op -> byte op*1024)
  //   [16384,24576): V single [64 rows][128B], swizzled
  //   [24576,32768): rh, 4 waves x [32 q][16 u32-slots], slot s at s^(q&15)
  //   [32768,40960): P scratch, 4 waves x 2048B
  //   prologue rw staging: wave w at [w*4352, +4352) inside K∪V region
  __shared__ __align__(16) char lds[40960];

  const __hip_bfloat16* Qb = Q + (size_t)bh * 65536;
  const __hip_bfloat16* Kb = Kd + (size_t)bh * 65536;
  const __hip_bfloat16* Vb = Vt + (size_t)bh * 65536;

  int q0 = qt * 128 + w * 32;              // this wave's 32 q-rows (mult of 32)
  int hq = q0 >> 5;                        // constant per wave

  short8 qf[2][2];
#pragma unroll
  for (int qh = 0; qh < 2; ++qh) {
    qf[qh][0] = *(const short8*)&Qb[(size_t)(q0 + qh * 16 + lr) * 64 + lg * 8];
    qf[qh][1] = *(const short8*)&Qb[(size_t)(q0 + qh * 16 + lr) * 64 + 32 + lg * 8];
  }

  // ---- rel-pos bias via MFMA (pre-scaled by L2E); swizzled-slot store ----
  char* rhb = lds + 24576 + w * 2048;      // [32 q][64B], pair-slot swizzled
#pragma unroll
  for (int kt = 0; kt < 2; ++kt) {
    int row = hq - (kt * 16 + lr) + 31;    // 0..62
    const float* tp = rph + (size_t)row * 64 + lg * 8;
    short8 th0 = cvt8(tp), th1 = cvt8(tp + 32);
#pragma unroll
    for (int qh = 0; qh < 2; ++qh) {
      f32x4 a = {};
      a = __builtin_amdgcn_mfma_f32_16x16x32_bf16(qf[qh][0], th0, a, 0, 0, 0);
      a = __builtin_amdgcn_mfma_f32_16x16x32_bf16(qf[qh][1], th1, a, 0, 0, 0);
#pragma unroll
      for (int r = 0; r < 4; ++r) {
        int q = qh * 16 + lg * 4 + r;
        int e = kt * 16 + lr;              // kh element 0..31
        int sw = ((e >> 1) ^ (q & 15)) << 2;
        *(__hip_bfloat16*)(rhb + q * 64 + sw + (e & 1) * 2) = __float2bfloat16(a[r] * L2E);
      }
    }
  }
  // rw staging in the (still dead) K/V region: wave w at byte w*4352, [32][68] bf16
  __hip_bfloat16* rwt = (__hip_bfloat16*)(lds + w * 4352);
#pragma unroll
  for (int jt = 0; jt < 4; ++jt) {
    const float* tp = rpw + (size_t)(jt * 16 + lr) * 64 + lg * 8;
    short8 tw0 = cvt8(tp), tw1 = cvt8(tp + 32);
#pragma unroll
    for (int qh = 0; qh < 2; ++qh) {
      f32x4 a = {};
      a = __builtin_amdgcn_mfma_f32_16x16x32_bf16(qf[qh][0], tw0, a, 0, 0, 0);
      a = __builtin_amdgcn_mfma_f32_16x16x32_bf16(qf[qh][1], tw1, a, 0, 0, 0);
#pragma unroll
      for (int r = 0; r < 4; ++r)
        rwt[(qh * 16 + lg * 4 + r) * 68 + jt * 16 + lr] = __float2bfloat16(a[r] * L2E);
    }
  }
  float rwreg[2][8];
#pragma unroll
  for (int qh = 0; qh < 2; ++qh) {
    int wq = qh * 16 + lr;                 // (q0 + qh*16 + lr) & 31
#pragma unroll
    for (int i = 0; i < 8; ++i) {
      int k = (i >> 2) * 16 + lg * 4 + (i & 3);
      rwreg[qh][i] = __bfloat162float(rwt[(qh * 16 + lr) * 68 + (wq - k + 31)]);
    }
  }
  __syncthreads();   // all rw reads done before DMA overwrites K/V region; drains vmem

  f32x4 O[2][4] = {};
  float m_[2] = {-1e30f, -1e30f};
  float lsum[2] = {0.f, 0.f};
  const float C = 0.125f * L2E;
  char* pc = lds + 32768 + w * 2048;       // P tile: [16 rows][8 slots x 16B] swizzled
  char* vcb = lds + 16384;                 // V single buffer

  // DMA staging geometry: wave w stages K rows [16w,16w+16) and V rows same.
  int g_ = lane >> 3;                      // row-in-8
  int colb = ((lane & 7) ^ g_) * 8;        // pre-swizzled source col

  // ---- prologue: stage chunk-0 K into buf 0 (2 ops/wave, left in flight) ----
#pragma unroll
  for (int i = 0; i < 2; ++i) {
    int op = 2 * w + i;                    // 0..7; each op = 1024 B
    gload16(&Kb[(size_t)(op * 8 + g_) * 64 + colb], lds + op * 1024);
  }

  int cur = 0;
#pragma unroll 1
  for (int kv0 = 0; kv0 < 1024; kv0 += 64) {
    __builtin_amdgcn_sched_barrier(0);
    __builtin_amdgcn_s_barrier();          // A: PV(prev) done; Kl[cur^1] reads done
    // ---- issue V_cur into the single V buffer (2 ops/wave) ----
#pragma unroll
    for (int i = 0; i < 2; ++i) {
      int op = 2 * w + i;
      gload16(&Vb[(size_t)(op * 8 + g_) * 1024 + kv0 + colb], vcb + op * 1024);
    }
    // ---- issue K_next into Kl[cur^1] (2 ops/wave; stays in flight all chunk)
    int nkv = (kv0 + 64 < 1024) ? kv0 + 64 : 960;  // last iter: dummy restage
#pragma unroll
    for (int i = 0; i < 2; ++i) {
      int op = 2 * w + i;
      gload16(&Kb[(size_t)(nkv + op * 8 + g_) * 64 + colb], lds + (cur ^ 1) * 8192 + op * 1024);
    }
    // ---- retire this wave's K_cur (keep V_cur + K_next = 4 newest in flight)
    asm volatile("s_waitcnt vmcnt(4)" ::: "memory");
    __builtin_amdgcn_sched_barrier(0);
    __builtin_amdgcn_s_barrier();          // B: ALL waves' K_cur retired
    __builtin_amdgcn_sched_barrier(0);

    const char* kc = lds + cur * 8192;
    // ---- K frags (swizzled ds_read_b128), shared by both q-halves ----
    short8 kf[8];
#pragma unroll
    for (int t = 0; t < 4; ++t)
#pragma unroll
      for (int h = 0; h < 2; ++h)
        kf[2 * t + h] = *(const short8*)(kc + (t * 16 + lr) * 128 + (((h * 4 + lg) ^ xr) * 16));
    // ---- QK^T (swapped): st[qh][t][r] = S[kv0+t*16+lg*4+r][q0+qh*16+lr] ----
    f32x4 st[2][4];
#pragma unroll
    for (int t = 0; t < 4; ++t)
#pragma unroll
      for (int qh = 0; qh < 2; ++qh) {
        f32x4 z = {};
        z = __builtin_amdgcn_mfma_f32_16x16x32_bf16(kf[2 * t], qf[qh][0], z, 0, 0, 0);
        z = __builtin_amdgcn_mfma_f32_16x16x32_bf16(kf[2 * t + 1], qf[qh][1], z, 0, 0, 0);
        st[qh][t] = z;
      }
    // ---- bias add (log2 domain) + in-lane max; rh pair read (swizzled slot) ----
    int s_ = kv0 >> 6;                     // u32 pair slot (kh = 2*s_, kh+1)
    float mxl[2];
#pragma unroll
    for (int qh = 0; qh < 2; ++qh) {
      int q = qh * 16 + lr;
      unsigned bu = *(const unsigned*)(rhb + q * 64 + ((s_ ^ (q & 15)) << 2));
      float bh0 = __uint_as_float(bu << 16);
      float bh1 = __uint_as_float(bu & 0xffff0000u);
      float mx = -1e30f;
#pragma unroll
      for (int t = 0; t < 4; ++t)
#pragma unroll
        for (int r = 0; r < 4; ++r) {
          float sv = fmaf(st[qh][t][r], C, ((t < 2) ? bh0 : bh1) + rwreg[qh][(t & 1) * 4 + r]);
          st[qh][t][r] = sv;
          mx = fmaxf(mx, sv);
        }
      mxl[qh] = mx;
    }
    // ---- defer-max rescale (rare) ----
    int cond = (mxl[0] <= m_[0] + 8.f) && (mxl[1] <= m_[1] + 8.f);
    if (!__all(cond)) {
#pragma unroll
      for (int qh = 0; qh < 2; ++qh) {
        float mw = fmaxf(mxl[qh], __shfl_xor(mxl[qh], 16, 64));
        mw = fmaxf(mw, __shfl_xor(mw, 32, 64));
        float mnew = fmaxf(m_[qh], mw);
        float al = exp2f(m_[qh] - mnew);
        lsum[qh] *= al;
        m_[qh] = mnew;
#pragma unroll
        for (int r = 0; r < 4; ++r) {
          float av = __shfl(al, lg * 4 + r, 64);
#pragma unroll
          for (int dt = 0; dt < 4; ++dt) O[qh][dt][r] *= av;
        }
      }
    }
    // ---- exp2 + per-lane partial sum + truncation-pack; P tile reused per qh
    short8 pf[2][2];
#pragma unroll
    for (int qh = 0; qh < 2; ++qh) {
      float mq = m_[qh];
      float sa = 0.f;
#pragma unroll
      for (int t = 0; t < 4; ++t) {
        float p0 = exp2f(st[qh][t][0] - mq);
        float p1 = exp2f(st[qh][t][1] - mq);
        float p2 = exp2f(st[qh][t][2] - mq);
        float p3 = exp2f(st[qh][t][3] - mq);
        sa += (p0 + p1) + (p2 + p3);
        uint2 wv;
        wv.x = packtrunc(p0, p1);
        wv.y = packtrunc(p2, p3);
        int slot = (2 * t + (lg >> 1)) ^ xr;
        *(uint2*)(pc + lr * 128 + slot * 16 + (lg & 1) * 8) = wv;
      }
      lsum[qh] += sa;
      // read this half's P A-frags before overwriting the tile (same-wave DS order)
      pf[qh][0] = *(const short8*)(pc + lr * 128 + (((0 + lg) ^ xr) * 16));
      pf[qh][1] = *(const short8*)(pc + lr * 128 + (((4 + lg) ^ xr) * 16));
    }
    // ---- retire V_cur (K_next stays in flight), then all-waves barrier ----
    asm volatile("s_waitcnt vmcnt(2)" ::: "memory");
    __builtin_amdgcn_sched_barrier(0);
    __builtin_amdgcn_s_barrier();          // C: ALL waves' V_cur retired
    __builtin_amdgcn_sched_barrier(0);
    // ---- PV: vf reads shared by both q-halves ----
#pragma unroll
    for (int dt = 0; dt < 4; ++dt) {
      short8 vf0 = *(const short8*)(vcb + (dt * 16 + lr) * 128 + (((0 + lg) ^ xr) * 16));
      short8 vf1 = *(const short8*)(vcb + (dt * 16 + lr) * 128 + (((4 + lg) ^ xr) * 16));
#pragma unroll
      for (int qh = 0; qh < 2; ++qh) {
        O[qh][dt] = __builtin_amdgcn_mfma_f32_16x16x32_bf16(pf[qh][0], vf0, O[qh][dt], 0, 0, 0);
        O[qh][dt] = __builtin_amdgcn_mfma_f32_16x16x32_bf16(pf[qh][1], vf1, O[qh][dt], 0, 0, 0);
      }
    }
    cur ^= 1;
  }

  // epilogue: reduce deferred l, then faithful out permutation (verified in R0)
#pragma unroll
  for (int qh = 0; qh < 2; ++qh) {
    float lt = lsum[qh];
    lt += __shfl_xor(lt, 16, 64);
    lt += __shfl_xor(lt, 32, 64);
    float linv = 1.f / lt;
#pragma unroll
    for (int r = 0; r < 4; ++r) {
      float lv = __shfl(linv, lg * 4 + r, 64);
      int n = q0 + qh * 16 + lg * 4 + r;
#pragma unroll
      for (int dt = 0; dt < 4; ++dt) {
        int d = dt * 16 + lr;
        int Sidx = bh * 65536 + n * 64 + d;
        int b = Sidx / 786432, r1 = Sidx % 786432;
        int pp = r1 / 24576, r2 = r1 % 24576;
        int qq = r2 / 768, r3 = r2 % 768;
        int j = r3 >> 6, dd = r3 & 63;
        int P = b * 786432 + j * 65536 + pp * 2048 + qq * 64 + dd;
        outp[P] = __float2bfloat16(O[qh][dt][r] * lv);
      }
    }
  }
}

extern "C" void kernel_launch(void* const* d_in, const int* in_sizes, int n_in,
                              void* d_out, int out_size, void* d_ws, size_t ws_size,
                              hipStream_t stream) {
  const float* x     = (const float*)d_in[0];
  const float* Wqkv  = (const float*)d_in[1];
  const float* bqkv  = (const float*)d_in[2];
  const float* Wproj = (const float*)d_in[3];
  const float* bproj = (const float*)d_in[4];
  const float* rph   = (const float*)d_in[5];
  const float* rpw   = (const float*)d_in[6];
  float* out = (float*)d_out;
  char* ws = (char*)d_ws;

  __hip_bfloat16* xb     = (__hip_bfloat16*)(ws);
  __hip_bfloat16* wqkvT  = (__hip_bfloat16*)(ws + 12582912);
  __hip_bfloat16* wprojT = (__hip_bfloat16*)(ws + 16121856);
  __hip_bfloat16* qkvb   = (__hip_bfloat16*)(ws + 17301504);  // later aliased as attn-out
  __hip_bfloat16* Qm     = (__hip_bfloat16*)(ws + 55050240);
  __hip_bfloat16* Km     = (__hip_bfloat16*)(ws + 67633152);
  __hip_bfloat16* Vtm    = (__hip_bfloat16*)(ws + 80216064);

  cast_f32_bf16<<<dim3(6144), dim3(256), 0, stream>>>(x, xb);
  transpose_cast<<<dim3(72, 24), dim3(256), 0, stream>>>(Wqkv, wqkvT, 768, 2304);
  transpose_cast<<<dim3(24, 24), dim3(256), 0, stream>>>(Wproj, wprojT, 768, 768);
  gemm_dma<128, true><<<dim3(18, 64), dim3(256), 0, stream>>>(xb, wqkvT, bqkv, (void*)qkvb, 2304, 768);
  permute_v2<<<dim3(16, 96), dim3(256), 0, stream>>>(qkvb, Qm, Km, Vtm);
  attn12<<<dim3(768), dim3(256), 0, stream>>>(Qm, Km, Vtm, rph, rpw, qkvb);
  gemm_dma<64, false><<<dim3(6, 128), dim3(256), 0, stream>>>(qkvb, wprojT, bproj, (void*)out, 768, 768);
}

// Round 16
// 174.716 us; speedup vs baseline: 1.8130x; 1.0082x over previous
//
#include <hip/hip_runtime.h>
#include <hip/hip_bf16.h>

// Shapes (fixed): B=8, H=W=32, E=768, nh=12, hd=64, N=1024, BH=96
// ws layout (bytes):
//   xb      @ 0          : 12,582,912  (x cast to bf16)
//   wqkvT   @ 12582912   :  3,538,944  (Wqkv^T bf16)
//   wprojT  @ 16121856   :  1,179,648  (Wproj^T bf16)
//   qkvb    @ 17301504   : 37,748,736  (qkv bf16; later aliased by attn-out bf16)
//   Q       @ 55050240   : 12,582,912
//   K       @ 67633152   : 12,582,912
//   Vt      @ 80216064   : 12,582,912  (V transposed: [bh][d][n])

typedef __attribute__((ext_vector_type(8))) short short8;
typedef __attribute__((ext_vector_type(4))) float f32x4;

__global__ __launch_bounds__(256) void cast_f32_bf16(const float* __restrict__ in,
                                                     __hip_bfloat16* __restrict__ out) {
  int i = (blockIdx.x * 256 + threadIdx.x) * 4;
  float4 v = *(const float4*)&in[i];
  out[i + 0] = __float2bfloat16(v.x);
  out[i + 1] = __float2bfloat16(v.y);
  out[i + 2] = __float2bfloat16(v.z);
  out[i + 3] = __float2bfloat16(v.w);
}

// in [K][N] f32 -> out [N][K] bf16
__global__ __launch_bounds__(256) void transpose_cast(const float* __restrict__ in,
                                                      __hip_bfloat16* __restrict__ out,
                                                      int K, int N) {
  __shared__ float tile[32][33];
  int n0 = blockIdx.x * 32, k0 = blockIdx.y * 32;
  int tx = threadIdx.x & 31, ty = threadIdx.x >> 5;  // 32 x 8
#pragma unroll
  for (int i = 0; i < 4; ++i)
    tile[ty + i * 8][tx] = in[(size_t)(k0 + ty + i * 8) * N + n0 + tx];
  __syncthreads();
#pragma unroll
  for (int i = 0; i < 4; ++i)
    out[(size_t)(n0 + ty + i * 8) * K + k0 + tx] = __float2bfloat16(tile[tx][ty + i * 8]);
}

__device__ inline void gload16(const void* g, void* l) {
  __builtin_amdgcn_global_load_lds((const __attribute__((address_space(1))) void*)g,
                                   (__attribute__((address_space(3))) void*)l, 16, 0, 0);
}

// C[M,N] = A[M,K]*Bt[N,K]^T + bias ; BMx128 tile (BM=128 or 64), 4 waves (2x2),
// BK=64, staging via global_load_lds width=16 into linear LDS (m97 structure).
template<int BM, bool OUT_BF16>
__global__ __launch_bounds__(256) void gemm_dma(const __hip_bfloat16* __restrict__ A,
                                                const __hip_bfloat16* __restrict__ Bt,
                                                const float* __restrict__ bias,
                                                void* __restrict__ Cout,
                                                int N, int K) {
  constexpr int FM = BM / 32;               // m-frags per wave (4 or 2)
  __shared__ __hip_bfloat16 Al[BM * 64];
  __shared__ __hip_bfloat16 Bl[128 * 64];
  int n0 = blockIdx.x * 128, m0 = blockIdx.y * BM;
  int tid = threadIdx.x, lane = tid & 63, wid = tid >> 6;
  int wm = wid >> 1, wn = wid & 1;
  int lr = lane & 15, lg = lane >> 4;
  int row_l = lane >> 3, col8 = (lane & 7) * 8;
  f32x4 acc[FM][4] = {};
  for (int k0 = 0; k0 < K; k0 += 64) {
#pragma unroll
    for (int j = 0; j < BM / 32; ++j) {     // A: BM*8/64 chunks over 4 waves
      int jj = wid * (BM / 32) + j;
      int arow = jj * 8 + row_l;
      gload16(&A[(size_t)(m0 + arow) * K + k0 + col8], &Al[jj * 512]);
    }
#pragma unroll
    for (int j = 0; j < 4; ++j) {           // B: 16 chunks over 4 waves
      int jj = wid * 4 + j;
      int brow = jj * 8 + row_l;
      gload16(&Bt[(size_t)(n0 + brow) * K + k0 + col8], &Bl[jj * 512]);
    }
    __syncthreads();  // drains vmcnt (DMA writes) per compiler barrier semantics
#pragma unroll
    for (int ks = 0; ks < 2; ++ks) {
      short8 af[FM], bfr[4];
#pragma unroll
      for (int m = 0; m < FM; ++m)
        af[m] = *(const short8*)&Al[(wm * (BM / 2) + m * 16 + lr) * 64 + ks * 32 + lg * 8];
#pragma unroll
      for (int n = 0; n < 4; ++n)
        bfr[n] = *(const short8*)&Bl[(wn * 64 + n * 16 + lr) * 64 + ks * 32 + lg * 8];
#pragma unroll
      for (int m = 0; m < FM; ++m)
#pragma unroll
        for (int n = 0; n < 4; ++n)
          acc[m][n] = __builtin_amdgcn_mfma_f32_16x16x32_bf16(af[m], bfr[n], acc[m][n], 0, 0, 0);
    }
    __syncthreads();
  }
#pragma unroll
  for (int n = 0; n < 4; ++n) {
    int col = n0 + wn * 64 + n * 16 + lr;
    float bv = bias[col];
#pragma unroll
    for (int m = 0; m < FM; ++m) {
      int rowb = m0 + wm * (BM / 2) + m * 16 + lg * 4;
#pragma unroll
      for (int r = 0; r < 4; ++r) {
        float v = acc[m][n][r] + bv;
        if (OUT_BF16)
          ((__hip_bfloat16*)Cout)[(size_t)(rowb + r) * N + col] = __float2bfloat16(v);
        else
          ((float*)Cout)[(size_t)(rowb + r) * N + col] = v;
      }
    }
  }
}

// permute_qkv v2 (verified R8): per dest (bh,n2) the CONTIGUOUS source window
// qkv_flat[(bh*1024+n2)*192 .. +192) with fixed intra-window permutation
// src_off(u) = (u&63)*3 + (u>>6), u = d2*3 + c2.
__global__ __launch_bounds__(256) void permute_v2(const __hip_bfloat16* __restrict__ qkv,
                                                  __hip_bfloat16* __restrict__ Q,
                                                  __hip_bfloat16* __restrict__ Kd,
                                                  __hip_bfloat16* __restrict__ Vt) {
  int bh = blockIdx.y, n0 = blockIdx.x * 64;
  int tid = threadIdx.x;
  __shared__ short raw[64 * 200];     // window wi stride 200 (pad)
  __shared__ short vt[64][72];
  const short* src = (const short*)qkv + (size_t)(bh * 1024 + n0) * 192;
#pragma unroll
  for (int i = 0; i < 6; ++i) {
    int c16 = tid + i * 256;          // 0..1535
    int wi = c16 / 24, off = (c16 % 24) * 8;
    *(short8*)&raw[wi * 200 + off] = *(const short8*)&src[(size_t)c16 * 8];
  }
  __syncthreads();
  int wi = tid >> 2, g4 = tid & 3;
  const short* rw_ = &raw[wi * 200];
  short8 qv[2], kv_[2];
#pragma unroll
  for (int half = 0; half < 2; ++half)
#pragma unroll
    for (int j = 0; j < 8; ++j) {
      int d2 = g4 * 16 + half * 8 + j;
      int u = 3 * d2;
      qv[half][j]  = rw_[((u) & 63) * 3 + ((u) >> 6)];
      kv_[half][j] = rw_[((u + 1) & 63) * 3 + ((u + 1) >> 6)];
      vt[d2][wi]   = rw_[((u + 2) & 63) * 3 + ((u + 2) >> 6)];
    }
  size_t base = (size_t)bh * 65536 + (size_t)(n0 + wi) * 64 + g4 * 16;
  *(short8*)&Q[base] = qv[0];
  *(short8*)&Q[base + 8] = qv[1];
  *(short8*)&Kd[base] = kv_[0];
  *(short8*)&Kd[base + 8] = kv_[1];
  __syncthreads();
  int d2r = tid >> 2;
  size_t vbase = (size_t)bh * 65536 + (size_t)d2r * 1024 + n0 + g4 * 16;
  *(short8*)&Vt[vbase]     = *(const short8*)&vt[d2r][g4 * 16];
  *(short8*)&Vt[vbase + 8] = *(const short8*)&vt[d2r][g4 * 16 + 8];
}

__device__ inline short8 cvt8(const float* p) {
  short8 r;
#pragma unroll
  for (int j = 0; j < 8; ++j) {
    __hip_bfloat16 b = __float2bfloat16(p[j]);
    r[j] = *reinterpret_cast<const short*>(&b);
  }
  return r;
}

// truncation pack: [b_hi16 | a_hi16] in one v_perm_b32 (valid: P>=0, no NaN).
__device__ inline unsigned packtrunc(float a, float b) {
  return __builtin_amdgcn_perm(__float_as_uint(b), __float_as_uint(a), 0x07060302u);
}

// Flash attention v13: 8 waves/block (512 thr), 16 q-rows/wave, grid 768
// (3 blocks/CU resident -> 24 waves/CU = 6/SIMD; R14's 17.6% occupancy was
// grid-limited at 3 blocks x 4 waves). Shared K/V staging: each wave stages
// 1 K-op + 1 V-op per chunk. LDS 49152 B: K dbuf 16K + V 8K + rh 8x1K + P 8x2K.
// Counted-vmcnt protocol (validated R11): {barrier A -> issue V_cur + K_next ->
// vmcnt(2) [K_cur ready] -> barrier B -> QK^T/softmax -> vmcnt(1) [V_cur
// ready; K_next in flight] -> barrier C -> PV}.
#define L2E 1.44269504088896f
__global__ __launch_bounds__(512) void attn13(const __hip_bfloat16* __restrict__ Q,
                                              const __hip_bfloat16* __restrict__ Kd,
                                              const __hip_bfloat16* __restrict__ Vt,
                                              const float* __restrict__ rph,
                                              const float* __restrict__ rpw,
                                              __hip_bfloat16* __restrict__ outp) {
  int orig = blockIdx.x;                   // 768 = 8 xcd * 96
  int xcd = orig & 7, loc = orig >> 3;     // 96 per xcd
  int bh = xcd * 12 + (loc % 12);
  int qt = loc / 12;                       // 0..7 (128-row q tile)
  int tid = threadIdx.x;
  int lane = tid & 63, w = tid >> 6;       // w in [0,8)
  int lr = lane & 15, lg = lane >> 4;
  int xr = lr & 7;

  // Carved LDS, 49152 B total (3 blocks/CU; 24 waves/CU):
  //   [    0,16384): K dbuf  [buf][64 rows][128B], swizzled (wave w -> byte w*1024)
  //   [16384,24576): V single [64 rows][128B], swizzled
  //   [24576,32768): rh, 8 waves x [16 q][16 u32-slots], slot s at s^(q&15)
  //   [32768,49152): P scratch, 8 waves x 2048B
  //   prologue rw staging: wave w at [w*2176, +2176) inside K∪V region
  __shared__ __align__(16) char lds[49152];

  const __hip_bfloat16* Qb = Q + (size_t)bh * 65536;
  const __hip_bfloat16* Kb = Kd + (size_t)bh * 65536;
  const __hip_bfloat16* Vb = Vt + (size_t)bh * 65536;

  int q0 = qt * 128 + w * 16;              // this wave's 16 q-rows
  int hq = q0 >> 5;                        // = qt*4 + (w>>1)
  int wq_lane = (q0 & 31) + lr;            // = (w&1)*16 + lr

  short8 qf0 = *(const short8*)&Qb[(size_t)(q0 + lr) * 64 + lg * 8];
  short8 qf1 = *(const short8*)&Qb[(size_t)(q0 + lr) * 64 + 32 + lg * 8];

  // ---- rel-pos bias via MFMA (pre-scaled by L2E); swizzled-slot store ----
  char* rhb = lds + 24576 + w * 1024;      // [16 q][64B], pair-slot swizzled
#pragma unroll
  for (int kt = 0; kt < 2; ++kt) {
    int row = hq - (kt * 16 + lr) + 31;    // 0..62
    const float* tp = rph + (size_t)row * 64 + lg * 8;
    short8 th0 = cvt8(tp), th1 = cvt8(tp + 32);
    f32x4 a = {};
    a = __builtin_amdgcn_mfma_f32_16x16x32_bf16(qf0, th0, a, 0, 0, 0);
    a = __builtin_amdgcn_mfma_f32_16x16x32_bf16(qf1, th1, a, 0, 0, 0);
#pragma unroll
    for (int r = 0; r < 4; ++r) {
      int q = lg * 4 + r;                  // 0..15
      int e = kt * 16 + lr;                // kh element 0..31
      int sw = ((e >> 1) ^ q) << 2;
      *(__hip_bfloat16*)(rhb + q * 64 + sw + (e & 1) * 2) = __float2bfloat16(a[r] * L2E);
    }
  }
  // rw staging in the (still dead) K/V region: wave w at byte w*2176, [16][68] bf16
  __hip_bfloat16* rwt = (__hip_bfloat16*)(lds + w * 2176);
#pragma unroll
  for (int jt = 0; jt < 4; ++jt) {
    const float* tp = rpw + (size_t)(jt * 16 + lr) * 64 + lg * 8;
    short8 tw0 = cvt8(tp), tw1 = cvt8(tp + 32);
    f32x4 a = {};
    a = __builtin_amdgcn_mfma_f32_16x16x32_bf16(qf0, tw0, a, 0, 0, 0);
    a = __builtin_amdgcn_mfma_f32_16x16x32_bf16(qf1, tw1, a, 0, 0, 0);
#pragma unroll
    for (int r = 0; r < 4; ++r)
      rwt[(lg * 4 + r) * 68 + jt * 16 + lr] = __float2bfloat16(a[r] * L2E);
  }
  float rwreg[8];
#pragma unroll
  for (int i = 0; i < 8; ++i) {
    int k = (i >> 2) * 16 + lg * 4 + (i & 3);
    rwreg[i] = __bfloat162float(rwt[lr * 68 + (wq_lane - k + 31)]);
  }
  __syncthreads();   // all rw reads done before DMA overwrites K/V region; drains vmem

  f32x4 O[4] = {};
  float m_ = -1e30f, lsum = 0.f;
  const float C = 0.125f * L2E;
  char* pc = lds + 32768 + w * 2048;       // P tile: [16 rows][8 slots x 16B] swizzled
  char* vcb = lds + 16384;                 // V single buffer

  // DMA staging geometry: wave w stages K rows [8w,8w+8) and V rows same (1 op each).
  int g_ = lane >> 3;                      // row-in-8
  int colb = ((lane & 7) ^ g_) * 8;        // pre-swizzled source col

  // ---- prologue: stage chunk-0 K into buf 0 (1 op/wave, left in flight) ----
  gload16(&Kb[(size_t)(w * 8 + g_) * 64 + colb], lds + w * 1024);

  int cur = 0;
#pragma unroll 1
  for (int kv0 = 0; kv0 < 1024; kv0 += 64) {
    __builtin_amdgcn_sched_barrier(0);
    __builtin_amdgcn_s_barrier();          // A: PV(prev) done; K[cur^1] reads done
    // ---- issue V_cur (1 op) and K_next (1 op); both stay counted ----
    gload16(&Vb[(size_t)(w * 8 + g_) * 1024 + kv0 + colb], vcb + w * 1024);
    int nkv = (kv0 + 64 < 1024) ? kv0 + 64 : 960;  // last iter: dummy restage
    gload16(&Kb[(size_t)(nkv + w * 8 + g_) * 64 + colb], lds + (cur ^ 1) * 8192 + w * 1024);
    // ---- retire this wave's K_cur (keep V_cur + K_next = 2 newest in flight)
    asm volatile("s_waitcnt vmcnt(2)" ::: "memory");
    __builtin_amdgcn_sched_barrier(0);
    __builtin_amdgcn_s_barrier();          // B: ALL waves' K_cur retired
    __builtin_amdgcn_sched_barrier(0);

    const char* kc = lds + cur * 8192;
    // ---- K frags (swizzled ds_read_b128) ----
    short8 kf[8];
#pragma unroll
    for (int t = 0; t < 4; ++t)
#pragma unroll
      for (int h = 0; h < 2; ++h)
        kf[2 * t + h] = *(const short8*)(kc + (t * 16 + lr) * 128 + (((h * 4 + lg) ^ xr) * 16));
    // ---- QK^T (swapped): st[t][r] = S[kv=kv0+t*16+lg*4+r][q=q0+lr] ----
    f32x4 st[4];
#pragma unroll
    for (int t = 0; t < 4; ++t) {
      f32x4 z = {};
      z = __builtin_amdgcn_mfma_f32_16x16x32_bf16(kf[2 * t], qf0, z, 0, 0, 0);
      z = __builtin_amdgcn_mfma_f32_16x16x32_bf16(kf[2 * t + 1], qf1, z, 0, 0, 0);
      st[t] = z;
    }
    // ---- bias add (log2 domain) + in-lane max; rh pair read (swizzled slot) ----
    int s_ = kv0 >> 6;                     // u32 pair slot (kh = 2*s_, 2*s_+1)
    unsigned bu = *(const unsigned*)(rhb + lr * 64 + ((s_ ^ lr) << 2));
    float bh0 = __uint_as_float(bu << 16);
    float bh1 = __uint_as_float(bu & 0xffff0000u);
    float mx = -1e30f;
#pragma unroll
    for (int t = 0; t < 4; ++t)
#pragma unroll
      for (int r = 0; r < 4; ++r) {
        float sv = fmaf(st[t][r], C, ((t < 2) ? bh0 : bh1) + rwreg[(t & 1) * 4 + r]);
        st[t][r] = sv;
        mx = fmaxf(mx, sv);
      }
    // ---- defer-max rescale (rare) ----
    if (!__all(mx <= m_ + 8.f)) {
      float mw = fmaxf(mx, __shfl_xor(mx, 16, 64));
      mw = fmaxf(mw, __shfl_xor(mw, 32, 64));
      float mnew = fmaxf(m_, mw);
      float al = exp2f(m_ - mnew);
      lsum *= al;
      m_ = mnew;
#pragma unroll
      for (int r = 0; r < 4; ++r) {
        float av = __shfl(al, lg * 4 + r, 64);
#pragma unroll
        for (int dt = 0; dt < 4; ++dt) O[dt][r] *= av;
      }
    }
    // ---- exp2 + per-lane partial sum + truncation-pack to swizzled P tile ----
    float sa = 0.f;
#pragma unroll
    for (int t = 0; t < 4; ++t) {
      float p0 = exp2f(st[t][0] - m_);
      float p1 = exp2f(st[t][1] - m_);
      float p2 = exp2f(st[t][2] - m_);
      float p3 = exp2f(st[t][3] - m_);
      sa += (p0 + p1) + (p2 + p3);
      uint2 wv;
      wv.x = packtrunc(p0, p1);
      wv.y = packtrunc(p2, p3);
      int slot = (2 * t + (lg >> 1)) ^ xr;
      *(uint2*)(pc + lr * 128 + slot * 16 + (lg & 1) * 8) = wv;
    }
    lsum += sa;
    // ---- P frags (same-wave DS ordering; no barrier needed) ----
    short8 pf0 = *(const short8*)(pc + lr * 128 + (((0 + lg) ^ xr) * 16));
    short8 pf1 = *(const short8*)(pc + lr * 128 + (((4 + lg) ^ xr) * 16));
    // ---- retire V_cur (K_next stays in flight), then all-waves barrier ----
    asm volatile("s_waitcnt vmcnt(1)" ::: "memory");
    __builtin_amdgcn_sched_barrier(0);
    __builtin_amdgcn_s_barrier();          // C: ALL waves' V_cur retired
    __builtin_amdgcn_sched_barrier(0);
    // ---- PV ----
#pragma unroll
    for (int dt = 0; dt < 4; ++dt) {
      short8 vf0 = *(const short8*)(vcb + (dt * 16 + lr) * 128 + (((0 + lg) ^ xr) * 16));
      short8 vf1 = *(const short8*)(vcb + (dt * 16 + lr) * 128 + (((4 + lg) ^ xr) * 16));
      O[dt] = __builtin_amdgcn_mfma_f32_16x16x32_bf16(pf0, vf0, O[dt], 0, 0, 0);
      O[dt] = __builtin_amdgcn_mfma_f32_16x16x32_bf16(pf1, vf1, O[dt], 0, 0, 0);
    }
    cur ^= 1;
  }

  // epilogue: reduce deferred l, then faithful out permutation (verified in R0)
  float lt = lsum;
  lt += __shfl_xor(lt, 16, 64);
  lt += __shfl_xor(lt, 32, 64);
  float linv = 1.f / lt;
#pragma unroll
  for (int r = 0; r < 4; ++r) {
    float lv = __shfl(linv, lg * 4 + r, 64);
    int n = q0 + lg * 4 + r;
#pragma unroll
    for (int dt = 0; dt < 4; ++dt) {
      int d = dt * 16 + lr;
      int Sidx = bh * 65536 + n * 64 + d;
      int b = Sidx / 786432, r1 = Sidx % 786432;
      int pp = r1 / 24576, r2 = r1 % 24576;
      int qq = r2 / 768, r3 = r2 % 768;
      int j = r3 >> 6, dd = r3 & 63;
      int P = b * 786432 + j * 65536 + pp * 2048 + qq * 64 + dd;
      outp[P] = __float2bfloat16(O[dt][r] * lv);
    }
  }
}

extern "C" void kernel_launch(void* const* d_in, const int* in_sizes, int n_in,
                              void* d_out, int out_size, void* d_ws, size_t ws_size,
                              hipStream_t stream) {
  const float* x     = (const float*)d_in[0];
  const float* Wqkv  = (const float*)d_in[1];
  const float* bqkv  = (const float*)d_in[2];
  const float* Wproj = (const float*)d_in[3];
  const float* bproj = (const float*)d_in[4];
  const float* rph   = (const float*)d_in[5];
  const float* rpw   = (const float*)d_in[6];
  float* out = (float*)d_out;
  char* ws = (char*)d_ws;

  __hip_bfloat16* xb     = (__hip_bfloat16*)(ws);
  __hip_bfloat16* wqkvT  = (__hip_bfloat16*)(ws + 12582912);
  __hip_bfloat16* wprojT = (__hip_bfloat16*)(ws + 16121856);
  __hip_bfloat16* qkvb   = (__hip_bfloat16*)(ws + 17301504);  // later aliased as attn-out
  __hip_bfloat16* Qm     = (__hip_bfloat16*)(ws + 55050240);
  __hip_bfloat16* Km     = (__hip_bfloat16*)(ws + 67633152);
  __hip_bfloat16* Vtm    = (__hip_bfloat16*)(ws + 80216064);

  cast_f32_bf16<<<dim3(6144), dim3(256), 0, stream>>>(x, xb);
  transpose_cast<<<dim3(72, 24), dim3(256), 0, stream>>>(Wqkv, wqkvT, 768, 2304);
  transpose_cast<<<dim3(24, 24), dim3(256), 0, stream>>>(Wproj, wprojT, 768, 768);
  gemm_dma<128, true><<<dim3(18, 64), dim3(256), 0, stream>>>(xb, wqkvT, bqkv, (void*)qkvb, 2304, 768);
  permute_v2<<<dim3(16, 96), dim3(256), 0, stream>>>(qkvb, Qm, Km, Vtm);
  attn13<<<dim3(768), dim3(512), 0, stream>>>(Qm, Km, Vtm, rph, rpw, qkvb);
  gemm_dma<64, false><<<dim3(6, 128), dim3(256), 0, stream>>>(qkvb, wprojT, bproj, (void*)out, 768, 768);
}

// Round 17
// 153.176 us; speedup vs baseline: 2.0680x; 1.1406x over previous
//
#include <hip/hip_runtime.h>
#include <hip/hip_bf16.h>

// Shapes (fixed): B=8, H=W=32, E=768, nh=12, hd=64, N=1024, BH=96
// ws layout (bytes):
//   xb      @ 0          : 12,582,912  (x cast to bf16)
//   wqkvT   @ 12582912   :  3,538,944  (Wqkv^T bf16)
//   wprojT  @ 16121856   :  1,179,648  (Wproj^T bf16)
//   qkvb    @ 17301504   : 37,748,736  (qkv bf16; later aliased by attn-out bf16)
//   Q       @ 55050240   : 12,582,912
//   K       @ 67633152   : 12,582,912
//   Vt      @ 80216064   : 12,582,912  (V transposed: [bh][d][n])

typedef __attribute__((ext_vector_type(8))) short short8;
typedef __attribute__((ext_vector_type(4))) float f32x4;

__global__ __launch_bounds__(256) void cast_f32_bf16(const float* __restrict__ in,
                                                     __hip_bfloat16* __restrict__ out) {
  int i = (blockIdx.x * 256 + threadIdx.x) * 4;
  float4 v = *(const float4*)&in[i];
  out[i + 0] = __float2bfloat16(v.x);
  out[i + 1] = __float2bfloat16(v.y);
  out[i + 2] = __float2bfloat16(v.z);
  out[i + 3] = __float2bfloat16(v.w);
}

// in [K][N] f32 -> out [N][K] bf16
__global__ __launch_bounds__(256) void transpose_cast(const float* __restrict__ in,
                                                      __hip_bfloat16* __restrict__ out,
                                                      int K, int N) {
  __shared__ float tile[32][33];
  int n0 = blockIdx.x * 32, k0 = blockIdx.y * 32;
  int tx = threadIdx.x & 31, ty = threadIdx.x >> 5;  // 32 x 8
#pragma unroll
  for (int i = 0; i < 4; ++i)
    tile[ty + i * 8][tx] = in[(size_t)(k0 + ty + i * 8) * N + n0 + tx];
  __syncthreads();
#pragma unroll
  for (int i = 0; i < 4; ++i)
    out[(size_t)(n0 + ty + i * 8) * K + k0 + tx] = __float2bfloat16(tile[tx][ty + i * 8]);
}

__device__ inline void gload16(const void* g, void* l) {
  __builtin_amdgcn_global_load_lds((const __attribute__((address_space(1))) void*)g,
                                   (__attribute__((address_space(3))) void*)l, 16, 0, 0);
}

// C[M,N] = A[M,K]*Bt[N,K]^T + bias ; BMx128 tile, 4 waves (2x2), BK=64.
// Counted-vmcnt double-buffered pipeline (protocol validated in attn, R11-R15):
// per K-step {barrier -> issue next-tile DMA -> vmcnt(OPW) retiring current
// tile -> barrier -> compute}. LDS XOR-swizzled BOTH sides (same algebra as
// attn staging: physical slot s of row r holds logical col16 s^(r&7)).
template<int BM, bool OUT_BF16>
__global__ __launch_bounds__(256) void gemm_pipe(const __hip_bfloat16* __restrict__ A,
                                                 const __hip_bfloat16* __restrict__ Bt,
                                                 const float* __restrict__ bias,
                                                 void* __restrict__ Cout,
                                                 int N, int K) {
  constexpr int FM = BM / 32;               // m-frags per wave (4 or 2)
  constexpr int ABYTES = BM * 128;          // bytes per A k-tile
  constexpr int AOPW = BM / 32;             // A DMA ops per wave per tile
  __shared__ __align__(16) char lds[2 * ABYTES + 2 * 16384];
  char* Abuf = lds;                         // [2][ABYTES]
  char* Bbuf = lds + 2 * ABYTES;            // [2][16384]
  int n0 = blockIdx.x * 128, m0 = blockIdx.y * BM;
  int tid = threadIdx.x, lane = tid & 63, wid = tid >> 6;
  int wm = wid >> 1, wn = wid & 1;
  int lr = lane & 15, lg = lane >> 4;
  int xr = lr & 7;
  int g_ = lane >> 3;                       // row-in-op (8 rows x 128B per op)
  int colsw = ((lane & 7) ^ g_) * 8;        // pre-swizzled source col (elements)
  f32x4 acc[FM][4] = {};

  // ---- prologue: stage k-tile 0 into buf 0 (AOPW+4 ops/wave, in flight) ----
#pragma unroll
  for (int j = 0; j < AOPW; ++j) {
    int op = wid * AOPW + j;
    gload16(&A[(size_t)(m0 + op * 8 + g_) * K + colsw], Abuf + op * 1024);
  }
#pragma unroll
  for (int j = 0; j < 4; ++j) {
    int op = wid * 4 + j;
    gload16(&Bt[(size_t)(n0 + op * 8 + g_) * K + colsw], Bbuf + op * 1024);
  }

  int cur = 0;
#pragma unroll 1
  for (int k0 = 0; k0 < K; k0 += 64) {
    __builtin_amdgcn_sched_barrier(0);
    __builtin_amdgcn_s_barrier();          // buf^1 reads (tile k-1) complete
    int kn = (k0 + 64 < K) ? k0 + 64 : k0; // last iter: dummy restage
#pragma unroll
    for (int j = 0; j < AOPW; ++j) {
      int op = wid * AOPW + j;
      gload16(&A[(size_t)(m0 + op * 8 + g_) * K + kn + colsw],
              Abuf + (cur ^ 1) * ABYTES + op * 1024);
    }
#pragma unroll
    for (int j = 0; j < 4; ++j) {
      int op = wid * 4 + j;
      gload16(&Bt[(size_t)(n0 + op * 8 + g_) * K + kn + colsw],
              Bbuf + (cur ^ 1) * 16384 + op * 1024);
    }
    // retire this wave's tile-k DMA (keep the AOPW+4 newest in flight)
    if constexpr (BM == 128) asm volatile("s_waitcnt vmcnt(8)" ::: "memory");
    else                     asm volatile("s_waitcnt vmcnt(6)" ::: "memory");
    __builtin_amdgcn_sched_barrier(0);
    __builtin_amdgcn_s_barrier();          // ALL waves' tile-k DMA retired
    __builtin_amdgcn_sched_barrier(0);

    const char* Ac = Abuf + cur * ABYTES;
    const char* Bc = Bbuf + cur * 16384;
#pragma unroll
    for (int ks = 0; ks < 2; ++ks) {
      short8 af[FM], bfr[4];
#pragma unroll
      for (int m = 0; m < FM; ++m) {
        int row = wm * (BM / 2) + m * 16 + lr;
        af[m] = *(const short8*)(Ac + row * 128 + (((ks * 4 + lg) ^ xr) * 16));
      }
#pragma unroll
      for (int n = 0; n < 4; ++n) {
        int row = wn * 64 + n * 16 + lr;
        bfr[n] = *(const short8*)(Bc + row * 128 + (((ks * 4 + lg) ^ xr) * 16));
      }
#pragma unroll
      for (int m = 0; m < FM; ++m)
#pragma unroll
        for (int n = 0; n < 4; ++n)
          acc[m][n] = __builtin_amdgcn_mfma_f32_16x16x32_bf16(af[m], bfr[n], acc[m][n], 0, 0, 0);
    }
    cur ^= 1;
  }
#pragma unroll
  for (int n = 0; n < 4; ++n) {
    int col = n0 + wn * 64 + n * 16 + lr;
    float bv = bias[col];
#pragma unroll
    for (int m = 0; m < FM; ++m) {
      int rowb = m0 + wm * (BM / 2) + m * 16 + lg * 4;
#pragma unroll
      for (int r = 0; r < 4; ++r) {
        float v = acc[m][n][r] + bv;
        if (OUT_BF16)
          ((__hip_bfloat16*)Cout)[(size_t)(rowb + r) * N + col] = __float2bfloat16(v);
        else
          ((float*)Cout)[(size_t)(rowb + r) * N + col] = v;
      }
    }
  }
}

// permute_qkv v2 (verified R8): per dest (bh,n2) the CONTIGUOUS source window
// qkv_flat[(bh*1024+n2)*192 .. +192) with fixed intra-window permutation
// src_off(u) = (u&63)*3 + (u>>6), u = d2*3 + c2.
__global__ __launch_bounds__(256) void permute_v2(const __hip_bfloat16* __restrict__ qkv,
                                                  __hip_bfloat16* __restrict__ Q,
                                                  __hip_bfloat16* __restrict__ Kd,
                                                  __hip_bfloat16* __restrict__ Vt) {
  int bh = blockIdx.y, n0 = blockIdx.x * 64;
  int tid = threadIdx.x;
  __shared__ short raw[64 * 200];     // window wi stride 200 (pad)
  __shared__ short vt[64][72];
  const short* src = (const short*)qkv + (size_t)(bh * 1024 + n0) * 192;
#pragma unroll
  for (int i = 0; i < 6; ++i) {
    int c16 = tid + i * 256;          // 0..1535
    int wi = c16 / 24, off = (c16 % 24) * 8;
    *(short8*)&raw[wi * 200 + off] = *(const short8*)&src[(size_t)c16 * 8];
  }
  __syncthreads();
  int wi = tid >> 2, g4 = tid & 3;
  const short* rw_ = &raw[wi * 200];
  short8 qv[2], kv_[2];
#pragma unroll
  for (int half = 0; half < 2; ++half)
#pragma unroll
    for (int j = 0; j < 8; ++j) {
      int d2 = g4 * 16 + half * 8 + j;
      int u = 3 * d2;
      qv[half][j]  = rw_[((u) & 63) * 3 + ((u) >> 6)];
      kv_[half][j] = rw_[((u + 1) & 63) * 3 + ((u + 1) >> 6)];
      vt[d2][wi]   = rw_[((u + 2) & 63) * 3 + ((u + 2) >> 6)];
    }
  size_t base = (size_t)bh * 65536 + (size_t)(n0 + wi) * 64 + g4 * 16;
  *(short8*)&Q[base] = qv[0];
  *(short8*)&Q[base + 8] = qv[1];
  *(short8*)&Kd[base] = kv_[0];
  *(short8*)&Kd[base + 8] = kv_[1];
  __syncthreads();
  int d2r = tid >> 2;
  size_t vbase = (size_t)bh * 65536 + (size_t)d2r * 1024 + n0 + g4 * 16;
  *(short8*)&Vt[vbase]     = *(const short8*)&vt[d2r][g4 * 16];
  *(short8*)&Vt[vbase + 8] = *(const short8*)&vt[d2r][g4 * 16 + 8];
}

__device__ inline short8 cvt8(const float* p) {
  short8 r;
#pragma unroll
  for (int j = 0; j < 8; ++j) {
    __hip_bfloat16 b = __float2bfloat16(p[j]);
    r[j] = *reinterpret_cast<const short*>(&b);
  }
  return r;
}

// truncation pack: [b_hi16 | a_hi16] in one v_perm_b32 (valid: P>=0, no NaN).
__device__ inline unsigned packtrunc(float a, float b) {
  return __builtin_amdgcn_perm(__float_as_uint(b), __float_as_uint(a), 0x07060302u);
}

// Flash attention v13 (validated R15): 8 waves/block (512 thr), 16 q-rows/wave,
// grid 768. Counted-vmcnt protocol; LDS 49152 B.
#define L2E 1.44269504088896f
__global__ __launch_bounds__(512) void attn13(const __hip_bfloat16* __restrict__ Q,
                                              const __hip_bfloat16* __restrict__ Kd,
                                              const __hip_bfloat16* __restrict__ Vt,
                                              const float* __restrict__ rph,
                                              const float* __restrict__ rpw,
                                              __hip_bfloat16* __restrict__ outp) {
  int orig = blockIdx.x;                   // 768 = 8 xcd * 96
  int xcd = orig & 7, loc = orig >> 3;     // 96 per xcd
  int bh = xcd * 12 + (loc % 12);
  int qt = loc / 12;                       // 0..7 (128-row q tile)
  int tid = threadIdx.x;
  int lane = tid & 63, w = tid >> 6;       // w in [0,8)
  int lr = lane & 15, lg = lane >> 4;
  int xr = lr & 7;

  __shared__ __align__(16) char lds[49152];

  const __hip_bfloat16* Qb = Q + (size_t)bh * 65536;
  const __hip_bfloat16* Kb = Kd + (size_t)bh * 65536;
  const __hip_bfloat16* Vb = Vt + (size_t)bh * 65536;

  int q0 = qt * 128 + w * 16;              // this wave's 16 q-rows
  int hq = q0 >> 5;                        // = qt*4 + (w>>1)
  int wq_lane = (q0 & 31) + lr;            // = (w&1)*16 + lr

  short8 qf0 = *(const short8*)&Qb[(size_t)(q0 + lr) * 64 + lg * 8];
  short8 qf1 = *(const short8*)&Qb[(size_t)(q0 + lr) * 64 + 32 + lg * 8];

  // ---- rel-pos bias via MFMA (pre-scaled by L2E); swizzled-slot store ----
  char* rhb = lds + 24576 + w * 1024;      // [16 q][64B], pair-slot swizzled
#pragma unroll
  for (int kt = 0; kt < 2; ++kt) {
    int row = hq - (kt * 16 + lr) + 31;    // 0..62
    const float* tp = rph + (size_t)row * 64 + lg * 8;
    short8 th0 = cvt8(tp), th1 = cvt8(tp + 32);
    f32x4 a = {};
    a = __builtin_amdgcn_mfma_f32_16x16x32_bf16(qf0, th0, a, 0, 0, 0);
    a = __builtin_amdgcn_mfma_f32_16x16x32_bf16(qf1, th1, a, 0, 0, 0);
#pragma unroll
    for (int r = 0; r < 4; ++r) {
      int q = lg * 4 + r;                  // 0..15
      int e = kt * 16 + lr;                // kh element 0..31
      int sw = ((e >> 1) ^ q) << 2;
      *(__hip_bfloat16*)(rhb + q * 64 + sw + (e & 1) * 2) = __float2bfloat16(a[r] * L2E);
    }
  }
  // rw staging in the (still dead) K/V region: wave w at byte w*2176, [16][68] bf16
  __hip_bfloat16* rwt = (__hip_bfloat16*)(lds + w * 2176);
#pragma unroll
  for (int jt = 0; jt < 4; ++jt) {
    const float* tp = rpw + (size_t)(jt * 16 + lr) * 64 + lg * 8;
    short8 tw0 = cvt8(tp), tw1 = cvt8(tp + 32);
    f32x4 a = {};
    a = __builtin_amdgcn_mfma_f32_16x16x32_bf16(qf0, tw0, a, 0, 0, 0);
    a = __builtin_amdgcn_mfma_f32_16x16x32_bf16(qf1, tw1, a, 0, 0, 0);
#pragma unroll
    for (int r = 0; r < 4; ++r)
      rwt[(lg * 4 + r) * 68 + jt * 16 + lr] = __float2bfloat16(a[r] * L2E);
  }
  float rwreg[8];
#pragma unroll
  for (int i = 0; i < 8; ++i) {
    int k = (i >> 2) * 16 + lg * 4 + (i & 3);
    rwreg[i] = __bfloat162float(rwt[lr * 68 + (wq_lane - k + 31)]);
  }
  __syncthreads();   // all rw reads done before DMA overwrites K/V region; drains vmem

  f32x4 O[4] = {};
  float m_ = -1e30f, lsum = 0.f;
  const float C = 0.125f * L2E;
  char* pc = lds + 32768 + w * 2048;       // P tile: [16 rows][8 slots x 16B] swizzled
  char* vcb = lds + 16384;                 // V single buffer

  int g_ = lane >> 3;                      // row-in-8
  int colb = ((lane & 7) ^ g_) * 8;        // pre-swizzled source col

  // ---- prologue: stage chunk-0 K into buf 0 (1 op/wave, left in flight) ----
  gload16(&Kb[(size_t)(w * 8 + g_) * 64 + colb], lds + w * 1024);

  int cur = 0;
#pragma unroll 1
  for (int kv0 = 0; kv0 < 1024; kv0 += 64) {
    __builtin_amdgcn_sched_barrier(0);
    __builtin_amdgcn_s_barrier();          // A: PV(prev) done; K[cur^1] reads done
    gload16(&Vb[(size_t)(w * 8 + g_) * 1024 + kv0 + colb], vcb + w * 1024);
    int nkv = (kv0 + 64 < 1024) ? kv0 + 64 : 960;  // last iter: dummy restage
    gload16(&Kb[(size_t)(nkv + w * 8 + g_) * 64 + colb], lds + (cur ^ 1) * 8192 + w * 1024);
    asm volatile("s_waitcnt vmcnt(2)" ::: "memory");
    __builtin_amdgcn_sched_barrier(0);
    __builtin_amdgcn_s_barrier();          // B: ALL waves' K_cur retired
    __builtin_amdgcn_sched_barrier(0);

    const char* kc = lds + cur * 8192;
    short8 kf[8];
#pragma unroll
    for (int t = 0; t < 4; ++t)
#pragma unroll
      for (int h = 0; h < 2; ++h)
        kf[2 * t + h] = *(const short8*)(kc + (t * 16 + lr) * 128 + (((h * 4 + lg) ^ xr) * 16));
    f32x4 st[4];
#pragma unroll
    for (int t = 0; t < 4; ++t) {
      f32x4 z = {};
      z = __builtin_amdgcn_mfma_f32_16x16x32_bf16(kf[2 * t], qf0, z, 0, 0, 0);
      z = __builtin_amdgcn_mfma_f32_16x16x32_bf16(kf[2 * t + 1], qf1, z, 0, 0, 0);
      st[t] = z;
    }
    int s_ = kv0 >> 6;
    unsigned bu = *(const unsigned*)(rhb + lr * 64 + ((s_ ^ lr) << 2));
    float bh0 = __uint_as_float(bu << 16);
    float bh1 = __uint_as_float(bu & 0xffff0000u);
    float mx = -1e30f;
#pragma unroll
    for (int t = 0; t < 4; ++t)
#pragma unroll
      for (int r = 0; r < 4; ++r) {
        float sv = fmaf(st[t][r], C, ((t < 2) ? bh0 : bh1) + rwreg[(t & 1) * 4 + r]);
        st[t][r] = sv;
        mx = fmaxf(mx, sv);
      }
    if (!__all(mx <= m_ + 8.f)) {
      float mw = fmaxf(mx, __shfl_xor(mx, 16, 64));
      mw = fmaxf(mw, __shfl_xor(mw, 32, 64));
      float mnew = fmaxf(m_, mw);
      float al = exp2f(m_ - mnew);
      lsum *= al;
      m_ = mnew;
#pragma unroll
      for (int r = 0; r < 4; ++r) {
        float av = __shfl(al, lg * 4 + r, 64);
#pragma unroll
        for (int dt = 0; dt < 4; ++dt) O[dt][r] *= av;
      }
    }
    float sa = 0.f;
#pragma unroll
    for (int t = 0; t < 4; ++t) {
      float p0 = exp2f(st[t][0] - m_);
      float p1 = exp2f(st[t][1] - m_);
      float p2 = exp2f(st[t][2] - m_);
      float p3 = exp2f(st[t][3] - m_);
      sa += (p0 + p1) + (p2 + p3);
      uint2 wv;
      wv.x = packtrunc(p0, p1);
      wv.y = packtrunc(p2, p3);
      int slot = (2 * t + (lg >> 1)) ^ xr;
      *(uint2*)(pc + lr * 128 + slot * 16 + (lg & 1) * 8) = wv;
    }
    lsum += sa;
    short8 pf0 = *(const short8*)(pc + lr * 128 + (((0 + lg) ^ xr) * 16));
    short8 pf1 = *(const short8*)(pc + lr * 128 + (((4 + lg) ^ xr) * 16));
    asm volatile("s_waitcnt vmcnt(1)" ::: "memory");
    __builtin_amdgcn_sched_barrier(0);
    __builtin_amdgcn_s_barrier();          // C: ALL waves' V_cur retired
    __builtin_amdgcn_sched_barrier(0);
#pragma unroll
    for (int dt = 0; dt < 4; ++dt) {
      short8 vf0 = *(const short8*)(vcb + (dt * 16 + lr) * 128 + (((0 + lg) ^ xr) * 16));
      short8 vf1 = *(const short8*)(vcb + (dt * 16 + lr) * 128 + (((4 + lg) ^ xr) * 16));
      O[dt] = __builtin_amdgcn_mfma_f32_16x16x32_bf16(pf0, vf0, O[dt], 0, 0, 0);
      O[dt] = __builtin_amdgcn_mfma_f32_16x16x32_bf16(pf1, vf1, O[dt], 0, 0, 0);
    }
    cur ^= 1;
  }

  float lt = lsum;
  lt += __shfl_xor(lt, 16, 64);
  lt += __shfl_xor(lt, 32, 64);
  float linv = 1.f / lt;
#pragma unroll
  for (int r = 0; r < 4; ++r) {
    float lv = __shfl(linv, lg * 4 + r, 64);
    int n = q0 + lg * 4 + r;
#pragma unroll
    for (int dt = 0; dt < 4; ++dt) {
      int d = dt * 16 + lr;
      int Sidx = bh * 65536 + n * 64 + d;
      int b = Sidx / 786432, r1 = Sidx % 786432;
      int pp = r1 / 24576, r2 = r1 % 24576;
      int qq = r2 / 768, r3 = r2 % 768;
      int j = r3 >> 6, dd = r3 & 63;
      int P = b * 786432 + j * 65536 + pp * 2048 + qq * 64 + dd;
      outp[P] = __float2bfloat16(O[dt][r] * lv);
    }
  }
}

extern "C" void kernel_launch(void* const* d_in, const int* in_sizes, int n_in,
                              void* d_out, int out_size, void* d_ws, size_t ws_size,
                              hipStream_t stream) {
  const float* x     = (const float*)d_in[0];
  const float* Wqkv  = (const float*)d_in[1];
  const float* bqkv  = (const float*)d_in[2];
  const float* Wproj = (const float*)d_in[3];
  const float* bproj = (const float*)d_in[4];
  const float* rph   = (const float*)d_in[5];
  const float* rpw   = (const float*)d_in[6];
  float* out = (float*)d_out;
  char* ws = (char*)d_ws;

  __hip_bfloat16* xb     = (__hip_bfloat16*)(ws);
  __hip_bfloat16* wqkvT  = (__hip_bfloat16*)(ws + 12582912);
  __hip_bfloat16* wprojT = (__hip_bfloat16*)(ws + 16121856);
  __hip_bfloat16* qkvb   = (__hip_bfloat16*)(ws + 17301504);  // later aliased as attn-out
  __hip_bfloat16* Qm     = (__hip_bfloat16*)(ws + 55050240);
  __hip_bfloat16* Km     = (__hip_bfloat16*)(ws + 67633152);
  __hip_bfloat16* Vtm    = (__hip_bfloat16*)(ws + 80216064);

  cast_f32_bf16<<<dim3(6144), dim3(256), 0, stream>>>(x, xb);
  transpose_cast<<<dim3(72, 24), dim3(256), 0, stream>>>(Wqkv, wqkvT, 768, 2304);
  transpose_cast<<<dim3(24, 24), dim3(256), 0, stream>>>(Wproj, wprojT, 768, 768);
  gemm_pipe<128, true><<<dim3(18, 64), dim3(256), 0, stream>>>(xb, wqkvT, bqkv, (void*)qkvb, 2304, 768);
  permute_v2<<<dim3(16, 96), dim3(256), 0, stream>>>(qkvb, Qm, Km, Vtm);
  attn13<<<dim3(768), dim3(512), 0, stream>>>(Qm, Km, Vtm, rph, rpw, qkvb);
  gemm_pipe<64, false><<<dim3(6, 128), dim3(256), 0, stream>>>(qkvb, wprojT, bproj, (void*)out, 768, 768);
}